// Round 1
// baseline (13664.720 us; speedup 1.0000x reference)
//
#include <hip/hip_runtime.h>
#include <math.h>

// Problem constants
constexpr int N = 1024, B = 64, T = 12, HOR = 12, H = 64, E = 8;

// Workspace layout (in floats)
constexpr size_t A_off   = 0;                            // [1024][1024]  (rows 0..1023 of stacked S)
constexpr size_t S2_off  = (size_t)N * N;                // [1024][1024]  (rows 1024..2047, contiguous after A)
constexpr size_t xT_off  = 2ull * N * N;                 // [1024][768]   xT[n][t*64+b]
constexpr size_t Px_off  = xT_off + (size_t)N * T * B;   // [2][1024][768]
constexpr size_t yT_off  = Px_off + 2ull * N * T * B;    // [1024][768]
constexpr size_t Py_off  = yT_off + (size_t)N * T * B;   // [2][1024][768]
constexpr size_t h_off   = Py_off + 2ull * N * T * B;    // [1024][4096]  h[n][b*64+j]
constexpr size_t Ph_off  = h_off + (size_t)N * B * H;    // [2][1024][4096] (also reused as Pzh)
constexpr size_t zh_off  = Ph_off + 2ull * N * B * H;    // [1024][4096]
constexpr size_t r_off   = zh_off + (size_t)N * B * H;   // [1024][4096]
constexpr size_t go_off  = r_off + (size_t)N * B * H;    // [1024][64]
constexpr size_t Pgo_off = go_off + (size_t)N * B;       // [2][1024][64]

// ---------------------------------------------------------------------------
// A = softmax(relu(emb @ emb^T)) row-wise. One block per row.
// ---------------------------------------------------------------------------
__global__ __launch_bounds__(256) void build_A(const float* __restrict__ emb,
                                               float* __restrict__ A) {
  __shared__ float sE[N * E];     // 32 KB
  __shared__ float sv[N];         // 4 KB
  __shared__ float rmax[4], rsum[4];
  const int i = blockIdx.x;
  for (int idx = threadIdx.x; idx < N * E / 4; idx += 256)
    ((float4*)sE)[idx] = ((const float4*)emb)[idx];
  __syncthreads();
  float ei[E];
#pragma unroll
  for (int e = 0; e < E; ++e) ei[e] = sE[i * E + e];
  float mymax = 0.f;  // relu output >= 0, so 0 is a safe init for the max
  for (int j = threadIdx.x; j < N; j += 256) {
    float d = 0.f;
#pragma unroll
    for (int e = 0; e < E; ++e) d = fmaf(ei[e], sE[j * E + e], d);
    d = fmaxf(d, 0.f);
    sv[j] = d;
    mymax = fmaxf(mymax, d);
  }
  for (int off = 32; off; off >>= 1) mymax = fmaxf(mymax, __shfl_down(mymax, off));
  const int wid = threadIdx.x >> 6, lid = threadIdx.x & 63;
  if (lid == 0) rmax[wid] = mymax;
  __syncthreads();
  const float m = fmaxf(fmaxf(rmax[0], rmax[1]), fmaxf(rmax[2], rmax[3]));
  float mysum = 0.f;
  for (int j = threadIdx.x; j < N; j += 256) {
    float ev = expf(sv[j] - m);
    sv[j] = ev;
    mysum += ev;
  }
  for (int off = 32; off; off >>= 1) mysum += __shfl_down(mysum, off);
  if (lid == 0) rsum[wid] = mysum;
  __syncthreads();
  const float inv = 1.f / (rsum[0] + rsum[1] + rsum[2] + rsum[3]);
  for (int j = threadIdx.x; j < N; j += 256) A[i * N + j] = sv[j] * inv;
}

// ---------------------------------------------------------------------------
// Generic fp32 GEMM: C[M][n1] = Am[M][K] @ Bm[K][n1]  (row-major, lda=K, ldb=ldc=n1)
// Optional fold: columns [n1, ntot) come from B2[K][64] and go to C2[M][64].
// mode 1: epilogue v = 2v - I (for S2 = 2*A@A - I).
// Tiles: 128x128x16, 256 threads, 8x8 per thread.
// ---------------------------------------------------------------------------
__global__ __launch_bounds__(256) void gemm_f32(
    const float* __restrict__ Am, const float* __restrict__ Bm,
    const float* __restrict__ B2, float* __restrict__ Cm, float* __restrict__ C2,
    int M, int K, int n1, int ntot, int mode) {
  __shared__ float As[16][132];
  __shared__ float Bs[16][132];
  const int t = threadIdx.x;
  const int bn = blockIdx.x * 128;
  const int bm = blockIdx.y * 128;
  const int tm = (t >> 4) * 8;
  const int tn = (t & 15) * 8;
  const bool inB1 = (bn < n1);
  float acc[8][8] = {};
  for (int k0 = 0; k0 < K; k0 += 16) {
#pragma unroll
    for (int u = 0; u < 2; ++u) {
      int id = t + u * 256;          // 0..511
      int m = id >> 2;
      int k4 = (id & 3) * 4;
      float4 v = *(const float4*)(Am + (size_t)(bm + m) * K + k0 + k4);
      As[k4 + 0][m] = v.x; As[k4 + 1][m] = v.y;
      As[k4 + 2][m] = v.z; As[k4 + 3][m] = v.w;
    }
#pragma unroll
    for (int u = 0; u < 2; ++u) {
      int id = t + u * 256;
      int kr = id >> 5;
      int c4 = (id & 31) * 4;
      float4 v;
      if (inB1) {
        v = *(const float4*)(Bm + (size_t)(k0 + kr) * n1 + bn + c4);
      } else {
        int c2 = bn - n1 + c4;
        if (c2 + 3 < 64) v = *(const float4*)(B2 + (size_t)(k0 + kr) * 64 + c2);
        else v = make_float4(0.f, 0.f, 0.f, 0.f);
      }
      *(float4*)(&Bs[kr][c4]) = v;
    }
    __syncthreads();
#pragma unroll
    for (int kk = 0; kk < 16; ++kk) {
      float a[8], bf[8];
      *(float4*)(a)      = *(const float4*)(&As[kk][tm]);
      *(float4*)(a + 4)  = *(const float4*)(&As[kk][tm + 4]);
      *(float4*)(bf)     = *(const float4*)(&Bs[kk][tn]);
      *(float4*)(bf + 4) = *(const float4*)(&Bs[kk][tn + 4]);
#pragma unroll
      for (int i = 0; i < 8; ++i)
#pragma unroll
        for (int j = 0; j < 8; ++j)
          acc[i][j] = fmaf(a[i], bf[j], acc[i][j]);
    }
    __syncthreads();
  }
#pragma unroll
  for (int i = 0; i < 8; ++i) {
    int gm = bm + tm + i;
#pragma unroll
    for (int j4 = 0; j4 < 2; ++j4) {
      float4 v = {acc[i][j4 * 4 + 0], acc[i][j4 * 4 + 1],
                  acc[i][j4 * 4 + 2], acc[i][j4 * 4 + 3]};
      int gc = bn + tn + j4 * 4;
      if (mode == 1) {
        v.x = 2.f * v.x - (gm == gc + 0 ? 1.f : 0.f);
        v.y = 2.f * v.y - (gm == gc + 1 ? 1.f : 0.f);
        v.z = 2.f * v.z - (gm == gc + 2 ? 1.f : 0.f);
        v.w = 2.f * v.w - (gm == gc + 3 ? 1.f : 0.f);
      }
      if (gc < n1) {
        *(float4*)(Cm + (size_t)gm * n1 + gc) = v;
      } else {
        int c2 = gc - n1;
        if (c2 < 64) *(float4*)(C2 + (size_t)gm * 64 + c2) = v;
      }
    }
  }
}

// ---------------------------------------------------------------------------
// Transpose x[b][t][n] -> xT[n][t*64+b]
// ---------------------------------------------------------------------------
__global__ __launch_bounds__(256) void transpose_bt(const float* __restrict__ src,
                                                    float* __restrict__ dst) {
  int id = blockIdx.x * 256 + threadIdx.x;
  if (id >= N * T * B) return;
  int n = id / (T * B);
  int tb = id % (T * B);
  int tt = tb >> 6, b = tb & 63;
  dst[id] = src[((size_t)b * T + tt) * N + n];
}

// ---------------------------------------------------------------------------
// Gate kernel: per node n, compute zr = sigmoid(gather([x_k, h_k]) @ W + b),
// write zh = z*h and r. Block = node; 256 threads = 32 col-quads x 8 b-groups.
// ---------------------------------------------------------------------------
template <int NS>
__global__ __launch_bounds__(256) void gate_kernel(
    const float* __restrict__ hmat, const float* __restrict__ Ph,
    const float* __restrict__ W, const float* __restrict__ bias,
    const float* __restrict__ s0, const float* __restrict__ Ps0, int s0_stride, int s0_off,
    const float* __restrict__ s1, const float* __restrict__ Ps1, int s1_stride, int s1_off,
    float* __restrict__ zh, float* __restrict__ rbuf) {
  const int n = blockIdx.x;
  __shared__ float sh[3][64][65];        // [k][c][b]
  __shared__ float sxs[3][NS][64];
  const float* hps[3] = {hmat + (size_t)n * 4096, Ph + (size_t)n * 4096,
                         Ph + (size_t)1024 * 4096 + (size_t)n * 4096};
#pragma unroll
  for (int p = 0; p < 3; ++p) {
    for (int i = threadIdx.x; i < 1024; i += 256) {
      float4 v = ((const float4*)hps[p])[i];
      int b = i >> 4;
      int c = (i & 15) * 4;
      sh[p][c + 0][b] = v.x; sh[p][c + 1][b] = v.y;
      sh[p][c + 2][b] = v.z; sh[p][c + 3][b] = v.w;
    }
  }
  if (threadIdx.x < 64) {
    int b = threadIdx.x;
    sxs[0][0][b] = s0[(size_t)n * s0_stride + s0_off + b];
    sxs[1][0][b] = Ps0[(size_t)n * s0_stride + s0_off + b];
    sxs[2][0][b] = Ps0[(size_t)1024 * s0_stride + (size_t)n * s0_stride + s0_off + b];
    if (NS == 2) {
      sxs[0][1][b] = s1[(size_t)n * s1_stride + s1_off + b];
      sxs[1][1][b] = Ps1[(size_t)n * s1_stride + s1_off + b];
      sxs[2][1][b] = Ps1[(size_t)1024 * s1_stride + (size_t)n * s1_stride + s1_off + b];
    }
  }
  __syncthreads();
  const int col4 = threadIdx.x & 31;   // column quad: cols col4*4..+3 of 128
  const int bgrp = threadIdx.x >> 5;   // 0..7 ; b = bgrp + 8*i
  const int CIN = NS + 64;
  float acc[8][4] = {};
#pragma unroll
  for (int k = 0; k < 3; ++k) {
    const float* Wk = W + (size_t)k * CIN * 128 + col4 * 4;
#pragma unroll
    for (int s = 0; s < NS; ++s) {
      float4 w = *(const float4*)(Wk + s * 128);
#pragma unroll
      for (int i = 0; i < 8; ++i) {
        float a = sxs[k][s][bgrp + 8 * i];
        acc[i][0] = fmaf(a, w.x, acc[i][0]);
        acc[i][1] = fmaf(a, w.y, acc[i][1]);
        acc[i][2] = fmaf(a, w.z, acc[i][2]);
        acc[i][3] = fmaf(a, w.w, acc[i][3]);
      }
    }
    const float* Wh = Wk + NS * 128;
    for (int c = 0; c < 64; ++c) {
      float4 w = *(const float4*)(Wh + c * 128);
#pragma unroll
      for (int i = 0; i < 8; ++i) {
        float a = sh[k][c][bgrp + 8 * i];
        acc[i][0] = fmaf(a, w.x, acc[i][0]);
        acc[i][1] = fmaf(a, w.y, acc[i][1]);
        acc[i][2] = fmaf(a, w.z, acc[i][2]);
        acc[i][3] = fmaf(a, w.w, acc[i][3]);
      }
    }
  }
  const int col = col4 * 4;
  float4 bv = *(const float4*)(bias + col);
  const float bb4[4] = {bv.x, bv.y, bv.z, bv.w};
#pragma unroll
  for (int i = 0; i < 8; ++i) {
    int b = bgrp + 8 * i;
    float v[4];
#pragma unroll
    for (int j = 0; j < 4; ++j) {
      float xx = acc[i][j] + bb4[j];
      v[j] = 1.f / (1.f + expf(-xx));
    }
    if (col < 64) {   // z part -> zh = z * h
      float4 o;
      o.x = v[0] * sh[0][col + 0][b];
      o.y = v[1] * sh[0][col + 1][b];
      o.z = v[2] * sh[0][col + 2][b];
      o.w = v[3] * sh[0][col + 3][b];
      *(float4*)(zh + (size_t)n * 4096 + b * 64 + col) = o;
    } else {          // r part
      float4 o = {v[0], v[1], v[2], v[3]};
      *(float4*)(rbuf + (size_t)n * 4096 + b * 64 + (col - 64)) = o;
    }
  }
}

// ---------------------------------------------------------------------------
// Update kernel: hc = tanh(gather([x_k, zh_k]) @ W + b); h = r*h + (1-r)*hc
// Block = node; 256 threads = 16 col-quads x 16 b-groups.
// ---------------------------------------------------------------------------
template <int NS>
__global__ __launch_bounds__(256) void upd_kernel(
    float* __restrict__ hmat, const float* __restrict__ Pzh, const float* __restrict__ zhb,
    const float* __restrict__ W, const float* __restrict__ bias,
    const float* __restrict__ s0, const float* __restrict__ Ps0, int s0_stride, int s0_off,
    const float* __restrict__ s1, const float* __restrict__ Ps1, int s1_stride, int s1_off,
    const float* __restrict__ rbuf) {
  const int n = blockIdx.x;
  __shared__ float sh[3][64][65];
  __shared__ float sxs[3][NS][64];
  const float* hps[3] = {zhb + (size_t)n * 4096, Pzh + (size_t)n * 4096,
                         Pzh + (size_t)1024 * 4096 + (size_t)n * 4096};
#pragma unroll
  for (int p = 0; p < 3; ++p) {
    for (int i = threadIdx.x; i < 1024; i += 256) {
      float4 v = ((const float4*)hps[p])[i];
      int b = i >> 4;
      int c = (i & 15) * 4;
      sh[p][c + 0][b] = v.x; sh[p][c + 1][b] = v.y;
      sh[p][c + 2][b] = v.z; sh[p][c + 3][b] = v.w;
    }
  }
  if (threadIdx.x < 64) {
    int b = threadIdx.x;
    sxs[0][0][b] = s0[(size_t)n * s0_stride + s0_off + b];
    sxs[1][0][b] = Ps0[(size_t)n * s0_stride + s0_off + b];
    sxs[2][0][b] = Ps0[(size_t)1024 * s0_stride + (size_t)n * s0_stride + s0_off + b];
    if (NS == 2) {
      sxs[0][1][b] = s1[(size_t)n * s1_stride + s1_off + b];
      sxs[1][1][b] = Ps1[(size_t)n * s1_stride + s1_off + b];
      sxs[2][1][b] = Ps1[(size_t)1024 * s1_stride + (size_t)n * s1_stride + s1_off + b];
    }
  }
  __syncthreads();
  const int col4 = threadIdx.x & 15;   // cols col4*4..+3 of 64
  const int bgrp = threadIdx.x >> 4;   // 0..15 ; b = bgrp + 16*i
  const int CIN = NS + 64;
  float acc[4][4] = {};
#pragma unroll
  for (int k = 0; k < 3; ++k) {
    const float* Wk = W + (size_t)k * CIN * 64 + col4 * 4;
#pragma unroll
    for (int s = 0; s < NS; ++s) {
      float4 w = *(const float4*)(Wk + s * 64);
#pragma unroll
      for (int i = 0; i < 4; ++i) {
        float a = sxs[k][s][bgrp + 16 * i];
        acc[i][0] = fmaf(a, w.x, acc[i][0]);
        acc[i][1] = fmaf(a, w.y, acc[i][1]);
        acc[i][2] = fmaf(a, w.z, acc[i][2]);
        acc[i][3] = fmaf(a, w.w, acc[i][3]);
      }
    }
    const float* Wh = Wk + NS * 64;
    for (int c = 0; c < 64; ++c) {
      float4 w = *(const float4*)(Wh + c * 64);
#pragma unroll
      for (int i = 0; i < 4; ++i) {
        float a = sh[k][c][bgrp + 16 * i];
        acc[i][0] = fmaf(a, w.x, acc[i][0]);
        acc[i][1] = fmaf(a, w.y, acc[i][1]);
        acc[i][2] = fmaf(a, w.z, acc[i][2]);
        acc[i][3] = fmaf(a, w.w, acc[i][3]);
      }
    }
  }
  const int col = col4 * 4;
  float4 bv = *(const float4*)(bias + col);
#pragma unroll
  for (int i = 0; i < 4; ++i) {
    int b = bgrp + 16 * i;
    float hc0 = tanhf(acc[i][0] + bv.x);
    float hc1 = tanhf(acc[i][1] + bv.y);
    float hc2 = tanhf(acc[i][2] + bv.z);
    float hc3 = tanhf(acc[i][3] + bv.w);
    size_t idx = (size_t)n * 4096 + b * 64 + col;
    float4 r4 = *(const float4*)(rbuf + idx);
    float4 h4 = *(const float4*)(hmat + idx);
    float4 o;
    o.x = r4.x * h4.x + (1.f - r4.x) * hc0;
    o.y = r4.y * h4.y + (1.f - r4.y) * hc1;
    o.z = r4.z * h4.z + (1.f - r4.z) * hc2;
    o.w = r4.w * h4.w + (1.f - r4.w) * hc3;
    *(float4*)(hmat + idx) = o;
  }
}

// ---------------------------------------------------------------------------
// Projection: go[n][b] = h[n][b*64..] . proj_W + pb ; write out[b][t][n] and gobuf
// ---------------------------------------------------------------------------
__global__ __launch_bounds__(256) void proj_kernel(
    const float* __restrict__ hmat, const float* __restrict__ pW,
    const float* __restrict__ pb, float* __restrict__ gobuf,
    float* __restrict__ out, int tstep) {
  const int n = blockIdx.x;
  const int b = threadIdx.x & 63;
  const int q = threadIdx.x >> 6;
  __shared__ float sW[64];
  __shared__ float part[4][64];
  if (threadIdx.x < 64) sW[threadIdx.x] = pW[threadIdx.x];
  __syncthreads();
  const float* hp = hmat + (size_t)n * 4096 + b * 64 + q * 16;
  float sum = 0.f;
#pragma unroll
  for (int j = 0; j < 16; ++j) sum = fmaf(hp[j], sW[q * 16 + j], sum);
  part[q][b] = sum;
  __syncthreads();
  if (threadIdx.x < 64) {
    int bb = threadIdx.x;
    float g = part[0][bb] + part[1][bb] + part[2][bb] + part[3][bb] + pb[0];
    gobuf[(size_t)n * 64 + bb] = g;
    out[((size_t)bb * HOR + tstep) * N + n] = g;
  }
}

// ---------------------------------------------------------------------------
extern "C" void kernel_launch(void* const* d_in, const int* in_sizes, int n_in,
                              void* d_out, int out_size, void* d_ws, size_t ws_size,
                              hipStream_t stream) {
  const float* x    = (const float*)d_in[0];
  const float* ycov = (const float*)d_in[1];
  const float* emb  = (const float*)d_in[2];
  const float* egW  = (const float*)d_in[3];
  const float* egb  = (const float*)d_in[4];
  const float* euW  = (const float*)d_in[5];
  const float* eub  = (const float*)d_in[6];
  const float* dgW  = (const float*)d_in[7];
  const float* dgb  = (const float*)d_in[8];
  const float* duW  = (const float*)d_in[9];
  const float* dub  = (const float*)d_in[10];
  const float* pW   = (const float*)d_in[11];
  const float* pb   = (const float*)d_in[12];
  float* out = (float*)d_out;
  float* ws  = (float*)d_ws;

  float* Amat = ws + A_off;   // stacked S = [A ; S2] : [2048][1024]
  float* S2   = ws + S2_off;
  float* xT   = ws + xT_off;
  float* Px   = ws + Px_off;
  float* yT   = ws + yT_off;
  float* Py   = ws + Py_off;
  float* hmat = ws + h_off;
  float* Ph   = ws + Ph_off;
  float* zh   = ws + zh_off;
  float* rb   = ws + r_off;
  float* gob  = ws + go_off;
  float* Pgo  = ws + Pgo_off;

  // ---- precompute ----
  build_A<<<N, 256, 0, stream>>>(emb, Amat);
  gemm_f32<<<dim3(8, 8), 256, 0, stream>>>(Amat, Amat, nullptr, S2, nullptr,
                                           N, N, N, N, 1);
  transpose_bt<<<(N * T * B + 255) / 256, 256, 0, stream>>>(x, xT);
  transpose_bt<<<(N * T * B + 255) / 256, 256, 0, stream>>>(ycov, yT);
  gemm_f32<<<dim3(6, 16), 256, 0, stream>>>(Amat, xT, nullptr, Px, nullptr,
                                            2 * N, N, T * B, T * B, 0);
  gemm_f32<<<dim3(6, 16), 256, 0, stream>>>(Amat, yT, nullptr, Py, nullptr,
                                            2 * N, N, T * B, T * B, 0);
  hipMemsetAsync(hmat, 0, (size_t)N * B * H * sizeof(float), stream);
  hipMemsetAsync(Ph, 0, 2ull * N * B * H * sizeof(float), stream);
  hipMemsetAsync(gob, 0, ((size_t)N * B + 2ull * N * B) * sizeof(float), stream);

  // ---- encoder ----
  for (int t = 0; t < T; ++t) {
    if (t > 0)  // t=0: h=0 so Ph=0 (memset above)
      gemm_f32<<<dim3(32, 16), 256, 0, stream>>>(Amat, hmat, nullptr, Ph, nullptr,
                                                 2 * N, N, B * H, B * H, 0);
    gate_kernel<1><<<N, 256, 0, stream>>>(hmat, Ph, egW, egb,
                                          xT, Px, T * B, t * B,
                                          nullptr, nullptr, 0, 0, zh, rb);
    gemm_f32<<<dim3(32, 16), 256, 0, stream>>>(Amat, zh, nullptr, Ph, nullptr,
                                               2 * N, N, B * H, B * H, 0);
    upd_kernel<1><<<N, 256, 0, stream>>>(hmat, Ph, zh, euW, eub,
                                         xT, Px, T * B, t * B,
                                         nullptr, nullptr, 0, 0, rb);
  }

  // ---- decoder ----
  for (int t = 0; t < HOR; ++t) {
    // gate propagation, with go-propagation folded in as 64 extra columns
    gemm_f32<<<dim3(33, 16), 256, 0, stream>>>(Amat, hmat, gob, Ph, Pgo,
                                               2 * N, N, B * H, B * H + B, 0);
    gate_kernel<2><<<N, 256, 0, stream>>>(hmat, Ph, dgW, dgb,
                                          gob, Pgo, B, 0,
                                          yT, Py, T * B, t * B, zh, rb);
    gemm_f32<<<dim3(32, 16), 256, 0, stream>>>(Amat, zh, nullptr, Ph, nullptr,
                                               2 * N, N, B * H, B * H, 0);
    upd_kernel<2><<<N, 256, 0, stream>>>(hmat, Ph, zh, duW, dub,
                                         gob, Pgo, B, 0,
                                         yT, Py, T * B, t * B, rb);
    proj_kernel<<<N, 256, 0, stream>>>(hmat, pW, pb, gob, out, t);
  }
}

// Round 2
// 7465.223 us; speedup vs baseline: 1.8305x; 1.8305x over previous
//
#include <hip/hip_runtime.h>
#include <math.h>

// Problem constants
constexpr int N = 1024, B = 64, T = 12, HOR = 12, H = 64, E = 8;
constexpr int K2 = 2048;         // split-doubled K for MFMA gemm
constexpr size_t NTB = (size_t)N * T * B;
constexpr size_t NBH = (size_t)N * B * H;

// Workspace layout (float units; bf16 buffers counted as float-equivalents)
constexpr size_t A_off   = 0;                       // [2048][1024] fp32 stacked S=[A;S2]
constexpr size_t xT_off  = 2ull * N * N;            // [1024][768]
constexpr size_t Px_off  = xT_off + NTB;            // [2][1024][768]
constexpr size_t yT_off  = Px_off + 2 * NTB;        // [1024][768]
constexpr size_t Py_off  = yT_off + NTB;            // [2][1024][768]
constexpr size_t h_off   = Py_off + 2 * NTB;        // [1024][4096]
constexpr size_t Ph_off  = h_off + NBH;             // [2][1024][4096] (also Pzh)
constexpr size_t zh_off  = Ph_off + 2 * NBH;        // [1024][4096]
constexpr size_t r_off   = zh_off + NBH;            // [1024][4096]
constexpr size_t go_off  = r_off + NBH;             // [1024][64]
constexpr size_t Pgo_off = go_off + (size_t)N * B;  // [2][1024][64]
// bf16-split buffers (ushort), K-major for the MFMA gemm (B^T layout)
constexpr size_t A2_off  = Pgo_off + 2ull * N * B;        // ushort[2048][2048]
constexpr size_t Bh_off  = A2_off + 2048ull * 1024;       // ushort[4224][2048]
constexpr size_t Bz_off  = Bh_off + 4224ull * 1024;       // ushort[4096][2048]

typedef __attribute__((ext_vector_type(8))) short short8;
typedef __attribute__((ext_vector_type(4))) float f32x4;

__device__ __forceinline__ unsigned f2bf(float x) {
  unsigned u = __float_as_uint(x);
  return (u + 0x7fffu + ((u >> 16) & 1u)) >> 16;
}
__device__ __forceinline__ float bf2f(unsigned h) {
  return __uint_as_float(h << 16);
}
__device__ __forceinline__ unsigned pack_split(float x) {
  unsigned hi = f2bf(x);
  float rem = x - bf2f(hi);
  unsigned lo = f2bf(rem);
  return (hi & 0xffffu) | (lo << 16);
}

// ---------------------------------------------------------------------------
// A = softmax(relu(emb @ emb^T)) row-wise. One block per row.
// ---------------------------------------------------------------------------
__global__ __launch_bounds__(256) void build_A(const float* __restrict__ emb,
                                               float* __restrict__ A) {
  __shared__ float sE[N * E];
  __shared__ float sv[N];
  __shared__ float rmax[4], rsum[4];
  const int i = blockIdx.x;
  for (int idx = threadIdx.x; idx < N * E / 4; idx += 256)
    ((float4*)sE)[idx] = ((const float4*)emb)[idx];
  __syncthreads();
  float ei[E];
#pragma unroll
  for (int e = 0; e < E; ++e) ei[e] = sE[i * E + e];
  float mymax = 0.f;
  for (int j = threadIdx.x; j < N; j += 256) {
    float d = 0.f;
#pragma unroll
    for (int e = 0; e < E; ++e) d = fmaf(ei[e], sE[j * E + e], d);
    d = fmaxf(d, 0.f);
    sv[j] = d;
    mymax = fmaxf(mymax, d);
  }
  for (int off = 32; off; off >>= 1) mymax = fmaxf(mymax, __shfl_down(mymax, off));
  const int wid = threadIdx.x >> 6, lid = threadIdx.x & 63;
  if (lid == 0) rmax[wid] = mymax;
  __syncthreads();
  const float m = fmaxf(fmaxf(rmax[0], rmax[1]), fmaxf(rmax[2], rmax[3]));
  float mysum = 0.f;
  for (int j = threadIdx.x; j < N; j += 256) {
    float ev = expf(sv[j] - m);
    sv[j] = ev;
    mysum += ev;
  }
  for (int off = 32; off; off >>= 1) mysum += __shfl_down(mysum, off);
  if (lid == 0) rsum[wid] = mysum;
  __syncthreads();
  const float inv = 1.f / (rsum[0] + rsum[1] + rsum[2] + rsum[3]);
  for (int j = threadIdx.x; j < N; j += 256) A[i * N + j] = sv[j] * inv;
}

// ---------------------------------------------------------------------------
// fp32 vector GEMM (precompute only: S2 = 2*A@A - I, Px, Py)
// ---------------------------------------------------------------------------
__global__ __launch_bounds__(256) void gemm_f32(
    const float* __restrict__ Am, const float* __restrict__ Bm,
    float* __restrict__ Cm, int M, int K, int n1, int mode) {
  __shared__ float As[16][132];
  __shared__ float Bs[16][132];
  const int t = threadIdx.x;
  const int bn = blockIdx.x * 128;
  const int bm = blockIdx.y * 128;
  const int tm = (t >> 4) * 8;
  const int tn = (t & 15) * 8;
  float acc[8][8] = {};
  for (int k0 = 0; k0 < K; k0 += 16) {
#pragma unroll
    for (int u = 0; u < 2; ++u) {
      int id = t + u * 256;
      int m = id >> 2;
      int k4 = (id & 3) * 4;
      float4 v = *(const float4*)(Am + (size_t)(bm + m) * K + k0 + k4);
      As[k4 + 0][m] = v.x; As[k4 + 1][m] = v.y;
      As[k4 + 2][m] = v.z; As[k4 + 3][m] = v.w;
    }
#pragma unroll
    for (int u = 0; u < 2; ++u) {
      int id = t + u * 256;
      int kr = id >> 5;
      int c4 = (id & 31) * 4;
      float4 v = *(const float4*)(Bm + (size_t)(k0 + kr) * n1 + bn + c4);
      *(float4*)(&Bs[kr][c4]) = v;
    }
    __syncthreads();
#pragma unroll
    for (int kk = 0; kk < 16; ++kk) {
      float a[8], bf[8];
      *(float4*)(a)      = *(const float4*)(&As[kk][tm]);
      *(float4*)(a + 4)  = *(const float4*)(&As[kk][tm + 4]);
      *(float4*)(bf)     = *(const float4*)(&Bs[kk][tn]);
      *(float4*)(bf + 4) = *(const float4*)(&Bs[kk][tn + 4]);
#pragma unroll
      for (int i = 0; i < 8; ++i)
#pragma unroll
        for (int j = 0; j < 8; ++j)
          acc[i][j] = fmaf(a[i], bf[j], acc[i][j]);
    }
    __syncthreads();
  }
#pragma unroll
  for (int i = 0; i < 8; ++i) {
    int gm = bm + tm + i;
#pragma unroll
    for (int j4 = 0; j4 < 2; ++j4) {
      float4 v = {acc[i][j4 * 4 + 0], acc[i][j4 * 4 + 1],
                  acc[i][j4 * 4 + 2], acc[i][j4 * 4 + 3]};
      int gc = bn + tn + j4 * 4;
      if (mode == 1) {
        v.x = 2.f * v.x - (gm == gc + 0 ? 1.f : 0.f);
        v.y = 2.f * v.y - (gm == gc + 1 ? 1.f : 0.f);
        v.z = 2.f * v.z - (gm == gc + 2 ? 1.f : 0.f);
        v.w = 2.f * v.w - (gm == gc + 3 ? 1.f : 0.f);
      }
      *(float4*)(Cm + (size_t)gm * n1 + gc) = v;
    }
  }
}

// ---------------------------------------------------------------------------
// Split stacked S [2048][1024] fp32 -> A2 ushort[2048][2048], K-interleaved
// ---------------------------------------------------------------------------
__global__ __launch_bounds__(256) void split_A(const float* __restrict__ S,
                                               unsigned* __restrict__ A2) {
  size_t idx = (size_t)blockIdx.x * 256 + threadIdx.x;
  A2[idx] = pack_split(S[idx]);
}

// ---------------------------------------------------------------------------
// MFMA split-bf16 GEMM (m97 structure): C[2048][*] = A2[2048][2048] @ Bcm^T
// Bcm is [cols][2048] K-major. 128x128 tile, BK=32, 4 waves, 16x16x32 MFMA.
// cols <4096 -> C1 (stride 4096); 4096..4159 -> C2 (stride 64); >=4160 drop.
// ---------------------------------------------------------------------------
typedef const __attribute__((address_space(1))) void gas_t;
typedef __attribute__((address_space(3))) void las_t;

__global__ __launch_bounds__(256) void gemm_mfma(
    const ushort* __restrict__ A2, const ushort* __restrict__ Bcm,
    float* __restrict__ C1, float* __restrict__ C2) {
  __shared__ ushort As[128 * 32];
  __shared__ ushort Bs[128 * 32];
  const int t = threadIdx.x;
  const int wave = t >> 6, lane = t & 63;
  const int bm = blockIdx.y * 128, bn = blockIdx.x * 128;
  const int wm = (wave & 1) * 64, wn = (wave >> 1) * 64;

  const ushort* aSrc[2]; const ushort* bSrc[2];
  ushort* aDst[2]; ushort* bDst[2];
#pragma unroll
  for (int u = 0; u < 2; ++u) {
    int idx = wave * 128 + u * 64 + lane;
    int row = idx >> 2;
    int kq = (idx & 3) * 8;
    aSrc[u] = A2 + (size_t)(bm + row) * K2 + kq;
    bSrc[u] = Bcm + (size_t)(bn + row) * K2 + kq;
    aDst[u] = &As[(wave * 128 + u * 64) * 8];
    bDst[u] = &Bs[(wave * 128 + u * 64) * 8];
  }

  const int lr = lane & 15;
  const int lk = (lane >> 4) * 8;
  const ushort* aFrag[4]; const ushort* bFrag[4];
#pragma unroll
  for (int i = 0; i < 4; ++i) {
    aFrag[i] = &As[(wm + i * 16 + lr) * 32 + lk];
    bFrag[i] = &Bs[(wn + i * 16 + lr) * 32 + lk];
  }

  f32x4 acc[4][4];
#pragma unroll
  for (int i = 0; i < 4; ++i)
#pragma unroll
    for (int j = 0; j < 4; ++j) acc[i][j] = {0.f, 0.f, 0.f, 0.f};

  for (int k0 = 0; k0 < K2; k0 += 32) {
#pragma unroll
    for (int u = 0; u < 2; ++u) {
      __builtin_amdgcn_global_load_lds((gas_t*)(aSrc[u] + k0), (las_t*)aDst[u], 16, 0, 0);
      __builtin_amdgcn_global_load_lds((gas_t*)(bSrc[u] + k0), (las_t*)bDst[u], 16, 0, 0);
    }
    __syncthreads();
    short8 a[4], b[4];
#pragma unroll
    for (int i = 0; i < 4; ++i) a[i] = *(const short8*)aFrag[i];
#pragma unroll
    for (int j = 0; j < 4; ++j) b[j] = *(const short8*)bFrag[j];
#pragma unroll
    for (int i = 0; i < 4; ++i)
#pragma unroll
      for (int j = 0; j < 4; ++j)
        acc[i][j] = __builtin_amdgcn_mfma_f32_16x16x32_bf16(a[i], b[j], acc[i][j], 0, 0, 0);
    __syncthreads();
  }

  const int cr = (lane >> 4) * 4;
  const int cc = lane & 15;
#pragma unroll
  for (int i = 0; i < 4; ++i) {
#pragma unroll
    for (int j = 0; j < 4; ++j) {
      int gm = bm + wm + i * 16 + cr;
      int gn = bn + wn + j * 16 + cc;
      if (gn < 4096) {
        float* p = C1 + (size_t)gm * 4096 + gn;
#pragma unroll
        for (int r = 0; r < 4; ++r) p[(size_t)r * 4096] = acc[i][j][r];
      } else if (C2 != nullptr && gn < 4160) {
        float* p = C2 + (size_t)gm * 64 + (gn - 4096);
#pragma unroll
        for (int r = 0; r < 4; ++r) p[(size_t)r * 64] = acc[i][j][r];
      }
    }
  }
}

// ---------------------------------------------------------------------------
__global__ __launch_bounds__(256) void transpose_bt(const float* __restrict__ src,
                                                    float* __restrict__ dst) {
  int id = blockIdx.x * 256 + threadIdx.x;
  if (id >= N * T * B) return;
  int n = id / (T * B);
  int tb = id % (T * B);
  int tt = tb >> 6, b = tb & 63;
  dst[id] = src[((size_t)b * T + tt) * N + n];
}

// ---------------------------------------------------------------------------
template <int NS>
__global__ __launch_bounds__(256) void gate_kernel(
    const float* __restrict__ hmat, const float* __restrict__ Ph,
    const float* __restrict__ W, const float* __restrict__ bias,
    const float* __restrict__ s0, const float* __restrict__ Ps0, int s0_stride, int s0_off,
    const float* __restrict__ s1, const float* __restrict__ Ps1, int s1_stride, int s1_off,
    float* __restrict__ zh, float* __restrict__ rbuf, unsigned* __restrict__ Bz32) {
  const int n = blockIdx.x;
  __shared__ float sh[3][64][65];
  __shared__ float sxs[3][NS][64];
  const float* hps[3] = {hmat + (size_t)n * 4096, Ph + (size_t)n * 4096,
                         Ph + (size_t)1024 * 4096 + (size_t)n * 4096};
#pragma unroll
  for (int p = 0; p < 3; ++p) {
    for (int i = threadIdx.x; i < 1024; i += 256) {
      float4 v = ((const float4*)hps[p])[i];
      int b = i >> 4;
      int c = (i & 15) * 4;
      sh[p][c + 0][b] = v.x; sh[p][c + 1][b] = v.y;
      sh[p][c + 2][b] = v.z; sh[p][c + 3][b] = v.w;
    }
  }
  if (threadIdx.x < 64) {
    int b = threadIdx.x;
    sxs[0][0][b] = s0[(size_t)n * s0_stride + s0_off + b];
    sxs[1][0][b] = Ps0[(size_t)n * s0_stride + s0_off + b];
    sxs[2][0][b] = Ps0[(size_t)1024 * s0_stride + (size_t)n * s0_stride + s0_off + b];
    if (NS == 2) {
      sxs[0][1][b] = s1[(size_t)n * s1_stride + s1_off + b];
      sxs[1][1][b] = Ps1[(size_t)n * s1_stride + s1_off + b];
      sxs[2][1][b] = Ps1[(size_t)1024 * s1_stride + (size_t)n * s1_stride + s1_off + b];
    }
  }
  __syncthreads();
  const int col4 = threadIdx.x & 31;
  const int bgrp = threadIdx.x >> 5;
  const int CIN = NS + 64;
  float acc[8][4] = {};
#pragma unroll
  for (int k = 0; k < 3; ++k) {
    const float* Wk = W + (size_t)k * CIN * 128 + col4 * 4;
#pragma unroll
    for (int s = 0; s < NS; ++s) {
      float4 w = *(const float4*)(Wk + s * 128);
#pragma unroll
      for (int i = 0; i < 8; ++i) {
        float a = sxs[k][s][bgrp + 8 * i];
        acc[i][0] = fmaf(a, w.x, acc[i][0]);
        acc[i][1] = fmaf(a, w.y, acc[i][1]);
        acc[i][2] = fmaf(a, w.z, acc[i][2]);
        acc[i][3] = fmaf(a, w.w, acc[i][3]);
      }
    }
    const float* Wh = Wk + NS * 128;
    for (int c = 0; c < 64; ++c) {
      float4 w = *(const float4*)(Wh + c * 128);
#pragma unroll
      for (int i = 0; i < 8; ++i) {
        float a = sh[k][c][bgrp + 8 * i];
        acc[i][0] = fmaf(a, w.x, acc[i][0]);
        acc[i][1] = fmaf(a, w.y, acc[i][1]);
        acc[i][2] = fmaf(a, w.z, acc[i][2]);
        acc[i][3] = fmaf(a, w.w, acc[i][3]);
      }
    }
  }
  const int col = col4 * 4;
  float4 bv = *(const float4*)(bias + col);
  const float bb4[4] = {bv.x, bv.y, bv.z, bv.w};
#pragma unroll
  for (int i = 0; i < 8; ++i) {
    int b = bgrp + 8 * i;
    float v[4];
#pragma unroll
    for (int j = 0; j < 4; ++j) {
      float xx = acc[i][j] + bb4[j];
      v[j] = 1.f / (1.f + expf(-xx));
    }
    if (col < 64) {
      float4 o;
      o.x = v[0] * sh[0][col + 0][b];
      o.y = v[1] * sh[0][col + 1][b];
      o.z = v[2] * sh[0][col + 2][b];
      o.w = v[3] * sh[0][col + 3][b];
      *(float4*)(zh + (size_t)n * 4096 + b * 64 + col) = o;
      Bz32[(size_t)(b * 64 + col + 0) * 1024 + n] = pack_split(o.x);
      Bz32[(size_t)(b * 64 + col + 1) * 1024 + n] = pack_split(o.y);
      Bz32[(size_t)(b * 64 + col + 2) * 1024 + n] = pack_split(o.z);
      Bz32[(size_t)(b * 64 + col + 3) * 1024 + n] = pack_split(o.w);
    } else {
      float4 o = {v[0], v[1], v[2], v[3]};
      *(float4*)(rbuf + (size_t)n * 4096 + b * 64 + (col - 64)) = o;
    }
  }
}

// ---------------------------------------------------------------------------
template <int NS>
__global__ __launch_bounds__(256) void upd_kernel(
    float* __restrict__ hmat, const float* __restrict__ Pzh, const float* __restrict__ zhb,
    const float* __restrict__ W, const float* __restrict__ bias,
    const float* __restrict__ s0, const float* __restrict__ Ps0, int s0_stride, int s0_off,
    const float* __restrict__ s1, const float* __restrict__ Ps1, int s1_stride, int s1_off,
    const float* __restrict__ rbuf, unsigned* __restrict__ Bh32) {
  const int n = blockIdx.x;
  __shared__ float sh[3][64][65];
  __shared__ float sxs[3][NS][64];
  const float* hps[3] = {zhb + (size_t)n * 4096, Pzh + (size_t)n * 4096,
                         Pzh + (size_t)1024 * 4096 + (size_t)n * 4096};
#pragma unroll
  for (int p = 0; p < 3; ++p) {
    for (int i = threadIdx.x; i < 1024; i += 256) {
      float4 v = ((const float4*)hps[p])[i];
      int b = i >> 4;
      int c = (i & 15) * 4;
      sh[p][c + 0][b] = v.x; sh[p][c + 1][b] = v.y;
      sh[p][c + 2][b] = v.z; sh[p][c + 3][b] = v.w;
    }
  }
  if (threadIdx.x < 64) {
    int b = threadIdx.x;
    sxs[0][0][b] = s0[(size_t)n * s0_stride + s0_off + b];
    sxs[1][0][b] = Ps0[(size_t)n * s0_stride + s0_off + b];
    sxs[2][0][b] = Ps0[(size_t)1024 * s0_stride + (size_t)n * s0_stride + s0_off + b];
    if (NS == 2) {
      sxs[0][1][b] = s1[(size_t)n * s1_stride + s1_off + b];
      sxs[1][1][b] = Ps1[(size_t)n * s1_stride + s1_off + b];
      sxs[2][1][b] = Ps1[(size_t)1024 * s1_stride + (size_t)n * s1_stride + s1_off + b];
    }
  }
  __syncthreads();
  const int col4 = threadIdx.x & 15;
  const int bgrp = threadIdx.x >> 4;
  const int CIN = NS + 64;
  float acc[4][4] = {};
#pragma unroll
  for (int k = 0; k < 3; ++k) {
    const float* Wk = W + (size_t)k * CIN * 64 + col4 * 4;
#pragma unroll
    for (int s = 0; s < NS; ++s) {
      float4 w = *(const float4*)(Wk + s * 64);
#pragma unroll
      for (int i = 0; i < 4; ++i) {
        float a = sxs[k][s][bgrp + 16 * i];
        acc[i][0] = fmaf(a, w.x, acc[i][0]);
        acc[i][1] = fmaf(a, w.y, acc[i][1]);
        acc[i][2] = fmaf(a, w.z, acc[i][2]);
        acc[i][3] = fmaf(a, w.w, acc[i][3]);
      }
    }
    const float* Wh = Wk + NS * 64;
    for (int c = 0; c < 64; ++c) {
      float4 w = *(const float4*)(Wh + c * 64);
#pragma unroll
      for (int i = 0; i < 4; ++i) {
        float a = sh[k][c][bgrp + 16 * i];
        acc[i][0] = fmaf(a, w.x, acc[i][0]);
        acc[i][1] = fmaf(a, w.y, acc[i][1]);
        acc[i][2] = fmaf(a, w.z, acc[i][2]);
        acc[i][3] = fmaf(a, w.w, acc[i][3]);
      }
    }
  }
  const int col = col4 * 4;
  float4 bv = *(const float4*)(bias + col);
#pragma unroll
  for (int i = 0; i < 4; ++i) {
    int b = bgrp + 16 * i;
    float hc0 = tanhf(acc[i][0] + bv.x);
    float hc1 = tanhf(acc[i][1] + bv.y);
    float hc2 = tanhf(acc[i][2] + bv.z);
    float hc3 = tanhf(acc[i][3] + bv.w);
    size_t idx = (size_t)n * 4096 + b * 64 + col;
    float4 r4 = *(const float4*)(rbuf + idx);
    float4 h4 = *(const float4*)(hmat + idx);
    float4 o;
    o.x = r4.x * h4.x + (1.f - r4.x) * hc0;
    o.y = r4.y * h4.y + (1.f - r4.y) * hc1;
    o.z = r4.z * h4.z + (1.f - r4.z) * hc2;
    o.w = r4.w * h4.w + (1.f - r4.w) * hc3;
    *(float4*)(hmat + idx) = o;
    Bh32[(size_t)(b * 64 + col + 0) * 1024 + n] = pack_split(o.x);
    Bh32[(size_t)(b * 64 + col + 1) * 1024 + n] = pack_split(o.y);
    Bh32[(size_t)(b * 64 + col + 2) * 1024 + n] = pack_split(o.z);
    Bh32[(size_t)(b * 64 + col + 3) * 1024 + n] = pack_split(o.w);
  }
}

// ---------------------------------------------------------------------------
__global__ __launch_bounds__(256) void proj_kernel(
    const float* __restrict__ hmat, const float* __restrict__ pW,
    const float* __restrict__ pb, float* __restrict__ gobuf,
    float* __restrict__ out, unsigned* __restrict__ Bh32, int tstep) {
  const int n = blockIdx.x;
  const int b = threadIdx.x & 63;
  const int q = threadIdx.x >> 6;
  __shared__ float sW[64];
  __shared__ float part[4][64];
  if (threadIdx.x < 64) sW[threadIdx.x] = pW[threadIdx.x];
  __syncthreads();
  const float* hp = hmat + (size_t)n * 4096 + b * 64 + q * 16;
  float sum = 0.f;
#pragma unroll
  for (int j = 0; j < 16; ++j) sum = fmaf(hp[j], sW[q * 16 + j], sum);
  part[q][b] = sum;
  __syncthreads();
  if (threadIdx.x < 64) {
    int bb = threadIdx.x;
    float g = part[0][bb] + part[1][bb] + part[2][bb] + part[3][bb] + pb[0];
    gobuf[(size_t)n * 64 + bb] = g;
    out[((size_t)bb * HOR + tstep) * N + n] = g;
    Bh32[(size_t)(4096 + bb) * 1024 + n] = pack_split(g);
  }
}

// ---------------------------------------------------------------------------
extern "C" void kernel_launch(void* const* d_in, const int* in_sizes, int n_in,
                              void* d_out, int out_size, void* d_ws, size_t ws_size,
                              hipStream_t stream) {
  const float* x    = (const float*)d_in[0];
  const float* ycov = (const float*)d_in[1];
  const float* emb  = (const float*)d_in[2];
  const float* egW  = (const float*)d_in[3];
  const float* egb  = (const float*)d_in[4];
  const float* euW  = (const float*)d_in[5];
  const float* eub  = (const float*)d_in[6];
  const float* dgW  = (const float*)d_in[7];
  const float* dgb  = (const float*)d_in[8];
  const float* duW  = (const float*)d_in[9];
  const float* dub  = (const float*)d_in[10];
  const float* pW   = (const float*)d_in[11];
  const float* pb   = (const float*)d_in[12];
  float* out = (float*)d_out;
  float* ws  = (float*)d_ws;

  float* Amat = ws + A_off;
  float* S2   = Amat + (size_t)N * N;
  float* xT   = ws + xT_off;
  float* Px   = ws + Px_off;
  float* yT   = ws + yT_off;
  float* Py   = ws + Py_off;
  float* hmat = ws + h_off;
  float* Ph   = ws + Ph_off;
  float* zh   = ws + zh_off;
  float* rb   = ws + r_off;
  float* gob  = ws + go_off;
  float* Pgo  = ws + Pgo_off;
  unsigned* A2u = (unsigned*)(ws + A2_off);
  const ushort* A2 = (const ushort*)A2u;
  ushort* Bh = (ushort*)(ws + Bh_off);
  ushort* Bz = (ushort*)(ws + Bz_off);

  // ---- precompute ----
  build_A<<<N, 256, 0, stream>>>(emb, Amat);
  gemm_f32<<<dim3(8, 8), 256, 0, stream>>>(Amat, Amat, S2, N, N, N, 1);
  split_A<<<(2048 * 1024) / 256, 256, 0, stream>>>(Amat, A2u);
  transpose_bt<<<(N * T * B + 255) / 256, 256, 0, stream>>>(x, xT);
  transpose_bt<<<(N * T * B + 255) / 256, 256, 0, stream>>>(ycov, yT);
  gemm_f32<<<dim3(6, 16), 256, 0, stream>>>(Amat, xT, Px, 2 * N, N, T * B, 0);
  gemm_f32<<<dim3(6, 16), 256, 0, stream>>>(Amat, yT, Py, 2 * N, N, T * B, 0);
  hipMemsetAsync(hmat, 0, NBH * sizeof(float), stream);
  hipMemsetAsync(Ph, 0, 2 * NBH * sizeof(float), stream);
  hipMemsetAsync(gob, 0, (size_t)N * B * sizeof(float), stream);
  hipMemsetAsync(Bh + 4096ull * 2048, 0, 128ull * 2048 * sizeof(ushort), stream);

  // ---- encoder ----
  for (int t = 0; t < T; ++t) {
    if (t > 0)
      gemm_mfma<<<dim3(32, 16), 256, 0, stream>>>(A2, Bh, Ph, nullptr);
    gate_kernel<1><<<N, 256, 0, stream>>>(hmat, Ph, egW, egb,
                                          xT, Px, T * B, t * B,
                                          nullptr, nullptr, 0, 0, zh, rb, (unsigned*)Bz);
    gemm_mfma<<<dim3(32, 16), 256, 0, stream>>>(A2, Bz, Ph, nullptr);
    upd_kernel<1><<<N, 256, 0, stream>>>(hmat, Ph, zh, euW, eub,
                                         xT, Px, T * B, t * B,
                                         nullptr, nullptr, 0, 0, rb, (unsigned*)Bh);
  }

  // ---- decoder ----
  for (int t = 0; t < HOR; ++t) {
    gemm_mfma<<<dim3(33, 16), 256, 0, stream>>>(A2, Bh, Ph, Pgo);
    gate_kernel<2><<<N, 256, 0, stream>>>(hmat, Ph, dgW, dgb,
                                          gob, Pgo, B, 0,
                                          yT, Py, T * B, t * B, zh, rb, (unsigned*)Bz);
    gemm_mfma<<<dim3(32, 16), 256, 0, stream>>>(A2, Bz, Ph, nullptr);
    upd_kernel<2><<<N, 256, 0, stream>>>(hmat, Ph, zh, duW, dub,
                                         gob, Pgo, B, 0,
                                         yT, Py, T * B, t * B, rb, (unsigned*)Bh);
    proj_kernel<<<N, 256, 0, stream>>>(hmat, pW, pb, gob, out, (unsigned*)Bh, t);
  }
}

// Round 3
// 5385.166 us; speedup vs baseline: 2.5375x; 1.3863x over previous
//
#include <hip/hip_runtime.h>
#include <math.h>

// Problem constants
constexpr int N = 1024, B = 64, T = 12, HOR = 12, H = 64, E = 8;
constexpr size_t NTB = (size_t)N * T * B;
constexpr size_t NBH = (size_t)N * B * H;

// Workspace layout (float units)
constexpr size_t A_off   = 0;                       // [2048][1024] fp32 stacked S=[A;S2]
constexpr size_t xT_off  = 2ull * N * N;            // [1024][768]
constexpr size_t Px_off  = xT_off + NTB;            // [2][1024][768]
constexpr size_t yT_off  = Px_off + 2 * NTB;        // [1024][768]
constexpr size_t Py_off  = yT_off + NTB;            // [2][1024][768]
constexpr size_t h_off   = Py_off + 2 * NTB;        // [1024][4096]
constexpr size_t Ph_off  = h_off + NBH;             // [2][1024][4096] (also Pzh)
constexpr size_t zh_off  = Ph_off + 2 * NBH;        // [1024][4096]
constexpr size_t r_off   = zh_off + NBH;            // [1024][4096]
constexpr size_t go_off  = r_off + NBH;             // [1024][64]
constexpr size_t Pgo_off = go_off + (size_t)N * B;  // [2][1024][64]
constexpr size_t A2_off  = Pgo_off + 2ull * N * B;  // ushort[2048][1024]

typedef __attribute__((ext_vector_type(8))) short short8;
typedef __attribute__((ext_vector_type(4))) float f32x4;

__device__ __forceinline__ unsigned f2bf(float x) {
  unsigned u = __float_as_uint(x);
  return (u + 0x7fffu + ((u >> 16) & 1u)) >> 16;   // RNE
}

// ---------------------------------------------------------------------------
// A = softmax(relu(emb @ emb^T)) row-wise. One block per row.
// ---------------------------------------------------------------------------
__global__ __launch_bounds__(256) void build_A(const float* __restrict__ emb,
                                               float* __restrict__ A) {
  __shared__ float sE[N * E];
  __shared__ float sv[N];
  __shared__ float rmax[4], rsum[4];
  const int i = blockIdx.x;
  for (int idx = threadIdx.x; idx < N * E / 4; idx += 256)
    ((float4*)sE)[idx] = ((const float4*)emb)[idx];
  __syncthreads();
  float ei[E];
#pragma unroll
  for (int e = 0; e < E; ++e) ei[e] = sE[i * E + e];
  float mymax = 0.f;
  for (int j = threadIdx.x; j < N; j += 256) {
    float d = 0.f;
#pragma unroll
    for (int e = 0; e < E; ++e) d = fmaf(ei[e], sE[j * E + e], d);
    d = fmaxf(d, 0.f);
    sv[j] = d;
    mymax = fmaxf(mymax, d);
  }
  for (int off = 32; off; off >>= 1) mymax = fmaxf(mymax, __shfl_down(mymax, off));
  const int wid = threadIdx.x >> 6, lid = threadIdx.x & 63;
  if (lid == 0) rmax[wid] = mymax;
  __syncthreads();
  const float m = fmaxf(fmaxf(rmax[0], rmax[1]), fmaxf(rmax[2], rmax[3]));
  float mysum = 0.f;
  for (int j = threadIdx.x; j < N; j += 256) {
    float ev = expf(sv[j] - m);
    sv[j] = ev;
    mysum += ev;
  }
  for (int off = 32; off; off >>= 1) mysum += __shfl_down(mysum, off);
  if (lid == 0) rsum[wid] = mysum;
  __syncthreads();
  const float inv = 1.f / (rsum[0] + rsum[1] + rsum[2] + rsum[3]);
  for (int j = threadIdx.x; j < N; j += 256) A[i * N + j] = sv[j] * inv;
}

// ---------------------------------------------------------------------------
// fp32 vector GEMM — used ONLY for S2 = 2*A@A - I (exact support precision)
// ---------------------------------------------------------------------------
__global__ __launch_bounds__(256) void gemm_f32(
    const float* __restrict__ Am, const float* __restrict__ Bm,
    float* __restrict__ Cm, int K, int n1, int mode) {
  __shared__ float As[16][132];
  __shared__ float Bs[16][132];
  const int t = threadIdx.x;
  const int bn = blockIdx.x * 128;
  const int bm = blockIdx.y * 128;
  const int tm = (t >> 4) * 8;
  const int tn = (t & 15) * 8;
  float acc[8][8] = {};
  for (int k0 = 0; k0 < K; k0 += 16) {
#pragma unroll
    for (int u = 0; u < 2; ++u) {
      int id = t + u * 256;
      int m = id >> 2;
      int k4 = (id & 3) * 4;
      float4 v = *(const float4*)(Am + (size_t)(bm + m) * K + k0 + k4);
      As[k4 + 0][m] = v.x; As[k4 + 1][m] = v.y;
      As[k4 + 2][m] = v.z; As[k4 + 3][m] = v.w;
    }
#pragma unroll
    for (int u = 0; u < 2; ++u) {
      int id = t + u * 256;
      int kr = id >> 5;
      int c4 = (id & 31) * 4;
      float4 v = *(const float4*)(Bm + (size_t)(k0 + kr) * n1 + bn + c4);
      *(float4*)(&Bs[kr][c4]) = v;
    }
    __syncthreads();
#pragma unroll
    for (int kk = 0; kk < 16; ++kk) {
      float a[8], bf[8];
      *(float4*)(a)      = *(const float4*)(&As[kk][tm]);
      *(float4*)(a + 4)  = *(const float4*)(&As[kk][tm + 4]);
      *(float4*)(bf)     = *(const float4*)(&Bs[kk][tn]);
      *(float4*)(bf + 4) = *(const float4*)(&Bs[kk][tn + 4]);
#pragma unroll
      for (int i = 0; i < 8; ++i)
#pragma unroll
        for (int j = 0; j < 8; ++j)
          acc[i][j] = fmaf(a[i], bf[j], acc[i][j]);
    }
    __syncthreads();
  }
#pragma unroll
  for (int i = 0; i < 8; ++i) {
    int gm = bm + tm + i;
#pragma unroll
    for (int j4 = 0; j4 < 2; ++j4) {
      float4 v = {acc[i][j4 * 4 + 0], acc[i][j4 * 4 + 1],
                  acc[i][j4 * 4 + 2], acc[i][j4 * 4 + 3]};
      int gc = bn + tn + j4 * 4;
      if (mode == 1) {
        v.x = 2.f * v.x - (gm == gc + 0 ? 1.f : 0.f);
        v.y = 2.f * v.y - (gm == gc + 1 ? 1.f : 0.f);
        v.z = 2.f * v.z - (gm == gc + 2 ? 1.f : 0.f);
        v.w = 2.f * v.w - (gm == gc + 3 ? 1.f : 0.f);
      }
      *(float4*)(Cm + (size_t)gm * n1 + gc) = v;
    }
  }
}

// ---------------------------------------------------------------------------
// fp32 -> bf16 bulk convert (for A2 = bf16(stacked S))
// ---------------------------------------------------------------------------
__global__ __launch_bounds__(256) void conv_bf16(const float* __restrict__ src,
                                                 ushort* __restrict__ dst) {
  int i = blockIdx.x * 256 + threadIdx.x;   // over float4s
  float4 v = ((const float4*)src)[i];
  ushort4 o;
  o.x = (ushort)f2bf(v.x); o.y = (ushort)f2bf(v.y);
  o.z = (ushort)f2bf(v.z); o.w = (ushort)f2bf(v.w);
  ((ushort4*)dst)[i] = o;
}

// ---------------------------------------------------------------------------
// Single-bf16 MFMA GEMM with fused fp32->bf16 B-staging.
//   C[M][n1] = bf16(S)[M][1024] @ Bf[1024][n1]   (Bf fp32 row-major)
// Optional fold: col block at bn==n1 reads B2[1024][64] -> C2[M][64].
// 128x128 tile, BK=32, 4 waves, 16x16x32 MFMA. A staged via global_load_lds.
// ---------------------------------------------------------------------------
typedef const __attribute__((address_space(1))) void gas_t;
typedef __attribute__((address_space(3))) void las_t;

__global__ __launch_bounds__(256) void gemm_bf(
    const ushort* __restrict__ A2, const float* __restrict__ Bf, int n1,
    const float* __restrict__ B2, float* __restrict__ C1, float* __restrict__ C2) {
  __shared__ ushort As[128 * 32];   // [m][k], row 64B
  __shared__ ushort Bs[128 * 40];   // [col][k], row 80B (pad 8)
  const int t = threadIdx.x;
  const int wave = t >> 6, lane = t & 63;
  const int bm = blockIdx.y * 128, bn = blockIdx.x * 128;
  const int wm = (wave & 1) * 64, wn = (wave >> 1) * 64;
  const bool inB1 = (bn < n1);

  const ushort* aSrc[2];
  ushort* aDst[2];
#pragma unroll
  for (int u = 0; u < 2; ++u) {
    int idx = wave * 128 + u * 64 + lane;
    int row = idx >> 2;
    int kq = (idx & 3) * 8;
    aSrc[u] = A2 + (size_t)(bm + row) * 1024 + kq;
    aDst[u] = &As[(size_t)(wave * 128 + u * 64) * 8];
  }

  const int c4  = (t & 31) * 4;    // B col within tile (0..124)
  const int dnb = (t >> 5) * 4;    // B k-row base within tile (0..28)

  const int lr = lane & 15;
  const int lk = (lane >> 4) * 8;
  const ushort* aFrag[4]; const ushort* bFrag[4];
#pragma unroll
  for (int i = 0; i < 4; ++i) {
    aFrag[i] = &As[(wm + i * 16 + lr) * 32 + lk];
    bFrag[i] = &Bs[(wn + i * 16 + lr) * 40 + lk];
  }

  f32x4 acc[4][4];
#pragma unroll
  for (int i = 0; i < 4; ++i)
#pragma unroll
    for (int j = 0; j < 4; ++j) acc[i][j] = {0.f, 0.f, 0.f, 0.f};

  for (int k0 = 0; k0 < 1024; k0 += 32) {
#pragma unroll
    for (int u = 0; u < 2; ++u)
      __builtin_amdgcn_global_load_lds((gas_t*)(aSrc[u] + k0), (las_t*)aDst[u], 16, 0, 0);
    // B: load 4 fp32 rows (k-adjacent), convert, transpose into Bs
    float4 bv[4];
#pragma unroll
    for (int p = 0; p < 4; ++p) {
      int kk = k0 + dnb + p;
      if (inB1) {
        bv[p] = *(const float4*)(Bf + (size_t)kk * n1 + bn + c4);
      } else if (c4 < 64) {
        bv[p] = *(const float4*)(B2 + (size_t)kk * 64 + c4);
      } else {
        bv[p] = make_float4(0.f, 0.f, 0.f, 0.f);
      }
    }
#pragma unroll
    for (int j = 0; j < 4; ++j) {
      float v0 = ((const float*)&bv[0])[j];
      float v1 = ((const float*)&bv[1])[j];
      float v2 = ((const float*)&bv[2])[j];
      float v3 = ((const float*)&bv[3])[j];
      uint2 u2;
      u2.x = (f2bf(v0) & 0xffffu) | (f2bf(v1) << 16);
      u2.y = (f2bf(v2) & 0xffffu) | (f2bf(v3) << 16);
      *(uint2*)&Bs[(c4 + j) * 40 + dnb] = u2;
    }
    __syncthreads();
    short8 a[4], b[4];
#pragma unroll
    for (int i = 0; i < 4; ++i) a[i] = *(const short8*)aFrag[i];
#pragma unroll
    for (int j = 0; j < 4; ++j) b[j] = *(const short8*)bFrag[j];
#pragma unroll
    for (int i = 0; i < 4; ++i)
#pragma unroll
      for (int j = 0; j < 4; ++j)
        acc[i][j] = __builtin_amdgcn_mfma_f32_16x16x32_bf16(a[i], b[j], acc[i][j], 0, 0, 0);
    __syncthreads();
  }

  const int cr = (lane >> 4) * 4;
  const int cc = lane & 15;
#pragma unroll
  for (int i = 0; i < 4; ++i) {
#pragma unroll
    for (int j = 0; j < 4; ++j) {
      int gm = bm + wm + i * 16 + cr;
      int gn = bn + wn + j * 16 + cc;
      if (gn < n1) {
        float* p = C1 + (size_t)gm * n1 + gn;
#pragma unroll
        for (int r = 0; r < 4; ++r) p[(size_t)r * n1] = acc[i][j][r];
      } else if (C2 != nullptr && gn < n1 + 64) {
        float* p = C2 + (size_t)gm * 64 + (gn - n1);
#pragma unroll
        for (int r = 0; r < 4; ++r) p[(size_t)r * 64] = acc[i][j][r];
      }
    }
  }
}

// ---------------------------------------------------------------------------
__global__ __launch_bounds__(256) void transpose_bt(const float* __restrict__ src,
                                                    float* __restrict__ dst) {
  int id = blockIdx.x * 256 + threadIdx.x;
  if (id >= N * T * B) return;
  int n = id / (T * B);
  int tb = id % (T * B);
  int tt = tb >> 6, b = tb & 63;
  dst[id] = src[((size_t)b * T + tt) * N + n];
}

// ---------------------------------------------------------------------------
// Gate kernel: zr = sigmoid(gather([x_k, h_k]) @ W + b); writes zh = z*h, r.
// ---------------------------------------------------------------------------
template <int NS>
__global__ __launch_bounds__(256) void gate_kernel(
    const float* __restrict__ hmat, const float* __restrict__ Ph,
    const float* __restrict__ W, const float* __restrict__ bias,
    const float* __restrict__ s0, const float* __restrict__ Ps0, int s0_stride, int s0_off,
    const float* __restrict__ s1, const float* __restrict__ Ps1, int s1_stride, int s1_off,
    float* __restrict__ zh, float* __restrict__ rbuf) {
  const int n = blockIdx.x;
  __shared__ float sh[3][64][65];
  __shared__ float sxs[3][NS][64];
  const float* hps[3] = {hmat + (size_t)n * 4096, Ph + (size_t)n * 4096,
                         Ph + (size_t)1024 * 4096 + (size_t)n * 4096};
#pragma unroll
  for (int p = 0; p < 3; ++p) {
    for (int i = threadIdx.x; i < 1024; i += 256) {
      float4 v = ((const float4*)hps[p])[i];
      int b = i >> 4;
      int c = (i & 15) * 4;
      sh[p][c + 0][b] = v.x; sh[p][c + 1][b] = v.y;
      sh[p][c + 2][b] = v.z; sh[p][c + 3][b] = v.w;
    }
  }
  if (threadIdx.x < 64) {
    int b = threadIdx.x;
    sxs[0][0][b] = s0[(size_t)n * s0_stride + s0_off + b];
    sxs[1][0][b] = Ps0[(size_t)n * s0_stride + s0_off + b];
    sxs[2][0][b] = Ps0[(size_t)1024 * s0_stride + (size_t)n * s0_stride + s0_off + b];
    if (NS == 2) {
      sxs[0][1][b] = s1[(size_t)n * s1_stride + s1_off + b];
      sxs[1][1][b] = Ps1[(size_t)n * s1_stride + s1_off + b];
      sxs[2][1][b] = Ps1[(size_t)1024 * s1_stride + (size_t)n * s1_stride + s1_off + b];
    }
  }
  __syncthreads();
  const int col4 = threadIdx.x & 31;
  const int bgrp = threadIdx.x >> 5;
  const int CIN = NS + 64;
  float acc[8][4] = {};
#pragma unroll
  for (int k = 0; k < 3; ++k) {
    const float* Wk = W + (size_t)k * CIN * 128 + col4 * 4;
#pragma unroll
    for (int s = 0; s < NS; ++s) {
      float4 w = *(const float4*)(Wk + s * 128);
#pragma unroll
      for (int i = 0; i < 8; ++i) {
        float a = sxs[k][s][bgrp + 8 * i];
        acc[i][0] = fmaf(a, w.x, acc[i][0]);
        acc[i][1] = fmaf(a, w.y, acc[i][1]);
        acc[i][2] = fmaf(a, w.z, acc[i][2]);
        acc[i][3] = fmaf(a, w.w, acc[i][3]);
      }
    }
    const float* Wh = Wk + NS * 128;
    for (int c = 0; c < 64; ++c) {
      float4 w = *(const float4*)(Wh + c * 128);
#pragma unroll
      for (int i = 0; i < 8; ++i) {
        float a = sh[k][c][bgrp + 8 * i];
        acc[i][0] = fmaf(a, w.x, acc[i][0]);
        acc[i][1] = fmaf(a, w.y, acc[i][1]);
        acc[i][2] = fmaf(a, w.z, acc[i][2]);
        acc[i][3] = fmaf(a, w.w, acc[i][3]);
      }
    }
  }
  const int col = col4 * 4;
  float4 bv = *(const float4*)(bias + col);
  const float bb4[4] = {bv.x, bv.y, bv.z, bv.w};
#pragma unroll
  for (int i = 0; i < 8; ++i) {
    int b = bgrp + 8 * i;
    float v[4];
#pragma unroll
    for (int j = 0; j < 4; ++j) {
      float xx = acc[i][j] + bb4[j];
      v[j] = 1.f / (1.f + expf(-xx));
    }
    if (col < 64) {
      float4 o;
      o.x = v[0] * sh[0][col + 0][b];
      o.y = v[1] * sh[0][col + 1][b];
      o.z = v[2] * sh[0][col + 2][b];
      o.w = v[3] * sh[0][col + 3][b];
      *(float4*)(zh + (size_t)n * 4096 + b * 64 + col) = o;
    } else {
      float4 o = {v[0], v[1], v[2], v[3]};
      *(float4*)(rbuf + (size_t)n * 4096 + b * 64 + (col - 64)) = o;
    }
  }
}

// ---------------------------------------------------------------------------
// Update kernel: hc = tanh(gather([x_k, zh_k]) @ W + b); h = r*h + (1-r)*hc
// ---------------------------------------------------------------------------
template <int NS>
__global__ __launch_bounds__(256) void upd_kernel(
    float* __restrict__ hmat, const float* __restrict__ Pzh, const float* __restrict__ zhb,
    const float* __restrict__ W, const float* __restrict__ bias,
    const float* __restrict__ s0, const float* __restrict__ Ps0, int s0_stride, int s0_off,
    const float* __restrict__ s1, const float* __restrict__ Ps1, int s1_stride, int s1_off,
    const float* __restrict__ rbuf) {
  const int n = blockIdx.x;
  __shared__ float sh[3][64][65];
  __shared__ float sxs[3][NS][64];
  const float* hps[3] = {zhb + (size_t)n * 4096, Pzh + (size_t)n * 4096,
                         Pzh + (size_t)1024 * 4096 + (size_t)n * 4096};
#pragma unroll
  for (int p = 0; p < 3; ++p) {
    for (int i = threadIdx.x; i < 1024; i += 256) {
      float4 v = ((const float4*)hps[p])[i];
      int b = i >> 4;
      int c = (i & 15) * 4;
      sh[p][c + 0][b] = v.x; sh[p][c + 1][b] = v.y;
      sh[p][c + 2][b] = v.z; sh[p][c + 3][b] = v.w;
    }
  }
  if (threadIdx.x < 64) {
    int b = threadIdx.x;
    sxs[0][0][b] = s0[(size_t)n * s0_stride + s0_off + b];
    sxs[1][0][b] = Ps0[(size_t)n * s0_stride + s0_off + b];
    sxs[2][0][b] = Ps0[(size_t)1024 * s0_stride + (size_t)n * s0_stride + s0_off + b];
    if (NS == 2) {
      sxs[0][1][b] = s1[(size_t)n * s1_stride + s1_off + b];
      sxs[1][1][b] = Ps1[(size_t)n * s1_stride + s1_off + b];
      sxs[2][1][b] = Ps1[(size_t)1024 * s1_stride + (size_t)n * s1_stride + s1_off + b];
    }
  }
  __syncthreads();
  const int col4 = threadIdx.x & 15;
  const int bgrp = threadIdx.x >> 4;
  const int CIN = NS + 64;
  float acc[4][4] = {};
#pragma unroll
  for (int k = 0; k < 3; ++k) {
    const float* Wk = W + (size_t)k * CIN * 64 + col4 * 4;
#pragma unroll
    for (int s = 0; s < NS; ++s) {
      float4 w = *(const float4*)(Wk + s * 64);
#pragma unroll
      for (int i = 0; i < 4; ++i) {
        float a = sxs[k][s][bgrp + 16 * i];
        acc[i][0] = fmaf(a, w.x, acc[i][0]);
        acc[i][1] = fmaf(a, w.y, acc[i][1]);
        acc[i][2] = fmaf(a, w.z, acc[i][2]);
        acc[i][3] = fmaf(a, w.w, acc[i][3]);
      }
    }
    const float* Wh = Wk + NS * 64;
    for (int c = 0; c < 64; ++c) {
      float4 w = *(const float4*)(Wh + c * 64);
#pragma unroll
      for (int i = 0; i < 4; ++i) {
        float a = sh[k][c][bgrp + 16 * i];
        acc[i][0] = fmaf(a, w.x, acc[i][0]);
        acc[i][1] = fmaf(a, w.y, acc[i][1]);
        acc[i][2] = fmaf(a, w.z, acc[i][2]);
        acc[i][3] = fmaf(a, w.w, acc[i][3]);
      }
    }
  }
  const int col = col4 * 4;
  float4 bv = *(const float4*)(bias + col);
#pragma unroll
  for (int i = 0; i < 4; ++i) {
    int b = bgrp + 16 * i;
    float hc0 = tanhf(acc[i][0] + bv.x);
    float hc1 = tanhf(acc[i][1] + bv.y);
    float hc2 = tanhf(acc[i][2] + bv.z);
    float hc3 = tanhf(acc[i][3] + bv.w);
    size_t idx = (size_t)n * 4096 + b * 64 + col;
    float4 r4 = *(const float4*)(rbuf + idx);
    float4 h4 = *(const float4*)(hmat + idx);
    float4 o;
    o.x = r4.x * h4.x + (1.f - r4.x) * hc0;
    o.y = r4.y * h4.y + (1.f - r4.y) * hc1;
    o.z = r4.z * h4.z + (1.f - r4.z) * hc2;
    o.w = r4.w * h4.w + (1.f - r4.w) * hc3;
    *(float4*)(hmat + idx) = o;
  }
}

// ---------------------------------------------------------------------------
__global__ __launch_bounds__(256) void proj_kernel(
    const float* __restrict__ hmat, const float* __restrict__ pW,
    const float* __restrict__ pb, float* __restrict__ gobuf,
    float* __restrict__ out, int tstep) {
  const int n = blockIdx.x;
  const int b = threadIdx.x & 63;
  const int q = threadIdx.x >> 6;
  __shared__ float sW[64];
  __shared__ float part[4][64];
  if (threadIdx.x < 64) sW[threadIdx.x] = pW[threadIdx.x];
  __syncthreads();
  const float* hp = hmat + (size_t)n * 4096 + b * 64 + q * 16;
  float sum = 0.f;
#pragma unroll
  for (int j = 0; j < 16; ++j) sum = fmaf(hp[j], sW[q * 16 + j], sum);
  part[q][b] = sum;
  __syncthreads();
  if (threadIdx.x < 64) {
    int bb = threadIdx.x;
    float g = part[0][bb] + part[1][bb] + part[2][bb] + part[3][bb] + pb[0];
    gobuf[(size_t)n * 64 + bb] = g;
    out[((size_t)bb * HOR + tstep) * N + n] = g;
  }
}

// ---------------------------------------------------------------------------
extern "C" void kernel_launch(void* const* d_in, const int* in_sizes, int n_in,
                              void* d_out, int out_size, void* d_ws, size_t ws_size,
                              hipStream_t stream) {
  const float* x    = (const float*)d_in[0];
  const float* ycov = (const float*)d_in[1];
  const float* emb  = (const float*)d_in[2];
  const float* egW  = (const float*)d_in[3];
  const float* egb  = (const float*)d_in[4];
  const float* euW  = (const float*)d_in[5];
  const float* eub  = (const float*)d_in[6];
  const float* dgW  = (const float*)d_in[7];
  const float* dgb  = (const float*)d_in[8];
  const float* duW  = (const float*)d_in[9];
  const float* dub  = (const float*)d_in[10];
  const float* pW   = (const float*)d_in[11];
  const float* pb   = (const float*)d_in[12];
  float* out = (float*)d_out;
  float* ws  = (float*)d_ws;

  float* Amat = ws + A_off;
  float* S2   = Amat + (size_t)N * N;
  float* xT   = ws + xT_off;
  float* Px   = ws + Px_off;
  float* yT   = ws + yT_off;
  float* Py   = ws + Py_off;
  float* hmat = ws + h_off;
  float* Ph   = ws + Ph_off;
  float* zh   = ws + zh_off;
  float* rb   = ws + r_off;
  float* gob  = ws + go_off;
  float* Pgo  = ws + Pgo_off;
  ushort* A2  = (ushort*)(ws + A2_off);   // bf16(stacked S) [2048][1024]

  // ---- precompute ----
  build_A<<<N, 256, 0, stream>>>(emb, Amat);
  gemm_f32<<<dim3(8, 8), 256, 0, stream>>>(Amat, Amat, S2, N, N, 1);
  conv_bf16<<<(2 * N * N / 4) / 256, 256, 0, stream>>>(Amat, A2);  // A + S2
  transpose_bt<<<(N * T * B + 255) / 256, 256, 0, stream>>>(x, xT);
  transpose_bt<<<(N * T * B + 255) / 256, 256, 0, stream>>>(ycov, yT);
  gemm_bf<<<dim3(6, 16), 256, 0, stream>>>(A2, xT, T * B, nullptr, Px, nullptr);
  gemm_bf<<<dim3(6, 16), 256, 0, stream>>>(A2, yT, T * B, nullptr, Py, nullptr);
  hipMemsetAsync(hmat, 0, NBH * sizeof(float), stream);
  hipMemsetAsync(Ph, 0, 2 * NBH * sizeof(float), stream);
  hipMemsetAsync(gob, 0, (size_t)N * B * sizeof(float), stream);

  // ---- encoder ----
  for (int t = 0; t < T; ++t) {
    if (t > 0)  // t=0: h=0 so Ph=0 (memset above)
      gemm_bf<<<dim3(32, 16), 256, 0, stream>>>(A2, hmat, B * H, nullptr, Ph, nullptr);
    gate_kernel<1><<<N, 256, 0, stream>>>(hmat, Ph, egW, egb,
                                          xT, Px, T * B, t * B,
                                          nullptr, nullptr, 0, 0, zh, rb);
    gemm_bf<<<dim3(32, 16), 256, 0, stream>>>(A2, zh, B * H, nullptr, Ph, nullptr);
    upd_kernel<1><<<N, 256, 0, stream>>>(hmat, Ph, zh, euW, eub,
                                         xT, Px, T * B, t * B,
                                         nullptr, nullptr, 0, 0, rb);
  }

  // ---- decoder ----
  for (int t = 0; t < HOR; ++t) {
    // h-propagation with go-propagation folded in (33rd column block)
    gemm_bf<<<dim3(33, 16), 256, 0, stream>>>(A2, hmat, B * H, gob, Ph, Pgo);
    gate_kernel<2><<<N, 256, 0, stream>>>(hmat, Ph, dgW, dgb,
                                          gob, Pgo, B, 0,
                                          yT, Py, T * B, t * B, zh, rb);
    gemm_bf<<<dim3(32, 16), 256, 0, stream>>>(A2, zh, B * H, nullptr, Ph, nullptr);
    upd_kernel<2><<<N, 256, 0, stream>>>(hmat, Ph, zh, duW, dub,
                                         gob, Pgo, B, 0,
                                         yT, Py, T * B, t * B, rb);
    proj_kernel<<<N, 256, 0, stream>>>(hmat, pW, pb, gob, out, t);
  }
}

// Round 5
// 4510.990 us; speedup vs baseline: 3.0292x; 1.1938x over previous
//
#include <hip/hip_runtime.h>
#include <math.h>

// Problem constants
constexpr int N = 1024, B = 64, T = 12, HOR = 12, H = 64, E = 8;
constexpr size_t NBH = (size_t)N * B * H;

// Workspace layout (float units)
constexpr size_t A_off   = 0;                           // [2048][1024] fp32 stacked S=[A;S2]
constexpr size_t xy_off  = 2ull * N * N;                // [1024][1536]  (xT | yT)
constexpr size_t Pxy_off = xy_off + (size_t)N * 1536;   // [2][1024][1536]
constexpr size_t h_off   = Pxy_off + 2ull * N * 1536;   // [1024][4096]
constexpr size_t Ph_off  = h_off + NBH;                 // [2][1024][4096] (also Pzh)
constexpr size_t zh_off  = Ph_off + 2 * NBH;            // [1024][4096] (precompute: AspL alias)
constexpr size_t r_off   = zh_off + NBH;                // [1024][4096] (precompute: AspR alias)
constexpr size_t go_off  = r_off + NBH;                 // [1024][64]
constexpr size_t Pgo_off = go_off + (size_t)N * B;      // [2][1024][64]
constexpr size_t A2_off  = Pgo_off + 2ull * N * B;      // ushort[2048][1024]

typedef __attribute__((ext_vector_type(8))) short short8;
typedef __attribute__((ext_vector_type(4))) float f32x4;

__device__ __forceinline__ unsigned f2bf(float x) {
  unsigned u = __float_as_uint(x);
  return (u + 0x7fffu + ((u >> 16) & 1u)) >> 16;   // RNE
}
__device__ __forceinline__ float bf2f(unsigned h) {
  return __uint_as_float(h << 16);
}
__device__ __forceinline__ unsigned pk2bf(float a, float b) {
  return (f2bf(a) & 0xffffu) | (f2bf(b) << 16);    // a -> low16, b -> high16
}

// ---------------------------------------------------------------------------
// A = softmax(relu(emb @ emb^T)) row-wise. One block per row.
// ---------------------------------------------------------------------------
__global__ __launch_bounds__(256) void build_A(const float* __restrict__ emb,
                                               float* __restrict__ A) {
  __shared__ float sE[N * E];
  __shared__ float sv[N];
  __shared__ float rmax[4], rsum[4];
  const int i = blockIdx.x;
  for (int idx = threadIdx.x; idx < N * E / 4; idx += 256)
    ((float4*)sE)[idx] = ((const float4*)emb)[idx];
  __syncthreads();
  float ei[E];
#pragma unroll
  for (int e = 0; e < E; ++e) ei[e] = sE[i * E + e];
  float mymax = 0.f;
  for (int j = threadIdx.x; j < N; j += 256) {
    float d = 0.f;
#pragma unroll
    for (int e = 0; e < E; ++e) d = fmaf(ei[e], sE[j * E + e], d);
    d = fmaxf(d, 0.f);
    sv[j] = d;
    mymax = fmaxf(mymax, d);
  }
  for (int off = 32; off; off >>= 1) mymax = fmaxf(mymax, __shfl_down(mymax, off));
  const int wid = threadIdx.x >> 6, lid = threadIdx.x & 63;
  if (lid == 0) rmax[wid] = mymax;
  __syncthreads();
  const float m = fmaxf(fmaxf(rmax[0], rmax[1]), fmaxf(rmax[2], rmax[3]));
  float mysum = 0.f;
  for (int j = threadIdx.x; j < N; j += 256) {
    float ev = expf(sv[j] - m);
    sv[j] = ev;
    mysum += ev;
  }
  for (int off = 32; off; off >>= 1) mysum += __shfl_down(mysum, off);
  if (lid == 0) rsum[wid] = mysum;
  __syncthreads();
  const float inv = 1.f / (rsum[0] + rsum[1] + rsum[2] + rsum[3]);
  for (int j = threadIdx.x; j < N; j += 256) A[i * N + j] = sv[j] * inv;
}

// ---------------------------------------------------------------------------
// Split-pack A for the exact S2 gemm.
//  L[m][3j+{0,1,2}] = (hi,lo,hi) of A[m][j]      (left operand, K-major rows)
//  R[c][3j+{0,1,2}] = (hi,hi,lo) of A[j][c]      (right operand, K-major cols)
// => sum over 3j of L*R = hi*hi + lo*hi + hi*lo  (fp32-quality product)
// ---------------------------------------------------------------------------
__global__ __launch_bounds__(256) void pack_split_S(const float* __restrict__ A,
                                                    ushort* __restrict__ L,
                                                    ushort* __restrict__ R) {
  __shared__ float tile[32][33];
  const int bx = blockIdx.x * 32;   // j range
  const int by = blockIdx.y * 32;   // m range
  const int tx = threadIdx.x & 31;
  const int tg = threadIdx.x >> 5;  // 0..7
#pragma unroll
  for (int p = 0; p < 4; ++p) {
    int ty = tg * 4 + p;
    tile[ty][tx] = A[(size_t)(by + ty) * 1024 + bx + tx];
  }
  __syncthreads();
#pragma unroll
  for (int p = 0; p < 4; ++p) {
    int ty = tg * 4 + p;
    // L: m = by+ty, j = bx+tx
    float v = tile[ty][tx];
    unsigned h = f2bf(v);
    unsigned l = f2bf(v - bf2f(h));
    size_t lb = (size_t)(by + ty) * 3072 + 3 * (bx + tx);
    L[lb + 0] = (ushort)h; L[lb + 1] = (ushort)l; L[lb + 2] = (ushort)h;
    // R: c = bx+ty, j = by+tx ; value A[j][c] = tile[tx][ty]
    float w = tile[tx][ty];
    unsigned hh = f2bf(w);
    unsigned ll = f2bf(w - bf2f(hh));
    size_t rbi = (size_t)(bx + ty) * 3072 + 3 * (by + tx);
    R[rbi + 0] = (ushort)hh; R[rbi + 1] = (ushort)hh; R[rbi + 2] = (ushort)ll;
  }
}

// ---------------------------------------------------------------------------
// fp32 -> bf16 bulk convert (A2 = bf16(stacked S))
// ---------------------------------------------------------------------------
__global__ __launch_bounds__(256) void conv_bf16(const float* __restrict__ src,
                                                 ushort* __restrict__ dst) {
  int i = blockIdx.x * 256 + threadIdx.x;   // over float4s
  float4 v = ((const float4*)src)[i];
  ushort4 o;
  o.x = (ushort)f2bf(v.x); o.y = (ushort)f2bf(v.y);
  o.z = (ushort)f2bf(v.z); o.w = (ushort)f2bf(v.w);
  ((ushort4*)dst)[i] = o;
}

typedef const __attribute__((address_space(1))) void gas_t;
typedef __attribute__((address_space(3))) void las_t;

// ---------------------------------------------------------------------------
// S2 = 2*A@A - I via split-bf16 MFMA (K=3072 interleaved, fp32-quality).
// ---------------------------------------------------------------------------
__global__ __launch_bounds__(256) void gemm_s2(
    const ushort* __restrict__ L, const ushort* __restrict__ R,
    float* __restrict__ S2) {
  __shared__ ushort As[128 * 32];
  __shared__ ushort Bs[128 * 32];
  const int t = threadIdx.x;
  const int wave = t >> 6, lane = t & 63;
  const int bm = blockIdx.y * 128, bn = blockIdx.x * 128;
  const int wm = (wave & 1) * 64, wn = (wave >> 1) * 64;

  const ushort* aSrc[2]; const ushort* bSrc[2];
  ushort* aDst[2]; ushort* bDst[2];
#pragma unroll
  for (int u = 0; u < 2; ++u) {
    int idx = wave * 128 + u * 64 + lane;
    int row = idx >> 2;
    int kq = (idx & 3) * 8;
    aSrc[u] = L + (size_t)(bm + row) * 3072 + kq;
    bSrc[u] = R + (size_t)(bn + row) * 3072 + kq;
    aDst[u] = &As[(wave * 128 + u * 64) * 8];
    bDst[u] = &Bs[(wave * 128 + u * 64) * 8];
  }
  const int lr = lane & 15;
  const int lk = (lane >> 4) * 8;
  f32x4 acc[4][4];
#pragma unroll
  for (int i = 0; i < 4; ++i)
#pragma unroll
    for (int j = 0; j < 4; ++j) acc[i][j] = {0.f, 0.f, 0.f, 0.f};

  for (int k0 = 0; k0 < 3072; k0 += 32) {
#pragma unroll
    for (int u = 0; u < 2; ++u) {
      __builtin_amdgcn_global_load_lds((gas_t*)(aSrc[u] + k0), (las_t*)aDst[u], 16, 0, 0);
      __builtin_amdgcn_global_load_lds((gas_t*)(bSrc[u] + k0), (las_t*)bDst[u], 16, 0, 0);
    }
    __syncthreads();
    short8 a[4], b[4];
#pragma unroll
    for (int i = 0; i < 4; ++i) a[i] = *(const short8*)&As[(wm + i * 16 + lr) * 32 + lk];
#pragma unroll
    for (int j = 0; j < 4; ++j) b[j] = *(const short8*)&Bs[(wn + j * 16 + lr) * 32 + lk];
#pragma unroll
    for (int i = 0; i < 4; ++i)
#pragma unroll
      for (int j = 0; j < 4; ++j)
        acc[i][j] = __builtin_amdgcn_mfma_f32_16x16x32_bf16(a[i], b[j], acc[i][j], 0, 0, 0);
    __syncthreads();
  }
  const int cr = (lane >> 4) * 4;
  const int cc = lane & 15;
#pragma unroll
  for (int i = 0; i < 4; ++i) {
#pragma unroll
    for (int j = 0; j < 4; ++j) {
      int gm = bm + wm + i * 16 + cr;
      int gn = bn + wn + j * 16 + cc;
#pragma unroll
      for (int r = 0; r < 4; ++r) {
        float v = 2.f * acc[i][j][r] - ((gm + r) == gn ? 1.f : 0.f);
        S2[(size_t)(gm + r) * 1024 + gn] = v;
      }
    }
  }
}

// ---------------------------------------------------------------------------
// Propagation GEMM: C[2048][n1(+64)] = bf16(S)[2048][1024] @ Bf[1024][n1]
// BK=64 as two 32-k panels. B fp32 row-major, converted in-flight.
// Fold: col block at bn==n1 reads B2[1024][64] -> C2. A via global_load_lds.
// ---------------------------------------------------------------------------
__global__ __launch_bounds__(256) void gemm_bf(
    const ushort* __restrict__ A2, const float* __restrict__ Bf, int n1,
    const float* __restrict__ B2, float* __restrict__ C1, float* __restrict__ C2) {
  __shared__ ushort As[2][128 * 32];   // [panel][m][32k], row 64 B
  __shared__ ushort Bs[2][128 * 40];   // [panel][col][32k+8pad], row 80 B
  const int t = threadIdx.x;
  const int wave = t >> 6, lane = t & 63;
  const int bm = blockIdx.y * 128, bn = blockIdx.x * 128;
  const int wm = (wave & 1) * 64, wn = (wave >> 1) * 64;
  const bool inB1 = (bn < n1);

  const ushort* aSrc[2];
  ushort* aDst[2][2];
#pragma unroll
  for (int u = 0; u < 2; ++u) {
    int idx = wave * 128 + u * 64 + lane;
    int row = idx >> 2;
    int kq = (idx & 3) * 8;
    aSrc[u] = A2 + (size_t)(bm + row) * 1024 + kq;
    aDst[0][u] = &As[0][(wave * 128 + u * 64) * 8];
    aDst[1][u] = &As[1][(wave * 128 + u * 64) * 8];
  }

  // B staging: thread covers 4 cols (c4..c4+3) x 8 k (kb..kb+7)
  const int c4 = (t & 31) * 4;
  const int kb = (t >> 5) * 8;          // 0..56
  const int bp = kb >> 5;               // panel
  const int kbl = kb & 31;
  const float* bBase = nullptr;
  int bStride = 0;
  if (inB1) { bBase = Bf + bn + c4; bStride = n1; }
  else if (c4 < 64) { bBase = B2 + c4; bStride = 64; }

  const int lr = lane & 15;
  const int lk = (lane >> 4) * 8;
  int aOff[4], bOff[4];
#pragma unroll
  for (int i = 0; i < 4; ++i) {
    aOff[i] = (wm + i * 16 + lr) * 32 + lk;
    bOff[i] = (wn + i * 16 + lr) * 40 + lk;
  }

  f32x4 acc[4][4];
#pragma unroll
  for (int i = 0; i < 4; ++i)
#pragma unroll
    for (int j = 0; j < 4; ++j) acc[i][j] = {0.f, 0.f, 0.f, 0.f};

  for (int k0 = 0; k0 < 1024; k0 += 64) {
#pragma unroll
    for (int p = 0; p < 2; ++p)
#pragma unroll
      for (int u = 0; u < 2; ++u)
        __builtin_amdgcn_global_load_lds((gas_t*)(aSrc[u] + k0 + p * 32),
                                         (las_t*)aDst[p][u], 16, 0, 0);
    float4 bv[8];
    if (bBase) {
#pragma unroll
      for (int p = 0; p < 8; ++p)
        bv[p] = *(const float4*)(bBase + (size_t)(k0 + kb + p) * bStride);
    } else {
#pragma unroll
      for (int p = 0; p < 8; ++p) bv[p] = make_float4(0.f, 0.f, 0.f, 0.f);
    }
#pragma unroll
    for (int j = 0; j < 4; ++j) {
      uint4 w;
      w.x = pk2bf(((const float*)&bv[0])[j], ((const float*)&bv[1])[j]);
      w.y = pk2bf(((const float*)&bv[2])[j], ((const float*)&bv[3])[j]);
      w.z = pk2bf(((const float*)&bv[4])[j], ((const float*)&bv[5])[j]);
      w.w = pk2bf(((const float*)&bv[6])[j], ((const float*)&bv[7])[j]);
      *(uint4*)&Bs[bp][(c4 + j) * 40 + kbl] = w;
    }
    __syncthreads();
#pragma unroll
    for (int p = 0; p < 2; ++p) {
      short8 a[4], b[4];
#pragma unroll
      for (int i = 0; i < 4; ++i) a[i] = *(const short8*)&As[p][aOff[i]];
#pragma unroll
      for (int j = 0; j < 4; ++j) b[j] = *(const short8*)&Bs[p][bOff[j]];
#pragma unroll
      for (int i = 0; i < 4; ++i)
#pragma unroll
        for (int j = 0; j < 4; ++j)
          acc[i][j] = __builtin_amdgcn_mfma_f32_16x16x32_bf16(a[i], b[j], acc[i][j], 0, 0, 0);
    }
    __syncthreads();
  }

  const int cr = (lane >> 4) * 4;
  const int cc = lane & 15;
#pragma unroll
  for (int i = 0; i < 4; ++i) {
#pragma unroll
    for (int j = 0; j < 4; ++j) {
      int gm = bm + wm + i * 16 + cr;
      int gn = bn + wn + j * 16 + cc;
      if (gn < n1) {
        float* p = C1 + (size_t)gm * n1 + gn;
#pragma unroll
        for (int r = 0; r < 4; ++r) p[(size_t)r * n1] = acc[i][j][r];
      } else if (C2 != nullptr && gn < n1 + 64) {
        float* p = C2 + (size_t)gm * 64 + (gn - n1);
#pragma unroll
        for (int r = 0; r < 4; ++r) p[(size_t)r * 64] = acc[i][j][r];
      }
    }
  }
}

// ---------------------------------------------------------------------------
// Transpose src[b][t][n] -> dst[n][off + t*64 + b]  (dst row pitch 1536)
// ---------------------------------------------------------------------------
__global__ __launch_bounds__(256) void transpose_bt(const float* __restrict__ src,
                                                    float* __restrict__ dst, int off) {
  int id = blockIdx.x * 256 + threadIdx.x;
  if (id >= N * T * B) return;
  int n = id / (T * B);
  int tb = id % (T * B);
  int tt = tb >> 6, b = tb & 63;
  dst[(size_t)n * 1536 + off + tb] = src[((size_t)b * T + tt) * N + n];
}

// ---------------------------------------------------------------------------
// Gate kernel: zr = sigmoid(gather([x_k, h_k]) @ W + b); writes zh = z*h, r.
// ---------------------------------------------------------------------------
template <int NS>
__global__ __launch_bounds__(256) void gate_kernel(
    const float* __restrict__ hmat, const float* __restrict__ Ph,
    const float* __restrict__ W, const float* __restrict__ bias,
    const float* __restrict__ s0, const float* __restrict__ Ps0, int s0_stride, int s0_off,
    const float* __restrict__ s1, const float* __restrict__ Ps1, int s1_stride, int s1_off,
    float* __restrict__ zh, float* __restrict__ rbuf) {
  const int n = blockIdx.x;
  __shared__ float sh[3][64][65];
  __shared__ float sxs[3][2][64];
  const float* hps[3] = {hmat + (size_t)n * 4096, Ph + (size_t)n * 4096,
                         Ph + (size_t)1024 * 4096 + (size_t)n * 4096};
#pragma unroll
  for (int p = 0; p < 3; ++p) {
    for (int i = threadIdx.x; i < 1024; i += 256) {
      float4 v = ((const float4*)hps[p])[i];
      int b = i >> 4;
      int c = (i & 15) * 4;
      sh[p][c + 0][b] = v.x; sh[p][c + 1][b] = v.y;
      sh[p][c + 2][b] = v.z; sh[p][c + 3][b] = v.w;
    }
  }
  if (threadIdx.x < 64) {
    int b = threadIdx.x;
    sxs[0][0][b] = s0[(size_t)n * s0_stride + s0_off + b];
    sxs[1][0][b] = Ps0[(size_t)n * s0_stride + s0_off + b];
    sxs[2][0][b] = Ps0[(size_t)1024 * s0_stride + (size_t)n * s0_stride + s0_off + b];
    if (NS == 2) {
      sxs[0][1][b] = s1[(size_t)n * s1_stride + s1_off + b];
      sxs[1][1][b] = Ps1[(size_t)n * s1_stride + s1_off + b];
      sxs[2][1][b] = Ps1[(size_t)1024 * s1_stride + (size_t)n * s1_stride + s1_off + b];
    }
  }
  __syncthreads();
  const int col4 = threadIdx.x & 31;
  const int bgrp = threadIdx.x >> 5;
  const int CIN = NS + 64;
  float acc[8][4] = {};
#pragma unroll
  for (int k = 0; k < 3; ++k) {
    const float* Wk = W + (size_t)k * CIN * 128 + col4 * 4;
#pragma unroll
    for (int s = 0; s < NS; ++s) {
      float4 w = *(const float4*)(Wk + s * 128);
#pragma unroll
      for (int i = 0; i < 8; ++i) {
        float a = sxs[k][s][bgrp + 8 * i];
        acc[i][0] = fmaf(a, w.x, acc[i][0]);
        acc[i][1] = fmaf(a, w.y, acc[i][1]);
        acc[i][2] = fmaf(a, w.z, acc[i][2]);
        acc[i][3] = fmaf(a, w.w, acc[i][3]);
      }
    }
    const float* Wh = Wk + NS * 128;
    for (int c = 0; c < 64; ++c) {
      float4 w = *(const float4*)(Wh + c * 128);
#pragma unroll
      for (int i = 0; i < 8; ++i) {
        float a = sh[k][c][bgrp + 8 * i];
        acc[i][0] = fmaf(a, w.x, acc[i][0]);
        acc[i][1] = fmaf(a, w.y, acc[i][1]);
        acc[i][2] = fmaf(a, w.z, acc[i][2]);
        acc[i][3] = fmaf(a, w.w, acc[i][3]);
      }
    }
  }
  const int col = col4 * 4;
  float4 bv = *(const float4*)(bias + col);
  const float bb4[4] = {bv.x, bv.y, bv.z, bv.w};
#pragma unroll
  for (int i = 0; i < 8; ++i) {
    int b = bgrp + 8 * i;
    float v[4];
#pragma unroll
    for (int j = 0; j < 4; ++j) {
      float xx = acc[i][j] + bb4[j];
      v[j] = 1.f / (1.f + expf(-xx));
    }
    if (col < 64) {
      float4 o;
      o.x = v[0] * sh[0][col + 0][b];
      o.y = v[1] * sh[0][col + 1][b];
      o.z = v[2] * sh[0][col + 2][b];
      o.w = v[3] * sh[0][col + 3][b];
      *(float4*)(zh + (size_t)n * 4096 + b * 64 + col) = o;
    } else {
      float4 o = {v[0], v[1], v[2], v[3]};
      *(float4*)(rbuf + (size_t)n * 4096 + b * 64 + (col - 64)) = o;
    }
  }
}

// ---------------------------------------------------------------------------
// Update kernel: hc = tanh(gather([x_k, zh_k]) @ W + b); h = r*h + (1-r)*hc
// PROJ=1 fuses go = h @ proj_W + pb (shuffle-reduce) and writes out + gobuf.
// ---------------------------------------------------------------------------
template <int NS, int PROJ>
__global__ __launch_bounds__(256) void upd_kernel(
    float* __restrict__ hmat, const float* __restrict__ Pzh, const float* __restrict__ zhb,
    const float* __restrict__ W, const float* __restrict__ bias,
    const float* __restrict__ s0, const float* __restrict__ Ps0, int s0_stride, int s0_off,
    const float* __restrict__ s1, const float* __restrict__ Ps1, int s1_stride, int s1_off,
    const float* __restrict__ rbuf,
    const float* __restrict__ pW, const float* __restrict__ pb,
    float* __restrict__ gobuf, float* __restrict__ outp, int tstep) {
  const int n = blockIdx.x;
  __shared__ float sh[3][64][65];
  __shared__ float sxs[3][2][64];
  const float* hps[3] = {zhb + (size_t)n * 4096, Pzh + (size_t)n * 4096,
                         Pzh + (size_t)1024 * 4096 + (size_t)n * 4096};
#pragma unroll
  for (int p = 0; p < 3; ++p) {
    for (int i = threadIdx.x; i < 1024; i += 256) {
      float4 v = ((const float4*)hps[p])[i];
      int b = i >> 4;
      int c = (i & 15) * 4;
      sh[p][c + 0][b] = v.x; sh[p][c + 1][b] = v.y;
      sh[p][c + 2][b] = v.z; sh[p][c + 3][b] = v.w;
    }
  }
  if (threadIdx.x < 64) {
    int b = threadIdx.x;
    sxs[0][0][b] = s0[(size_t)n * s0_stride + s0_off + b];
    sxs[1][0][b] = Ps0[(size_t)n * s0_stride + s0_off + b];
    sxs[2][0][b] = Ps0[(size_t)1024 * s0_stride + (size_t)n * s0_stride + s0_off + b];
    if (NS == 2) {
      sxs[0][1][b] = s1[(size_t)n * s1_stride + s1_off + b];
      sxs[1][1][b] = Ps1[(size_t)n * s1_stride + s1_off + b];
      sxs[2][1][b] = Ps1[(size_t)1024 * s1_stride + (size_t)n * s1_stride + s1_off + b];
    }
  }
  __syncthreads();
  const int col4 = threadIdx.x & 15;
  const int bgrp = threadIdx.x >> 4;
  const int CIN = NS + 64;
  float acc[4][4] = {};
#pragma unroll
  for (int k = 0; k < 3; ++k) {
    const float* Wk = W + (size_t)k * CIN * 64 + col4 * 4;
#pragma unroll
    for (int s = 0; s < NS; ++s) {
      float4 w = *(const float4*)(Wk + s * 64);
#pragma unroll
      for (int i = 0; i < 4; ++i) {
        float a = sxs[k][s][bgrp + 16 * i];
        acc[i][0] = fmaf(a, w.x, acc[i][0]);
        acc[i][1] = fmaf(a, w.y, acc[i][1]);
        acc[i][2] = fmaf(a, w.z, acc[i][2]);
        acc[i][3] = fmaf(a, w.w, acc[i][3]);
      }
    }
    const float* Wh = Wk + NS * 64;
    for (int c = 0; c < 64; ++c) {
      float4 w = *(const float4*)(Wh + c * 64);
#pragma unroll
      for (int i = 0; i < 4; ++i) {
        float a = sh[k][c][bgrp + 16 * i];
        acc[i][0] = fmaf(a, w.x, acc[i][0]);
        acc[i][1] = fmaf(a, w.y, acc[i][1]);
        acc[i][2] = fmaf(a, w.z, acc[i][2]);
        acc[i][3] = fmaf(a, w.w, acc[i][3]);
      }
    }
  }
  const int col = col4 * 4;
  float4 bv = *(const float4*)(bias + col);
  float4 pw = make_float4(0.f, 0.f, 0.f, 0.f);
  if (PROJ) pw = *(const float4*)(pW + col);
  float ps[4] = {0.f, 0.f, 0.f, 0.f};
#pragma unroll
  for (int i = 0; i < 4; ++i) {
    int b = bgrp + 16 * i;
    float hc0 = tanhf(acc[i][0] + bv.x);
    float hc1 = tanhf(acc[i][1] + bv.y);
    float hc2 = tanhf(acc[i][2] + bv.z);
    float hc3 = tanhf(acc[i][3] + bv.w);
    size_t idx = (size_t)n * 4096 + b * 64 + col;
    float4 r4 = *(const float4*)(rbuf + idx);
    float4 h4 = *(const float4*)(hmat + idx);
    float4 o;
    o.x = r4.x * h4.x + (1.f - r4.x) * hc0;
    o.y = r4.y * h4.y + (1.f - r4.y) * hc1;
    o.z = r4.z * h4.z + (1.f - r4.z) * hc2;
    o.w = r4.w * h4.w + (1.f - r4.w) * hc3;
    *(float4*)(hmat + idx) = o;
    if (PROJ)
      ps[i] = o.x * pw.x + o.y * pw.y + o.z * pw.z + o.w * pw.w;
  }
  if (PROJ) {
#pragma unroll
    for (int i = 0; i < 4; ++i)
#pragma unroll
      for (int off = 8; off; off >>= 1)
        ps[i] += __shfl_down(ps[i], off, 16);
    if (col4 == 0) {
      float pb0 = pb[0];
#pragma unroll
      for (int i = 0; i < 4; ++i) {
        int b = bgrp + 16 * i;
        float g = ps[i] + pb0;
        gobuf[(size_t)n * 64 + b] = g;
        outp[((size_t)b * HOR + tstep) * N + n] = g;
      }
    }
  }
}

// ---------------------------------------------------------------------------
extern "C" void kernel_launch(void* const* d_in, const int* in_sizes, int n_in,
                              void* d_out, int out_size, void* d_ws, size_t ws_size,
                              hipStream_t stream) {
  const float* x    = (const float*)d_in[0];
  const float* ycov = (const float*)d_in[1];
  const float* emb  = (const float*)d_in[2];
  const float* egW  = (const float*)d_in[3];
  const float* egb  = (const float*)d_in[4];
  const float* euW  = (const float*)d_in[5];
  const float* eub  = (const float*)d_in[6];
  const float* dgW  = (const float*)d_in[7];
  const float* dgb  = (const float*)d_in[8];
  const float* duW  = (const float*)d_in[9];
  const float* dub  = (const float*)d_in[10];
  const float* pW   = (const float*)d_in[11];
  const float* pb   = (const float*)d_in[12];
  float* out = (float*)d_out;
  float* ws  = (float*)d_ws;

  float* Amat = ws + A_off;
  float* S2   = Amat + (size_t)N * N;
  float* xy   = ws + xy_off;
  float* Pxy  = ws + Pxy_off;
  float* hmat = ws + h_off;
  float* Ph   = ws + Ph_off;
  float* zh   = ws + zh_off;
  float* rb   = ws + r_off;
  float* gob  = ws + go_off;
  float* Pgo  = ws + Pgo_off;
  ushort* A2  = (ushort*)(ws + A2_off);    // bf16(stacked S) [2048][1024]
  ushort* AspL = (ushort*)(ws + zh_off);   // precompute-only aliases
  ushort* AspR = (ushort*)(ws + r_off);

  // ---- precompute ----
  build_A<<<N, 256, 0, stream>>>(emb, Amat);
  pack_split_S<<<dim3(32, 32), 256, 0, stream>>>(Amat, AspL, AspR);
  gemm_s2<<<dim3(8, 8), 256, 0, stream>>>(AspL, AspR, S2);
  conv_bf16<<<(2 * N * N / 4) / 256, 256, 0, stream>>>(Amat, A2);
  transpose_bt<<<(N * T * B + 255) / 256, 256, 0, stream>>>(x, xy, 0);
  transpose_bt<<<(N * T * B + 255) / 256, 256, 0, stream>>>(ycov, xy, 768);
  gemm_bf<<<dim3(12, 16), 256, 0, stream>>>(A2, xy, 1536, nullptr, Pxy, nullptr);
  (void)hipMemsetAsync(hmat, 0, NBH * sizeof(float), stream);
  (void)hipMemsetAsync(Ph, 0, 2 * NBH * sizeof(float), stream);
  (void)hipMemsetAsync(gob, 0, (size_t)N * B * sizeof(float), stream);

  // ---- encoder ----
  for (int t = 0; t < T; ++t) {
    if (t > 0)  // t=0: h=0 so Ph=0 (memset)
      gemm_bf<<<dim3(32, 16), 256, 0, stream>>>(A2, hmat, B * H, nullptr, Ph, nullptr);
    gate_kernel<1><<<N, 256, 0, stream>>>(hmat, Ph, egW, egb,
                                          xy, Pxy, 1536, t * B,
                                          nullptr, nullptr, 0, 0, zh, rb);
    if (t > 0)  // t=0: zh = z*0 = 0, so P(zh)=0 (Ph still zero)
      gemm_bf<<<dim3(32, 16), 256, 0, stream>>>(A2, zh, B * H, nullptr, Ph, nullptr);
    upd_kernel<1, 0><<<N, 256, 0, stream>>>(hmat, Ph, zh, euW, eub,
                                            xy, Pxy, 1536, t * B,
                                            nullptr, nullptr, 0, 0, rb,
                                            nullptr, nullptr, nullptr, nullptr, 0);
  }

  // ---- decoder ----
  for (int t = 0; t < HOR; ++t) {
    // h-propagation with go-propagation folded in (33rd column block)
    gemm_bf<<<dim3(33, 16), 256, 0, stream>>>(A2, hmat, B * H, gob, Ph, Pgo);
    gate_kernel<2><<<N, 256, 0, stream>>>(hmat, Ph, dgW, dgb,
                                          gob, Pgo, B, 0,
                                          xy, Pxy, 1536, 768 + t * B, zh, rb);
    gemm_bf<<<dim3(32, 16), 256, 0, stream>>>(A2, zh, B * H, nullptr, Ph, nullptr);
    upd_kernel<2, 1><<<N, 256, 0, stream>>>(hmat, Ph, zh, duW, dub,
                                            gob, Pgo, B, 0,
                                            xy, Pxy, 1536, 768 + t * B, rb,
                                            pW, pb, gob, out, t);
  }
}

// Round 6
// 3244.432 us; speedup vs baseline: 4.2117x; 1.3904x over previous
//
#include <hip/hip_runtime.h>
#include <math.h>

// Problem constants
constexpr int N = 1024, B = 64, T = 12, HOR = 12, H = 64, E = 8;
constexpr size_t NBH = (size_t)N * B * H;

// Workspace layout (float units)
constexpr size_t A_off   = 0;                           // [2048][1024] fp32 stacked S=[A;S2]
constexpr size_t xy_off  = 2ull * N * N;                // [1024][1536]  (xT | yT)
constexpr size_t Pxy_off = xy_off + (size_t)N * 1536;   // [2][1024][1536]
constexpr size_t h_off   = Pxy_off + 2ull * N * 1536;   // [1024][4096]
constexpr size_t Ph_off  = h_off + NBH;                 // [2][1024][4096] (also Pzh)
constexpr size_t zh_off  = Ph_off + 2 * NBH;            // [1024][4096] (precompute: AspL alias)
constexpr size_t r_off   = zh_off + NBH;                // [1024][4096] (precompute: AspR alias)
constexpr size_t go_off  = r_off + NBH;                 // [1024][64]
constexpr size_t Pgo_off = go_off + (size_t)N * B;      // [2][1024][64]
constexpr size_t A2_off  = Pgo_off + 2ull * N * B;      // ushort[2048][1024] = 1M floats
// pre-split weight panels (ushort), panel-major [s][half][hi|lo][col][32]
constexpr size_t wpge_off = A2_off + 1048576;           // gate enc: 3*2*2*128*32 ush = 24576 fl
constexpr size_t wpgd_off = wpge_off + 24576;           // gate dec
constexpr size_t wpue_off = wpgd_off + 24576;           // upd enc: 3*2*2*64*32 ush = 12288 fl
constexpr size_t wpud_off = wpue_off + 12288;           // upd dec

typedef __attribute__((ext_vector_type(8))) short short8;
typedef __attribute__((ext_vector_type(4))) float f32x4;

__device__ __forceinline__ unsigned f2bf(float x) {
  unsigned u = __float_as_uint(x);
  return (u + 0x7fffu + ((u >> 16) & 1u)) >> 16;   // RNE
}
__device__ __forceinline__ float bf2f(unsigned h) {
  return __uint_as_float(h << 16);
}
__device__ __forceinline__ unsigned pk2bf(float a, float b) {
  return (f2bf(a) & 0xffffu) | (f2bf(b) << 16);
}
__device__ __forceinline__ void split4(float4 v, uint2& hi, uint2& lo) {
  unsigned h0 = f2bf(v.x), h1 = f2bf(v.y), h2 = f2bf(v.z), h3 = f2bf(v.w);
  unsigned l0 = f2bf(v.x - bf2f(h0)), l1 = f2bf(v.y - bf2f(h1));
  unsigned l2 = f2bf(v.z - bf2f(h2)), l3 = f2bf(v.w - bf2f(h3));
  hi.x = (h0 & 0xffffu) | (h1 << 16); hi.y = (h2 & 0xffffu) | (h3 << 16);
  lo.x = (l0 & 0xffffu) | (l1 << 16); lo.y = (l2 & 0xffffu) | (l3 << 16);
}

typedef const __attribute__((address_space(1))) void gas_t;
typedef __attribute__((address_space(3))) void las_t;

// ---------------------------------------------------------------------------
// A = softmax(relu(emb @ emb^T)) row-wise. One block per row.
// ---------------------------------------------------------------------------
__global__ __launch_bounds__(256) void build_A(const float* __restrict__ emb,
                                               float* __restrict__ A) {
  __shared__ float sE[N * E];
  __shared__ float sv[N];
  __shared__ float rmax[4], rsum[4];
  const int i = blockIdx.x;
  for (int idx = threadIdx.x; idx < N * E / 4; idx += 256)
    ((float4*)sE)[idx] = ((const float4*)emb)[idx];
  __syncthreads();
  float ei[E];
#pragma unroll
  for (int e = 0; e < E; ++e) ei[e] = sE[i * E + e];
  float mymax = 0.f;
  for (int j = threadIdx.x; j < N; j += 256) {
    float d = 0.f;
#pragma unroll
    for (int e = 0; e < E; ++e) d = fmaf(ei[e], sE[j * E + e], d);
    d = fmaxf(d, 0.f);
    sv[j] = d;
    mymax = fmaxf(mymax, d);
  }
  for (int off = 32; off; off >>= 1) mymax = fmaxf(mymax, __shfl_down(mymax, off));
  const int wid = threadIdx.x >> 6, lid = threadIdx.x & 63;
  if (lid == 0) rmax[wid] = mymax;
  __syncthreads();
  const float m = fmaxf(fmaxf(rmax[0], rmax[1]), fmaxf(rmax[2], rmax[3]));
  float mysum = 0.f;
  for (int j = threadIdx.x; j < N; j += 256) {
    float ev = expf(sv[j] - m);
    sv[j] = ev;
    mysum += ev;
  }
  for (int off = 32; off; off >>= 1) mysum += __shfl_down(mysum, off);
  if (lid == 0) rsum[wid] = mysum;
  __syncthreads();
  const float inv = 1.f / (rsum[0] + rsum[1] + rsum[2] + rsum[3]);
  for (int j = threadIdx.x; j < N; j += 256) A[i * N + j] = sv[j] * inv;
}

// ---------------------------------------------------------------------------
// Split-pack A for the exact S2 gemm: L=(hi,lo,hi), R=(hi,hi,lo) K-triples.
// ---------------------------------------------------------------------------
__global__ __launch_bounds__(256) void pack_split_S(const float* __restrict__ A,
                                                    ushort* __restrict__ L,
                                                    ushort* __restrict__ R) {
  __shared__ float tile[32][33];
  const int bx = blockIdx.x * 32;
  const int by = blockIdx.y * 32;
  const int tx = threadIdx.x & 31;
  const int tg = threadIdx.x >> 5;
#pragma unroll
  for (int p = 0; p < 4; ++p) {
    int ty = tg * 4 + p;
    tile[ty][tx] = A[(size_t)(by + ty) * 1024 + bx + tx];
  }
  __syncthreads();
#pragma unroll
  for (int p = 0; p < 4; ++p) {
    int ty = tg * 4 + p;
    float v = tile[ty][tx];
    unsigned h = f2bf(v);
    unsigned l = f2bf(v - bf2f(h));
    size_t lb = (size_t)(by + ty) * 3072 + 3 * (bx + tx);
    L[lb + 0] = (ushort)h; L[lb + 1] = (ushort)l; L[lb + 2] = (ushort)h;
    float w = tile[tx][ty];
    unsigned hh = f2bf(w);
    unsigned ll = f2bf(w - bf2f(hh));
    size_t rbi = (size_t)(bx + ty) * 3072 + 3 * (by + tx);
    R[rbi + 0] = (ushort)hh; R[rbi + 1] = (ushort)hh; R[rbi + 2] = (ushort)ll;
  }
}

// ---------------------------------------------------------------------------
// fp32 -> bf16 bulk convert (A2 = bf16(stacked S))
// ---------------------------------------------------------------------------
__global__ __launch_bounds__(256) void conv_bf16(const float* __restrict__ src,
                                                 ushort* __restrict__ dst) {
  int i = blockIdx.x * 256 + threadIdx.x;
  float4 v = ((const float4*)src)[i];
  ushort4 o;
  o.x = (ushort)f2bf(v.x); o.y = (ushort)f2bf(v.y);
  o.z = (ushort)f2bf(v.z); o.w = (ushort)f2bf(v.w);
  ((ushort4*)dst)[i] = o;
}

// ---------------------------------------------------------------------------
// Pre-split gate/upd weights (h-rows only) into panel-major bf16:
// out[s][half][hi|lo][col][kk],  value W[(s*CIN + xoff + half*32 + kk)*NC + col]
// ---------------------------------------------------------------------------
__global__ __launch_bounds__(256) void pack_W(const float* __restrict__ W,
                                              ushort* __restrict__ out,
                                              int CIN, int NC, int xoff) {
  int idx = blockIdx.x * 256 + threadIdx.x;
  int total = 3 * 2 * NC * 32;
  if (idx >= total) return;
  int kk = idx & 31;
  int colrest = idx >> 5;
  int col = colrest % NC;
  int rest = colrest / NC;
  int half = rest & 1;
  int s = rest >> 1;
  float v = W[(size_t)(s * CIN + xoff + half * 32 + kk) * NC + col];
  unsigned hi = f2bf(v);
  unsigned lo = f2bf(v - bf2f(hi));
  size_t base = (size_t)((s * 2 + half) * 2) * NC * 32;
  out[base + (size_t)col * 32 + kk] = (ushort)hi;
  out[base + (size_t)NC * 32 + (size_t)col * 32 + kk] = (ushort)lo;
}

// ---------------------------------------------------------------------------
// S2 = 2*A@A - I via split-bf16 MFMA (K=3072 interleaved, fp32-quality).
// ---------------------------------------------------------------------------
__global__ __launch_bounds__(256) void gemm_s2(
    const ushort* __restrict__ L, const ushort* __restrict__ R,
    float* __restrict__ S2) {
  __shared__ ushort As[128 * 32];
  __shared__ ushort Bs[128 * 32];
  const int t = threadIdx.x;
  const int wave = t >> 6, lane = t & 63;
  const int bm = blockIdx.y * 128, bn = blockIdx.x * 128;
  const int wm = (wave & 1) * 64, wn = (wave >> 1) * 64;

  const ushort* aSrc[2]; const ushort* bSrc[2];
  ushort* aDst[2]; ushort* bDst[2];
#pragma unroll
  for (int u = 0; u < 2; ++u) {
    int idx = wave * 128 + u * 64 + lane;
    int row = idx >> 2;
    int kq = (idx & 3) * 8;
    aSrc[u] = L + (size_t)(bm + row) * 3072 + kq;
    bSrc[u] = R + (size_t)(bn + row) * 3072 + kq;
    aDst[u] = &As[(wave * 128 + u * 64) * 8];
    bDst[u] = &Bs[(wave * 128 + u * 64) * 8];
  }
  const int lr = lane & 15;
  const int lk = (lane >> 4) * 8;
  f32x4 acc[4][4];
#pragma unroll
  for (int i = 0; i < 4; ++i)
#pragma unroll
    for (int j = 0; j < 4; ++j) acc[i][j] = {0.f, 0.f, 0.f, 0.f};

  for (int k0 = 0; k0 < 3072; k0 += 32) {
#pragma unroll
    for (int u = 0; u < 2; ++u) {
      __builtin_amdgcn_global_load_lds((gas_t*)(aSrc[u] + k0), (las_t*)aDst[u], 16, 0, 0);
      __builtin_amdgcn_global_load_lds((gas_t*)(bSrc[u] + k0), (las_t*)bDst[u], 16, 0, 0);
    }
    __syncthreads();
    short8 a[4], b[4];
#pragma unroll
    for (int i = 0; i < 4; ++i) a[i] = *(const short8*)&As[(wm + i * 16 + lr) * 32 + lk];
#pragma unroll
    for (int j = 0; j < 4; ++j) b[j] = *(const short8*)&Bs[(wn + j * 16 + lr) * 32 + lk];
#pragma unroll
    for (int i = 0; i < 4; ++i)
#pragma unroll
      for (int j = 0; j < 4; ++j)
        acc[i][j] = __builtin_amdgcn_mfma_f32_16x16x32_bf16(a[i], b[j], acc[i][j], 0, 0, 0);
    __syncthreads();
  }
  const int cr = (lane >> 4) * 4;
  const int cc = lane & 15;
#pragma unroll
  for (int i = 0; i < 4; ++i) {
#pragma unroll
    for (int j = 0; j < 4; ++j) {
      int gm = bm + wm + i * 16 + cr;
      int gn = bn + wn + j * 16 + cc;
#pragma unroll
      for (int r = 0; r < 4; ++r) {
        float v = 2.f * acc[i][j][r] - ((gm + r) == gn ? 1.f : 0.f);
        S2[(size_t)(gm + r) * 1024 + gn] = v;
      }
    }
  }
}

// ---------------------------------------------------------------------------
// Propagation GEMM: C[2048][n1(+64)] = bf16(S)[2048][1024] @ Bf[1024][n1]
// BK=64 (two 32-k panels), B fp32 converted in-flight, A via global_load_lds.
// ---------------------------------------------------------------------------
__global__ __launch_bounds__(256) void gemm_bf(
    const ushort* __restrict__ A2, const float* __restrict__ Bf, int n1,
    const float* __restrict__ B2, float* __restrict__ C1, float* __restrict__ C2) {
  __shared__ ushort As[2][128 * 32];
  __shared__ ushort Bs[2][128 * 40];
  const int t = threadIdx.x;
  const int wave = t >> 6, lane = t & 63;
  const int bm = blockIdx.y * 128, bn = blockIdx.x * 128;
  const int wm = (wave & 1) * 64, wn = (wave >> 1) * 64;
  const bool inB1 = (bn < n1);

  const ushort* aSrc[2];
  ushort* aDst[2][2];
#pragma unroll
  for (int u = 0; u < 2; ++u) {
    int idx = wave * 128 + u * 64 + lane;
    int row = idx >> 2;
    int kq = (idx & 3) * 8;
    aSrc[u] = A2 + (size_t)(bm + row) * 1024 + kq;
    aDst[0][u] = &As[0][(wave * 128 + u * 64) * 8];
    aDst[1][u] = &As[1][(wave * 128 + u * 64) * 8];
  }

  const int c4 = (t & 31) * 4;
  const int kb = (t >> 5) * 8;
  const int bp = kb >> 5;
  const int kbl = kb & 31;
  const float* bBase = nullptr;
  int bStride = 0;
  if (inB1) { bBase = Bf + bn + c4; bStride = n1; }
  else if (c4 < 64) { bBase = B2 + c4; bStride = 64; }

  const int lr = lane & 15;
  const int lk = (lane >> 4) * 8;
  int aOff[4], bOff[4];
#pragma unroll
  for (int i = 0; i < 4; ++i) {
    aOff[i] = (wm + i * 16 + lr) * 32 + lk;
    bOff[i] = (wn + i * 16 + lr) * 40 + lk;
  }

  f32x4 acc[4][4];
#pragma unroll
  for (int i = 0; i < 4; ++i)
#pragma unroll
    for (int j = 0; j < 4; ++j) acc[i][j] = {0.f, 0.f, 0.f, 0.f};

  for (int k0 = 0; k0 < 1024; k0 += 64) {
#pragma unroll
    for (int p = 0; p < 2; ++p)
#pragma unroll
      for (int u = 0; u < 2; ++u)
        __builtin_amdgcn_global_load_lds((gas_t*)(aSrc[u] + k0 + p * 32),
                                         (las_t*)aDst[p][u], 16, 0, 0);
    float4 bv[8];
    if (bBase) {
#pragma unroll
      for (int p = 0; p < 8; ++p)
        bv[p] = *(const float4*)(bBase + (size_t)(k0 + kb + p) * bStride);
    } else {
#pragma unroll
      for (int p = 0; p < 8; ++p) bv[p] = make_float4(0.f, 0.f, 0.f, 0.f);
    }
#pragma unroll
    for (int j = 0; j < 4; ++j) {
      uint4 w;
      w.x = pk2bf(((const float*)&bv[0])[j], ((const float*)&bv[1])[j]);
      w.y = pk2bf(((const float*)&bv[2])[j], ((const float*)&bv[3])[j]);
      w.z = pk2bf(((const float*)&bv[4])[j], ((const float*)&bv[5])[j]);
      w.w = pk2bf(((const float*)&bv[6])[j], ((const float*)&bv[7])[j]);
      *(uint4*)&Bs[bp][(c4 + j) * 40 + kbl] = w;
    }
    __syncthreads();
#pragma unroll
    for (int p = 0; p < 2; ++p) {
      short8 a[4], b[4];
#pragma unroll
      for (int i = 0; i < 4; ++i) a[i] = *(const short8*)&As[p][aOff[i]];
#pragma unroll
      for (int j = 0; j < 4; ++j) b[j] = *(const short8*)&Bs[p][bOff[j]];
#pragma unroll
      for (int i = 0; i < 4; ++i)
#pragma unroll
        for (int j = 0; j < 4; ++j)
          acc[i][j] = __builtin_amdgcn_mfma_f32_16x16x32_bf16(a[i], b[j], acc[i][j], 0, 0, 0);
    }
    __syncthreads();
  }

  const int cr = (lane >> 4) * 4;
  const int cc = lane & 15;
#pragma unroll
  for (int i = 0; i < 4; ++i) {
#pragma unroll
    for (int j = 0; j < 4; ++j) {
      int gm = bm + wm + i * 16 + cr;
      int gn = bn + wn + j * 16 + cc;
      if (gn < n1) {
        float* p = C1 + (size_t)gm * n1 + gn;
#pragma unroll
        for (int r = 0; r < 4; ++r) p[(size_t)r * n1] = acc[i][j][r];
      } else if (C2 != nullptr && gn < n1 + 64) {
        float* p = C2 + (size_t)gm * 64 + (gn - n1);
#pragma unroll
        for (int r = 0; r < 4; ++r) p[(size_t)r * 64] = acc[i][j][r];
      }
    }
  }
}

// ---------------------------------------------------------------------------
// Transpose src[b][t][n] -> dst[n][off + t*64 + b]  (dst row pitch 1536)
// ---------------------------------------------------------------------------
__global__ __launch_bounds__(256) void transpose_bt(const float* __restrict__ src,
                                                    float* __restrict__ dst, int off) {
  int id = blockIdx.x * 256 + threadIdx.x;
  if (id >= N * T * B) return;
  int n = id / (T * B);
  int tb = id % (T * B);
  int tt = tb >> 6, b = tb & 63;
  dst[(size_t)n * 1536 + off + tb] = src[((size_t)b * T + tt) * N + n];
}

// ---------------------------------------------------------------------------
// Gate via MFMA: zr = sigmoid( [h|Ph1|Ph2]-GEMM (split-bf16, fp32-quality)
//                              + exact fp32 x-terms + bias )
// rows (n*64+b) = 65536, cols 128. Tile 128x128, K = 3 supports x (hi,lo).
// Writes zh = z*h and r.
// ---------------------------------------------------------------------------
template <int NX>
__global__ __launch_bounds__(256) void gate_mfma(
    const float* __restrict__ s0, const float* __restrict__ s1, const float* __restrict__ s2,
    const ushort* __restrict__ Wp, const float* __restrict__ Wf, const float* __restrict__ bias,
    const float* __restrict__ xb0, const float* __restrict__ xp0, int xs0,
    const float* __restrict__ xb1, const float* __restrict__ xp1, int xs1,
    float* __restrict__ zh, float* __restrict__ rbuf) {
  constexpr int CIN = NX + 64;
  __shared__ ushort Ah[128 * 32], Al[128 * 32];
  __shared__ ushort Bh[128 * 32], Bl[128 * 32];
  __shared__ float sxv[3][2][128];
  __shared__ float sWx[3][2][128];
  const int t = threadIdx.x;
  const int wave = t >> 6, lane = t & 63;
  const int bm = blockIdx.x * 128;
  const int wm = (wave & 1) * 64, wn = (wave >> 1) * 64;
  const int lr = lane & 15;
  const int lk = (lane >> 4) * 8;

  // stage per-row x scalars and per-col W x-rows
  if (t < 128) {
    int grow = bm + t;
    int n = grow >> 6, b = grow & 63;
    sxv[0][0][t] = xb0[(size_t)n * xs0 + b];
    sxv[1][0][t] = xp0[(size_t)n * xs0 + b];
    sxv[2][0][t] = xp0[(size_t)1024 * xs0 + (size_t)n * xs0 + b];
    if (NX == 2) {
      sxv[0][1][t] = xb1[(size_t)n * xs1 + b];
      sxv[1][1][t] = xp1[(size_t)n * xs1 + b];
      sxv[2][1][t] = xp1[(size_t)1024 * xs1 + (size_t)n * xs1 + b];
    }
  } else {
    int col = t - 128;
#pragma unroll
    for (int s = 0; s < 3; ++s)
#pragma unroll
      for (int f = 0; f < NX; ++f)
        sWx[s][f][col] = Wf[(size_t)(s * CIN + f) * 128 + col];
  }

  f32x4 acc[4][4];
#pragma unroll
  for (int i = 0; i < 4; ++i)
#pragma unroll
    for (int j = 0; j < 4; ++j) acc[i][j] = {0.f, 0.f, 0.f, 0.f};

  for (int it = 0; it < 6; ++it) {
    const int s = it >> 1, half = it & 1, j0 = half * 32;
    const float* src = (s == 0) ? s0 : ((s == 1) ? s1 : s2);
    // A-pack: fp32 -> hi/lo panels
#pragma unroll
    for (int p = 0; p < 4; ++p) {
      int f = p * 256 + t;          // 0..1023 float4s
      int row = f >> 3;
      int jq = (f & 7) * 4;
      float4 v = *(const float4*)(src + (size_t)(bm + row) * 64 + j0 + jq);
      uint2 hi, lo;
      split4(v, hi, lo);
      *(uint2*)&Ah[row * 32 + jq] = hi;
      *(uint2*)&Al[row * 32 + jq] = lo;
    }
    // B panels via global_load_lds
    const ushort* wph = Wp + (size_t)((s * 2 + half) * 2) * (128 * 32);
    const ushort* wpl = wph + 128 * 32;
#pragma unroll
    for (int u = 0; u < 2; ++u) {
      int idx = wave * 128 + u * 64 + lane;
      __builtin_amdgcn_global_load_lds((gas_t*)(wph + idx * 8), (las_t*)&Bh[idx * 8], 16, 0, 0);
      __builtin_amdgcn_global_load_lds((gas_t*)(wpl + idx * 8), (las_t*)&Bl[idx * 8], 16, 0, 0);
    }
    __syncthreads();
    short8 ah[4], al[4], bh[4], bl[4];
#pragma unroll
    for (int i = 0; i < 4; ++i) {
      ah[i] = *(const short8*)&Ah[(wm + i * 16 + lr) * 32 + lk];
      al[i] = *(const short8*)&Al[(wm + i * 16 + lr) * 32 + lk];
    }
#pragma unroll
    for (int j = 0; j < 4; ++j) {
      bh[j] = *(const short8*)&Bh[(wn + j * 16 + lr) * 32 + lk];
      bl[j] = *(const short8*)&Bl[(wn + j * 16 + lr) * 32 + lk];
    }
#pragma unroll
    for (int i = 0; i < 4; ++i)
#pragma unroll
      for (int j = 0; j < 4; ++j) {
        acc[i][j] = __builtin_amdgcn_mfma_f32_16x16x32_bf16(ah[i], bh[j], acc[i][j], 0, 0, 0);
        acc[i][j] = __builtin_amdgcn_mfma_f32_16x16x32_bf16(al[i], bh[j], acc[i][j], 0, 0, 0);
        acc[i][j] = __builtin_amdgcn_mfma_f32_16x16x32_bf16(ah[i], bl[j], acc[i][j], 0, 0, 0);
      }
    __syncthreads();
  }

  const int cr = (lane >> 4) * 4;
  const int cc = lane & 15;
#pragma unroll
  for (int i = 0; i < 4; ++i) {
#pragma unroll
    for (int j = 0; j < 4; ++j) {
      int col = wn + j * 16 + cc;
      float bcol = bias[col];
#pragma unroll
      for (int r = 0; r < 4; ++r) {
        int rowl = wm + i * 16 + cr + r;
        int grow = bm + rowl;
        float v = acc[i][j][r] + bcol;
#pragma unroll
        for (int s = 0; s < 3; ++s)
#pragma unroll
          for (int f = 0; f < NX; ++f)
            v = fmaf(sxv[s][f][rowl], sWx[s][f][col], v);
        float sig = 1.f / (1.f + expf(-v));
        if (col < 64) {
          zh[(size_t)grow * 64 + col] = sig * s0[(size_t)grow * 64 + col];
        } else {
          rbuf[(size_t)grow * 64 + col - 64] = sig;
        }
      }
    }
  }
}

// ---------------------------------------------------------------------------
// Update via MFMA: hc = tanh([zh|Pzh1|Pzh2]-GEMM + x-terms + bias);
// h = r*h + (1-r)*hc.  Tile 128x64. PROJ=1 fuses go = h@pW + pb.
// ---------------------------------------------------------------------------
template <int NX, int PROJ>
__global__ __launch_bounds__(256) void upd_mfma(
    float* __restrict__ hmat,
    const float* __restrict__ s0, const float* __restrict__ s1, const float* __restrict__ s2,
    const ushort* __restrict__ Wp, const float* __restrict__ Wf, const float* __restrict__ bias,
    const float* __restrict__ xb0, const float* __restrict__ xp0, int xs0,
    const float* __restrict__ xb1, const float* __restrict__ xp1, int xs1,
    const float* __restrict__ rbuf,
    const float* __restrict__ pW, const float* __restrict__ pb,
    float* __restrict__ gobuf, float* __restrict__ outp, int tstep) {
  constexpr int CIN = NX + 64;
  __shared__ ushort Ah[128 * 32], Al[128 * 32];
  __shared__ ushort Bh[64 * 32], Bl[64 * 32];
  __shared__ float sxv[3][2][128];
  __shared__ float sWx[3][2][64];
  __shared__ float part[2][128];
  const int t = threadIdx.x;
  const int wave = t >> 6, lane = t & 63;
  const int bm = blockIdx.x * 128;
  const int wm = (wave & 1) * 64, wn = (wave >> 1) * 32;
  const int lr = lane & 15;
  const int lk = (lane >> 4) * 8;

  if (t < 128) {
    int grow = bm + t;
    int n = grow >> 6, b = grow & 63;
    sxv[0][0][t] = xb0[(size_t)n * xs0 + b];
    sxv[1][0][t] = xp0[(size_t)n * xs0 + b];
    sxv[2][0][t] = xp0[(size_t)1024 * xs0 + (size_t)n * xs0 + b];
    if (NX == 2) {
      sxv[0][1][t] = xb1[(size_t)n * xs1 + b];
      sxv[1][1][t] = xp1[(size_t)n * xs1 + b];
      sxv[2][1][t] = xp1[(size_t)1024 * xs1 + (size_t)n * xs1 + b];
    }
  } else if (t < 192) {
    int col = t - 128;
#pragma unroll
    for (int s = 0; s < 3; ++s)
#pragma unroll
      for (int f = 0; f < NX; ++f)
        sWx[s][f][col] = Wf[(size_t)(s * CIN + f) * 64 + col];
  }

  f32x4 acc[4][2];
#pragma unroll
  for (int i = 0; i < 4; ++i)
#pragma unroll
    for (int j = 0; j < 2; ++j) acc[i][j] = {0.f, 0.f, 0.f, 0.f};

  for (int it = 0; it < 6; ++it) {
    const int s = it >> 1, half = it & 1, j0 = half * 32;
    const float* src = (s == 0) ? s0 : ((s == 1) ? s1 : s2);
#pragma unroll
    for (int p = 0; p < 4; ++p) {
      int f = p * 256 + t;
      int row = f >> 3;
      int jq = (f & 7) * 4;
      float4 v = *(const float4*)(src + (size_t)(bm + row) * 64 + j0 + jq);
      uint2 hi, lo;
      split4(v, hi, lo);
      *(uint2*)&Ah[row * 32 + jq] = hi;
      *(uint2*)&Al[row * 32 + jq] = lo;
    }
    const ushort* wph = Wp + (size_t)((s * 2 + half) * 2) * (64 * 32);
    const ushort* wpl = wph + 64 * 32;
    {
      int idx = wave * 64 + lane;
      __builtin_amdgcn_global_load_lds((gas_t*)(wph + idx * 8), (las_t*)&Bh[idx * 8], 16, 0, 0);
      __builtin_amdgcn_global_load_lds((gas_t*)(wpl + idx * 8), (las_t*)&Bl[idx * 8], 16, 0, 0);
    }
    __syncthreads();
    short8 ah[4], al[4], bh[2], bl[2];
#pragma unroll
    for (int i = 0; i < 4; ++i) {
      ah[i] = *(const short8*)&Ah[(wm + i * 16 + lr) * 32 + lk];
      al[i] = *(const short8*)&Al[(wm + i * 16 + lr) * 32 + lk];
    }
#pragma unroll
    for (int j = 0; j < 2; ++j) {
      bh[j] = *(const short8*)&Bh[(wn + j * 16 + lr) * 32 + lk];
      bl[j] = *(const short8*)&Bl[(wn + j * 16 + lr) * 32 + lk];
    }
#pragma unroll
    for (int i = 0; i < 4; ++i)
#pragma unroll
      for (int j = 0; j < 2; ++j) {
        acc[i][j] = __builtin_amdgcn_mfma_f32_16x16x32_bf16(ah[i], bh[j], acc[i][j], 0, 0, 0);
        acc[i][j] = __builtin_amdgcn_mfma_f32_16x16x32_bf16(al[i], bh[j], acc[i][j], 0, 0, 0);
        acc[i][j] = __builtin_amdgcn_mfma_f32_16x16x32_bf16(ah[i], bl[j], acc[i][j], 0, 0, 0);
      }
    __syncthreads();
  }

  const int cr = (lane >> 4) * 4;
  const int cc = lane & 15;
  float psv[4][4];
#pragma unroll
  for (int i = 0; i < 4; ++i)
#pragma unroll
    for (int r = 0; r < 4; ++r) psv[i][r] = 0.f;

#pragma unroll
  for (int i = 0; i < 4; ++i) {
#pragma unroll
    for (int j = 0; j < 2; ++j) {
      int col = wn + j * 16 + cc;
      float bcol = bias[col];
      float pwc = PROJ ? pW[col] : 0.f;
#pragma unroll
      for (int r = 0; r < 4; ++r) {
        int rowl = wm + i * 16 + cr + r;
        int grow = bm + rowl;
        float v = acc[i][j][r] + bcol;
#pragma unroll
        for (int s = 0; s < 3; ++s)
#pragma unroll
          for (int f = 0; f < NX; ++f)
            v = fmaf(sxv[s][f][rowl], sWx[s][f][col], v);
        float hc = tanhf(v);
        size_t idx = (size_t)grow * 64 + col;
        float rr = rbuf[idx];
        float ho = hmat[idx];
        float o = rr * ho + (1.f - rr) * hc;
        hmat[idx] = o;
        if (PROJ) psv[i][r] += o * pwc;
      }
    }
  }
  if (PROJ) {
#pragma unroll
    for (int i = 0; i < 4; ++i)
#pragma unroll
      for (int r = 0; r < 4; ++r)
#pragma unroll
        for (int off = 8; off; off >>= 1)
          psv[i][r] += __shfl_down(psv[i][r], off, 16);
    if (cc == 0) {
#pragma unroll
      for (int i = 0; i < 4; ++i)
#pragma unroll
        for (int r = 0; r < 4; ++r)
          part[wn >> 5][wm + i * 16 + cr + r] = psv[i][r];
    }
    __syncthreads();
    if (t < 128) {
      int grow = bm + t;
      int n = grow >> 6, b = grow & 63;
      float g = part[0][t] + part[1][t] + pb[0];
      gobuf[grow] = g;
      outp[((size_t)b * HOR + tstep) * N + n] = g;
    }
  }
}

// ---------------------------------------------------------------------------
extern "C" void kernel_launch(void* const* d_in, const int* in_sizes, int n_in,
                              void* d_out, int out_size, void* d_ws, size_t ws_size,
                              hipStream_t stream) {
  const float* x    = (const float*)d_in[0];
  const float* ycov = (const float*)d_in[1];
  const float* emb  = (const float*)d_in[2];
  const float* egW  = (const float*)d_in[3];
  const float* egb  = (const float*)d_in[4];
  const float* euW  = (const float*)d_in[5];
  const float* eub  = (const float*)d_in[6];
  const float* dgW  = (const float*)d_in[7];
  const float* dgb  = (const float*)d_in[8];
  const float* duW  = (const float*)d_in[9];
  const float* dub  = (const float*)d_in[10];
  const float* pW   = (const float*)d_in[11];
  const float* pb   = (const float*)d_in[12];
  float* out = (float*)d_out;
  float* ws  = (float*)d_ws;

  float* Amat = ws + A_off;
  float* S2   = Amat + (size_t)N * N;
  float* xy   = ws + xy_off;
  float* Pxy  = ws + Pxy_off;
  float* hmat = ws + h_off;
  float* Ph   = ws + Ph_off;
  float* zh   = ws + zh_off;
  float* rb   = ws + r_off;
  float* gob  = ws + go_off;
  float* Pgo  = ws + Pgo_off;
  ushort* A2   = (ushort*)(ws + A2_off);
  ushort* AspL = (ushort*)(ws + zh_off);   // precompute-only aliases
  ushort* AspR = (ushort*)(ws + r_off);
  ushort* WPge = (ushort*)(ws + wpge_off);
  ushort* WPgd = (ushort*)(ws + wpgd_off);
  ushort* WPue = (ushort*)(ws + wpue_off);
  ushort* WPud = (ushort*)(ws + wpud_off);

  // ---- precompute ----
  build_A<<<N, 256, 0, stream>>>(emb, Amat);
  pack_split_S<<<dim3(32, 32), 256, 0, stream>>>(Amat, AspL, AspR);
  gemm_s2<<<dim3(8, 8), 256, 0, stream>>>(AspL, AspR, S2);
  conv_bf16<<<(2 * N * N / 4) / 256, 256, 0, stream>>>(Amat, A2);
  pack_W<<<(3 * 2 * 128 * 32 + 255) / 256, 256, 0, stream>>>(egW, WPge, 65, 128, 1);
  pack_W<<<(3 * 2 * 128 * 32 + 255) / 256, 256, 0, stream>>>(dgW, WPgd, 66, 128, 2);
  pack_W<<<(3 * 2 * 64 * 32 + 255) / 256, 256, 0, stream>>>(euW, WPue, 65, 64, 1);
  pack_W<<<(3 * 2 * 64 * 32 + 255) / 256, 256, 0, stream>>>(duW, WPud, 66, 64, 2);
  transpose_bt<<<(N * T * B + 255) / 256, 256, 0, stream>>>(x, xy, 0);
  transpose_bt<<<(N * T * B + 255) / 256, 256, 0, stream>>>(ycov, xy, 768);
  gemm_bf<<<dim3(12, 16), 256, 0, stream>>>(A2, xy, 1536, nullptr, Pxy, nullptr);
  (void)hipMemsetAsync(hmat, 0, NBH * sizeof(float), stream);
  (void)hipMemsetAsync(Ph, 0, 2 * NBH * sizeof(float), stream);
  (void)hipMemsetAsync(gob, 0, (size_t)N * B * sizeof(float), stream);

  const float* Ph1 = Ph;
  const float* Ph2 = Ph + (size_t)1024 * 4096;

  // ---- encoder ----
  for (int t = 0; t < T; ++t) {
    if (t > 0)
      gemm_bf<<<dim3(32, 16), 256, 0, stream>>>(A2, hmat, B * H, nullptr, Ph, nullptr);
    gate_mfma<1><<<512, 256, 0, stream>>>(hmat, Ph1, Ph2, WPge, egW, egb,
                                          xy + t * B, Pxy + t * B, 1536,
                                          nullptr, nullptr, 0, zh, rb);
    if (t > 0)
      gemm_bf<<<dim3(32, 16), 256, 0, stream>>>(A2, zh, B * H, nullptr, Ph, nullptr);
    upd_mfma<1, 0><<<512, 256, 0, stream>>>(hmat, zh, Ph1, Ph2, WPue, euW, eub,
                                            xy + t * B, Pxy + t * B, 1536,
                                            nullptr, nullptr, 0, rb,
                                            nullptr, nullptr, nullptr, nullptr, 0);
  }

  // ---- decoder ----
  for (int t = 0; t < HOR; ++t) {
    gemm_bf<<<dim3(33, 16), 256, 0, stream>>>(A2, hmat, B * H, gob, Ph, Pgo);
    gate_mfma<2><<<512, 256, 0, stream>>>(hmat, Ph1, Ph2, WPgd, dgW, dgb,
                                          gob, Pgo, 64,
                                          xy + 768 + t * B, Pxy + 768 + t * B, 1536,
                                          zh, rb);
    gemm_bf<<<dim3(32, 16), 256, 0, stream>>>(A2, zh, B * H, nullptr, Ph, nullptr);
    upd_mfma<2, 1><<<512, 256, 0, stream>>>(hmat, zh, Ph1, Ph2, WPud, duW, dub,
                                            gob, Pgo, 64,
                                            xy + 768 + t * B, Pxy + 768 + t * B, 1536,
                                            rb, pW, pb, gob, out, t);
  }
}

// Round 7
// 3088.865 us; speedup vs baseline: 4.4239x; 1.0504x over previous
//
#include <hip/hip_runtime.h>
#include <math.h>

// Problem constants
constexpr int N = 1024, B = 64, T = 12, HOR = 12, H = 64, E = 8;
constexpr size_t NBH = 4194304;  // 65536 * 64

// Row index convention for all state arrays: grow = b*1024 + n  (b = grow>>10)
// Workspace layout (float units)
constexpr size_t A_off   = 0;                      // [1024][1024] fp32 A
constexpr size_t Pxy_off = 1048576;                // [2][1024][1536] fp32 (n-major)
constexpr size_t h_off   = Pxy_off + 3145728;      // [65536][64] fp32
constexpr size_t Ph_off  = h_off + NBH;            // [2][65536][64] fp32 (precompute: S2 partials alias)
constexpr size_t zh_off  = Ph_off + 2 * NBH;       // [65536][64] fp32 (precompute: AspL alias)
constexpr size_t r_off   = zh_off + NBH;           // [65536][64] fp32 (precompute: AspR alias)
constexpr size_t go_off  = r_off + NBH;            // [65536] fp32
constexpr size_t A2_off  = go_off + 65536;         // ushort[2048][1024]
constexpr size_t Bth_off = A2_off + 1048576;       // ushort[4224][1024] (rows 4096..4159 = go)
constexpr size_t Btz_off = Bth_off + 2162688;      // ushort[4096][1024]
constexpr size_t xyK_off = Btz_off + 2097152;      // ushort[1536][1024]
constexpr size_t Pgo_off = xyK_off + 786432;       // [2][1024][64] fp32
constexpr size_t wp_off  = Pgo_off + 131072;       // weight panels

typedef __attribute__((ext_vector_type(8))) short short8;
typedef __attribute__((ext_vector_type(4))) float f32x4;

__device__ __forceinline__ unsigned f2bf(float x) {
  unsigned u = __float_as_uint(x);
  return (u + 0x7fffu + ((u >> 16) & 1u)) >> 16;   // RNE
}
__device__ __forceinline__ float bf2f(unsigned h) {
  return __uint_as_float(h << 16);
}
__device__ __forceinline__ void split4(float4 v, uint2& hi, uint2& lo) {
  unsigned h0 = f2bf(v.x), h1 = f2bf(v.y), h2 = f2bf(v.z), h3 = f2bf(v.w);
  unsigned l0 = f2bf(v.x - bf2f(h0)), l1 = f2bf(v.y - bf2f(h1));
  unsigned l2 = f2bf(v.z - bf2f(h2)), l3 = f2bf(v.w - bf2f(h3));
  hi.x = (h0 & 0xffffu) | (h1 << 16); hi.y = (h2 & 0xffffu) | (h3 << 16);
  lo.x = (l0 & 0xffffu) | (l1 << 16); lo.y = (l2 & 0xffffu) | (l3 << 16);
}

typedef const __attribute__((address_space(1))) void gas_t;
typedef __attribute__((address_space(3))) void las_t;

// ---------------------------------------------------------------------------
// A = softmax(relu(emb @ emb^T)) row-wise. One block per row.
// ---------------------------------------------------------------------------
__global__ __launch_bounds__(256) void build_A(const float* __restrict__ emb,
                                               float* __restrict__ A) {
  __shared__ float sE[N * E];
  __shared__ float sv[N];
  __shared__ float rmax[4], rsum[4];
  const int i = blockIdx.x;
  for (int idx = threadIdx.x; idx < N * E / 4; idx += 256)
    ((float4*)sE)[idx] = ((const float4*)emb)[idx];
  __syncthreads();
  float ei[E];
#pragma unroll
  for (int e = 0; e < E; ++e) ei[e] = sE[i * E + e];
  float mymax = 0.f;
  for (int j = threadIdx.x; j < N; j += 256) {
    float d = 0.f;
#pragma unroll
    for (int e = 0; e < E; ++e) d = fmaf(ei[e], sE[j * E + e], d);
    d = fmaxf(d, 0.f);
    sv[j] = d;
    mymax = fmaxf(mymax, d);
  }
  for (int off = 32; off; off >>= 1) mymax = fmaxf(mymax, __shfl_down(mymax, off));
  const int wid = threadIdx.x >> 6, lid = threadIdx.x & 63;
  if (lid == 0) rmax[wid] = mymax;
  __syncthreads();
  const float m = fmaxf(fmaxf(rmax[0], rmax[1]), fmaxf(rmax[2], rmax[3]));
  float mysum = 0.f;
  for (int j = threadIdx.x; j < N; j += 256) {
    float ev = expf(sv[j] - m);
    sv[j] = ev;
    mysum += ev;
  }
  for (int off = 32; off; off >>= 1) mysum += __shfl_down(mysum, off);
  if (lid == 0) rsum[wid] = mysum;
  __syncthreads();
  const float inv = 1.f / (rsum[0] + rsum[1] + rsum[2] + rsum[3]);
  for (int j = threadIdx.x; j < N; j += 256) A[i * N + j] = sv[j] * inv;
}

// ---------------------------------------------------------------------------
// Split-pack A for the exact S2 gemm: L=(hi,lo,hi), R=(hi,hi,lo) K-triples.
// ---------------------------------------------------------------------------
__global__ __launch_bounds__(256) void pack_split_S(const float* __restrict__ A,
                                                    ushort* __restrict__ L,
                                                    ushort* __restrict__ R) {
  __shared__ float tile[32][33];
  const int bx = blockIdx.x * 32;
  const int by = blockIdx.y * 32;
  const int tx = threadIdx.x & 31;
  const int tg = threadIdx.x >> 5;
#pragma unroll
  for (int p = 0; p < 4; ++p) {
    int ty = tg * 4 + p;
    tile[ty][tx] = A[(size_t)(by + ty) * 1024 + bx + tx];
  }
  __syncthreads();
#pragma unroll
  for (int p = 0; p < 4; ++p) {
    int ty = tg * 4 + p;
    float v = tile[ty][tx];
    unsigned h = f2bf(v);
    unsigned l = f2bf(v - bf2f(h));
    size_t lb = (size_t)(by + ty) * 3072 + 3 * (bx + tx);
    L[lb + 0] = (ushort)h; L[lb + 1] = (ushort)l; L[lb + 2] = (ushort)h;
    float w = tile[tx][ty];
    unsigned hh = f2bf(w);
    unsigned ll = f2bf(w - bf2f(hh));
    size_t rbi = (size_t)(bx + ty) * 3072 + 3 * (by + tx);
    R[rbi + 0] = (ushort)hh; R[rbi + 1] = (ushort)hh; R[rbi + 2] = (ushort)ll;
  }
}

// ---------------------------------------------------------------------------
// fp32 -> bf16 bulk convert (A2 rows 0..1023 = bf16(A))
// ---------------------------------------------------------------------------
__global__ __launch_bounds__(256) void conv_bf16(const float* __restrict__ src,
                                                 ushort* __restrict__ dst) {
  int i = blockIdx.x * 256 + threadIdx.x;   // over float4s
  float4 v = ((const float4*)src)[i];
  ushort4 o;
  o.x = (ushort)f2bf(v.x); o.y = (ushort)f2bf(v.y);
  o.z = (ushort)f2bf(v.z); o.w = (ushort)f2bf(v.w);
  ((ushort4*)dst)[i] = o;
}

// ---------------------------------------------------------------------------
// x/ycov -> bf16 K-major: dst[(off + t*64 + b)][n] = bf16(src[b][t][n])
// ---------------------------------------------------------------------------
__global__ __launch_bounds__(256) void conv_xyK(const float* __restrict__ src,
                                                ushort* __restrict__ dst, int off) {
  int id = blockIdx.x * 256 + threadIdx.x;   // over 768*1024
  int tb = id >> 10, n = id & 1023;
  int tt = tb >> 6, b = tb & 63;
  dst[(size_t)(off + tb) * 1024 + n] = (ushort)f2bf(src[((size_t)b * T + tt) * 1024 + n]);
}

// ---------------------------------------------------------------------------
// Pre-split gate/upd weights (h-rows) into panel-major bf16.
// ---------------------------------------------------------------------------
__global__ __launch_bounds__(256) void pack_W(const float* __restrict__ W,
                                              ushort* __restrict__ out,
                                              int CIN, int NC, int xoff) {
  int idx = blockIdx.x * 256 + threadIdx.x;
  int total = 3 * 2 * NC * 32;
  if (idx >= total) return;
  int kk = idx & 31;
  int colrest = idx >> 5;
  int col = colrest % NC;
  int rest = colrest / NC;
  int half = rest & 1;
  int s = rest >> 1;
  float v = W[(size_t)(s * CIN + xoff + half * 32 + kk) * NC + col];
  unsigned hi = f2bf(v);
  unsigned lo = f2bf(v - bf2f(hi));
  size_t base = (size_t)((s * 2 + half) * 2) * NC * 32;
  out[base + (size_t)col * 32 + kk] = (ushort)hi;
  out[base + (size_t)NC * 32 + (size_t)col * 32 + kk] = (ushort)lo;
}

// ---------------------------------------------------------------------------
// S2 partials: split-K=4 of the split-bf16 A@A gemm (K=3072 interleaved).
// ---------------------------------------------------------------------------
__global__ __launch_bounds__(256) void gemm_s2p(
    const ushort* __restrict__ L, const ushort* __restrict__ R,
    float* __restrict__ P) {
  __shared__ ushort As[128 * 32];
  __shared__ ushort Bs[128 * 32];
  const int t = threadIdx.x;
  const int wave = t >> 6, lane = t & 63;
  const int bm = blockIdx.y * 128, bn = blockIdx.x * 128;
  const int wm = (wave & 1) * 64, wn = (wave >> 1) * 64;
  float* Pz = P + (size_t)blockIdx.z * 1048576;
  const int kbase = blockIdx.z * 768;

  const ushort* aSrc[2]; const ushort* bSrc[2];
  ushort* aDst[2]; ushort* bDst[2];
#pragma unroll
  for (int u = 0; u < 2; ++u) {
    int idx = wave * 128 + u * 64 + lane;
    int row = idx >> 2;
    int kq = (idx & 3) * 8;
    aSrc[u] = L + (size_t)(bm + row) * 3072 + kq;
    bSrc[u] = R + (size_t)(bn + row) * 3072 + kq;
    aDst[u] = &As[(wave * 128 + u * 64) * 8];
    bDst[u] = &Bs[(wave * 128 + u * 64) * 8];
  }
  const int lr = lane & 15;
  const int lk = (lane >> 4) * 8;
  f32x4 acc[4][4];
#pragma unroll
  for (int i = 0; i < 4; ++i)
#pragma unroll
    for (int j = 0; j < 4; ++j) acc[i][j] = {0.f, 0.f, 0.f, 0.f};

  for (int k0 = kbase; k0 < kbase + 768; k0 += 32) {
#pragma unroll
    for (int u = 0; u < 2; ++u) {
      __builtin_amdgcn_global_load_lds((gas_t*)(aSrc[u] + k0), (las_t*)aDst[u], 16, 0, 0);
      __builtin_amdgcn_global_load_lds((gas_t*)(bSrc[u] + k0), (las_t*)bDst[u], 16, 0, 0);
    }
    __syncthreads();
    short8 a[4], b[4];
#pragma unroll
    for (int i = 0; i < 4; ++i) a[i] = *(const short8*)&As[(wm + i * 16 + lr) * 32 + lk];
#pragma unroll
    for (int j = 0; j < 4; ++j) b[j] = *(const short8*)&Bs[(wn + j * 16 + lr) * 32 + lk];
#pragma unroll
    for (int i = 0; i < 4; ++i)
#pragma unroll
      for (int j = 0; j < 4; ++j)
        acc[i][j] = __builtin_amdgcn_mfma_f32_16x16x32_bf16(a[i], b[j], acc[i][j], 0, 0, 0);
    __syncthreads();
  }
  const int cr = (lane >> 4) * 4;
  const int cc = lane & 15;
#pragma unroll
  for (int i = 0; i < 4; ++i)
#pragma unroll
    for (int j = 0; j < 4; ++j) {
      int gm = bm + wm + i * 16 + cr;
      int gn = bn + wn + j * 16 + cc;
#pragma unroll
      for (int r = 0; r < 4; ++r)
        Pz[(size_t)(gm + r) * 1024 + gn] = acc[i][j][r];
    }
}

// ---------------------------------------------------------------------------
// Combine S2 partials: v = 2*sum - I, write bf16 into A2 rows 1024..2047.
// ---------------------------------------------------------------------------
__global__ __launch_bounds__(256) void comb_s2(const float* __restrict__ P,
                                               ushort* __restrict__ A2) {
  int idx = blockIdx.x * 256 + threadIdx.x;    // over 262144 float4s
  float4 a = ((const float4*)P)[idx];
  float4 b = ((const float4*)(P + 1048576))[idx];
  float4 c = ((const float4*)(P + 2097152))[idx];
  float4 d = ((const float4*)(P + 3145728))[idx];
  int base = idx << 2;
  int m = base >> 10, c0 = base & 1023;
  float v0 = 2.f * (a.x + b.x + c.x + d.x) - (m == c0 + 0 ? 1.f : 0.f);
  float v1 = 2.f * (a.y + b.y + c.y + d.y) - (m == c0 + 1 ? 1.f : 0.f);
  float v2 = 2.f * (a.z + b.z + c.z + d.z) - (m == c0 + 2 ? 1.f : 0.f);
  float v3 = 2.f * (a.w + b.w + c.w + d.w) - (m == c0 + 3 ? 1.f : 0.f);
  ushort4 o;
  o.x = (ushort)f2bf(v0); o.y = (ushort)f2bf(v1);
  o.z = (ushort)f2bf(v2); o.w = (ushort)f2bf(v3);
  ((ushort4*)(A2 + 1048576))[idx] = o;
}

// ---------------------------------------------------------------------------
// Propagation GEMM (pure bf16 B^T, m97 form): C[2048][cols] = A2 @ Bt^T.
// Bt is ushort[rows=cols][1024] K-major. BK=64 (two 32-k panels), both
// operands via global_load_lds. CMODE 0: C1 row-major stride n1 (Pxy).
// CMODE 1: C1 = Ph state layout [half][(b,n)][j]. Fold cols >= n1 -> C2.
// ---------------------------------------------------------------------------
template <int CMODE>
__global__ __launch_bounds__(256) void gemm_bt(
    const ushort* __restrict__ A2, const ushort* __restrict__ Bt, int n1,
    float* __restrict__ C1, float* __restrict__ C2) {
  __shared__ ushort As[2][128 * 32];
  __shared__ ushort Bs[2][128 * 32];
  const int t = threadIdx.x;
  const int wave = t >> 6, lane = t & 63;
  const int bm = blockIdx.y * 128, bn = blockIdx.x * 128;
  const int wm = (wave & 1) * 64, wn = (wave >> 1) * 64;

  const ushort* aSrc[2]; const ushort* bSrc[2];
  ushort* aDst[2][2]; ushort* bDst[2][2];
#pragma unroll
  for (int u = 0; u < 2; ++u) {
    int idx = wave * 128 + u * 64 + lane;
    int row = idx >> 2;
    int kq = (idx & 3) * 8;
    aSrc[u] = A2 + (size_t)(bm + row) * 1024 + kq;
    bSrc[u] = Bt + (size_t)(bn + row) * 1024 + kq;
#pragma unroll
    for (int p = 0; p < 2; ++p) {
      aDst[p][u] = &As[p][(wave * 128 + u * 64) * 8];
      bDst[p][u] = &Bs[p][(wave * 128 + u * 64) * 8];
    }
  }
  const int lr = lane & 15, lk = (lane >> 4) * 8;
  int aOff[4], bOff[4];
#pragma unroll
  for (int i = 0; i < 4; ++i) {
    aOff[i] = (wm + i * 16 + lr) * 32 + lk;
    bOff[i] = (wn + i * 16 + lr) * 32 + lk;
  }
  f32x4 acc[4][4];
#pragma unroll
  for (int i = 0; i < 4; ++i)
#pragma unroll
    for (int j = 0; j < 4; ++j) acc[i][j] = {0.f, 0.f, 0.f, 0.f};

  for (int k0 = 0; k0 < 1024; k0 += 64) {
#pragma unroll
    for (int p = 0; p < 2; ++p)
#pragma unroll
      for (int u = 0; u < 2; ++u) {
        __builtin_amdgcn_global_load_lds((gas_t*)(aSrc[u] + k0 + p * 32),
                                         (las_t*)aDst[p][u], 16, 0, 0);
        __builtin_amdgcn_global_load_lds((gas_t*)(bSrc[u] + k0 + p * 32),
                                         (las_t*)bDst[p][u], 16, 0, 0);
      }
    __syncthreads();
#pragma unroll
    for (int p = 0; p < 2; ++p) {
      short8 a[4], b[4];
#pragma unroll
      for (int i = 0; i < 4; ++i) a[i] = *(const short8*)&As[p][aOff[i]];
#pragma unroll
      for (int j = 0; j < 4; ++j) b[j] = *(const short8*)&Bs[p][bOff[j]];
#pragma unroll
      for (int i = 0; i < 4; ++i)
#pragma unroll
        for (int j = 0; j < 4; ++j)
          acc[i][j] = __builtin_amdgcn_mfma_f32_16x16x32_bf16(a[i], b[j], acc[i][j], 0, 0, 0);
    }
    __syncthreads();
  }

  const int cr = (lane >> 4) * 4;
  const int cc = lane & 15;
#pragma unroll
  for (int i = 0; i < 4; ++i) {
#pragma unroll
    for (int j = 0; j < 4; ++j) {
      int gm = bm + wm + i * 16 + cr;
      int gn = bn + wn + j * 16 + cc;
      if (gn < n1) {
        if (CMODE == 0) {
          float* p = C1 + (size_t)gm * n1 + gn;
#pragma unroll
          for (int r = 0; r < 4; ++r) p[(size_t)r * n1] = acc[i][j][r];
        } else {
          int half = gm >> 10, nn = gm & 1023;
          float* p = C1 + (size_t)half * NBH +
                     ((size_t)(gn >> 6) * 1024 + nn) * 64 + (gn & 63);
#pragma unroll
          for (int r = 0; r < 4; ++r) p[(size_t)r * 64] = acc[i][j][r];
        }
      } else if (C2 != nullptr && gn < n1 + 64) {
        float* p = C2 + (size_t)gm * 64 + (gn - n1);
#pragma unroll
        for (int r = 0; r < 4; ++r) p[(size_t)r * 64] = acc[i][j][r];
      }
    }
  }
}

// ---------------------------------------------------------------------------
// Gate via MFMA (split-bf16, fp32-quality) + exact fp32 x-terms.
// Rows grow = b*1024+n; tile 128x128. Writes zh=z*h (fp32 + bf16 K-major), r.
// ---------------------------------------------------------------------------
template <int NX>
__global__ __launch_bounds__(256) void gate_mfma(
    const float* __restrict__ hmat, const float* __restrict__ Ph,
    const ushort* __restrict__ Wp, const float* __restrict__ Wf, const float* __restrict__ bias,
    const float* __restrict__ xb0, int xbs0, const float* __restrict__ xp0, int xs0,
    const float* __restrict__ xb1, int xbs1, const float* __restrict__ xp1, int xs1,
    float* __restrict__ zh, float* __restrict__ rbuf, ushort* __restrict__ Btz) {
  constexpr int CIN = NX + 64;
  __shared__ ushort Ah[128 * 32], Al[128 * 32];
  __shared__ ushort Bh[128 * 32], Bl[128 * 32];
  __shared__ ushort transT[64 * 136];
  __shared__ float sxv[3][2][128];
  __shared__ float sWx[3][2][128];
  const int t = threadIdx.x;
  const int wave = t >> 6, lane = t & 63;
  const int bm = blockIdx.x * 128;
  const int wm = (wave & 1) * 64, wn = (wave >> 1) * 64;
  const int lr = lane & 15, lk = (lane >> 4) * 8;
  const float* s1 = Ph;
  const float* s2 = Ph + NBH;

  if (t < 128) {
    int grow = bm + t;
    int n = grow & 1023, b = grow >> 10;
    sxv[0][0][t] = xb0[(size_t)b * xbs0 + n];
    sxv[1][0][t] = xp0[(size_t)n * xs0 + b];
    sxv[2][0][t] = xp0[(size_t)1024 * xs0 + (size_t)n * xs0 + b];
    if (NX == 2) {
      sxv[0][1][t] = xb1[(size_t)b * xbs1 + n];
      sxv[1][1][t] = xp1[(size_t)n * xs1 + b];
      sxv[2][1][t] = xp1[(size_t)1024 * xs1 + (size_t)n * xs1 + b];
    }
  } else {
    int col = t - 128;
#pragma unroll
    for (int s = 0; s < 3; ++s)
#pragma unroll
      for (int f = 0; f < NX; ++f)
        sWx[s][f][col] = Wf[(size_t)(s * CIN + f) * 128 + col];
  }

  f32x4 acc[4][4];
#pragma unroll
  for (int i = 0; i < 4; ++i)
#pragma unroll
    for (int j = 0; j < 4; ++j) acc[i][j] = {0.f, 0.f, 0.f, 0.f};

  for (int it = 0; it < 6; ++it) {
    const int s = it >> 1, half = it & 1, j0 = half * 32;
    const float* src = (s == 0) ? hmat : ((s == 1) ? s1 : s2);
#pragma unroll
    for (int p = 0; p < 4; ++p) {
      int f = p * 256 + t;
      int row = f >> 3;
      int jq = (f & 7) * 4;
      float4 v = *(const float4*)(src + (size_t)(bm + row) * 64 + j0 + jq);
      uint2 hi, lo;
      split4(v, hi, lo);
      *(uint2*)&Ah[row * 32 + jq] = hi;
      *(uint2*)&Al[row * 32 + jq] = lo;
    }
    const ushort* wph = Wp + (size_t)((s * 2 + half) * 2) * (128 * 32);
    const ushort* wpl = wph + 128 * 32;
#pragma unroll
    for (int u = 0; u < 2; ++u) {
      int idx = wave * 128 + u * 64 + lane;
      __builtin_amdgcn_global_load_lds((gas_t*)(wph + idx * 8), (las_t*)&Bh[idx * 8], 16, 0, 0);
      __builtin_amdgcn_global_load_lds((gas_t*)(wpl + idx * 8), (las_t*)&Bl[idx * 8], 16, 0, 0);
    }
    __syncthreads();
    short8 ah[4], al[4], bh[4], bl[4];
#pragma unroll
    for (int i = 0; i < 4; ++i) {
      ah[i] = *(const short8*)&Ah[(wm + i * 16 + lr) * 32 + lk];
      al[i] = *(const short8*)&Al[(wm + i * 16 + lr) * 32 + lk];
    }
#pragma unroll
    for (int j = 0; j < 4; ++j) {
      bh[j] = *(const short8*)&Bh[(wn + j * 16 + lr) * 32 + lk];
      bl[j] = *(const short8*)&Bl[(wn + j * 16 + lr) * 32 + lk];
    }
#pragma unroll
    for (int i = 0; i < 4; ++i)
#pragma unroll
      for (int j = 0; j < 4; ++j) {
        acc[i][j] = __builtin_amdgcn_mfma_f32_16x16x32_bf16(ah[i], bh[j], acc[i][j], 0, 0, 0);
        acc[i][j] = __builtin_amdgcn_mfma_f32_16x16x32_bf16(al[i], bh[j], acc[i][j], 0, 0, 0);
        acc[i][j] = __builtin_amdgcn_mfma_f32_16x16x32_bf16(ah[i], bl[j], acc[i][j], 0, 0, 0);
      }
    __syncthreads();
  }

  const int cr = (lane >> 4) * 4;
  const int cc = lane & 15;
#pragma unroll
  for (int i = 0; i < 4; ++i) {
#pragma unroll
    for (int j = 0; j < 4; ++j) {
      int col = wn + j * 16 + cc;
      float bcol = bias[col];
#pragma unroll
      for (int r = 0; r < 4; ++r) {
        int rowl = wm + i * 16 + cr + r;
        int grow = bm + rowl;
        float v = acc[i][j][r] + bcol;
#pragma unroll
        for (int s = 0; s < 3; ++s)
#pragma unroll
          for (int f = 0; f < NX; ++f)
            v = fmaf(sxv[s][f][rowl], sWx[s][f][col], v);
        float sig = 1.f / (1.f + expf(-v));
        if (col < 64) {
          float zv = sig * hmat[(size_t)grow * 64 + col];
          zh[(size_t)grow * 64 + col] = zv;
          transT[col * 136 + rowl] = (ushort)f2bf(zv);
        } else {
          rbuf[(size_t)grow * 64 + col - 64] = sig;
        }
      }
    }
  }
  __syncthreads();
  const int bq = bm >> 10, nb = bm & 1023;
  for (int idx = t; idx < 1024; idx += 256) {
    int j = idx >> 4, ch = idx & 15;
    uint4 v = *(const uint4*)&transT[j * 136 + ch * 8];
    *(uint4*)(Btz + (((size_t)(bq * 64 + j)) << 10) + nb + ch * 8) = v;
  }
}

// ---------------------------------------------------------------------------
// Update via MFMA: hc = tanh(GEMM + x-terms + b); h = r*h + (1-r)*hc.
// Writes h fp32 + bf16 K-major copy. PROJ=1 fuses go-projection + out + go-bf16.
// ---------------------------------------------------------------------------
template <int NX, int PROJ>
__global__ __launch_bounds__(256) void upd_mfma(
    float* __restrict__ hmat, const float* __restrict__ zhb, const float* __restrict__ Pzh,
    const ushort* __restrict__ Wp, const float* __restrict__ Wf, const float* __restrict__ bias,
    const float* __restrict__ xb0, int xbs0, const float* __restrict__ xp0, int xs0,
    const float* __restrict__ xb1, int xbs1, const float* __restrict__ xp1, int xs1,
    const float* __restrict__ rbuf, ushort* __restrict__ Bth,
    const float* __restrict__ pW, const float* __restrict__ pb,
    float* __restrict__ gobuf, float* __restrict__ outp, int tstep) {
  constexpr int CIN = NX + 64;
  __shared__ ushort Ah[128 * 32], Al[128 * 32];
  __shared__ ushort Bh[64 * 32], Bl[64 * 32];
  __shared__ ushort transT[64 * 136];
  __shared__ float sxv[3][2][128];
  __shared__ float sWx[3][2][64];
  __shared__ float part[2][128];
  const int t = threadIdx.x;
  const int wave = t >> 6, lane = t & 63;
  const int bm = blockIdx.x * 128;
  const int wm = (wave & 1) * 64, wn = (wave >> 1) * 32;
  const int lr = lane & 15, lk = (lane >> 4) * 8;
  const float* s1 = Pzh;
  const float* s2 = Pzh + NBH;

  if (t < 128) {
    int grow = bm + t;
    int n = grow & 1023, b = grow >> 10;
    sxv[0][0][t] = xb0[(size_t)b * xbs0 + n];
    sxv[1][0][t] = xp0[(size_t)n * xs0 + b];
    sxv[2][0][t] = xp0[(size_t)1024 * xs0 + (size_t)n * xs0 + b];
    if (NX == 2) {
      sxv[0][1][t] = xb1[(size_t)b * xbs1 + n];
      sxv[1][1][t] = xp1[(size_t)n * xs1 + b];
      sxv[2][1][t] = xp1[(size_t)1024 * xs1 + (size_t)n * xs1 + b];
    }
  } else if (t < 192) {
    int col = t - 128;
#pragma unroll
    for (int s = 0; s < 3; ++s)
#pragma unroll
      for (int f = 0; f < NX; ++f)
        sWx[s][f][col] = Wf[(size_t)(s * CIN + f) * 64 + col];
  }

  f32x4 acc[4][2];
#pragma unroll
  for (int i = 0; i < 4; ++i)
#pragma unroll
    for (int j = 0; j < 2; ++j) acc[i][j] = {0.f, 0.f, 0.f, 0.f};

  for (int it = 0; it < 6; ++it) {
    const int s = it >> 1, half = it & 1, j0 = half * 32;
    const float* src = (s == 0) ? zhb : ((s == 1) ? s1 : s2);
#pragma unroll
    for (int p = 0; p < 4; ++p) {
      int f = p * 256 + t;
      int row = f >> 3;
      int jq = (f & 7) * 4;
      float4 v = *(const float4*)(src + (size_t)(bm + row) * 64 + j0 + jq);
      uint2 hi, lo;
      split4(v, hi, lo);
      *(uint2*)&Ah[row * 32 + jq] = hi;
      *(uint2*)&Al[row * 32 + jq] = lo;
    }
    const ushort* wph = Wp + (size_t)((s * 2 + half) * 2) * (64 * 32);
    const ushort* wpl = wph + 64 * 32;
    {
      int idx = wave * 64 + lane;
      __builtin_amdgcn_global_load_lds((gas_t*)(wph + idx * 8), (las_t*)&Bh[idx * 8], 16, 0, 0);
      __builtin_amdgcn_global_load_lds((gas_t*)(wpl + idx * 8), (las_t*)&Bl[idx * 8], 16, 0, 0);
    }
    __syncthreads();
    short8 ah[4], al[4], bh[2], bl[2];
#pragma unroll
    for (int i = 0; i < 4; ++i) {
      ah[i] = *(const short8*)&Ah[(wm + i * 16 + lr) * 32 + lk];
      al[i] = *(const short8*)&Al[(wm + i * 16 + lr) * 32 + lk];
    }
#pragma unroll
    for (int j = 0; j < 2; ++j) {
      bh[j] = *(const short8*)&Bh[(wn + j * 16 + lr) * 32 + lk];
      bl[j] = *(const short8*)&Bl[(wn + j * 16 + lr) * 32 + lk];
    }
#pragma unroll
    for (int i = 0; i < 4; ++i)
#pragma unroll
      for (int j = 0; j < 2; ++j) {
        acc[i][j] = __builtin_amdgcn_mfma_f32_16x16x32_bf16(ah[i], bh[j], acc[i][j], 0, 0, 0);
        acc[i][j] = __builtin_amdgcn_mfma_f32_16x16x32_bf16(al[i], bh[j], acc[i][j], 0, 0, 0);
        acc[i][j] = __builtin_amdgcn_mfma_f32_16x16x32_bf16(ah[i], bl[j], acc[i][j], 0, 0, 0);
      }
    __syncthreads();
  }

  const int cr = (lane >> 4) * 4;
  const int cc = lane & 15;
  float psv[4][4];
#pragma unroll
  for (int i = 0; i < 4; ++i)
#pragma unroll
    for (int r = 0; r < 4; ++r) psv[i][r] = 0.f;

#pragma unroll
  for (int i = 0; i < 4; ++i) {
#pragma unroll
    for (int j = 0; j < 2; ++j) {
      int col = wn + j * 16 + cc;
      float bcol = bias[col];
      float pwc = PROJ ? pW[col] : 0.f;
#pragma unroll
      for (int r = 0; r < 4; ++r) {
        int rowl = wm + i * 16 + cr + r;
        int grow = bm + rowl;
        float v = acc[i][j][r] + bcol;
#pragma unroll
        for (int s = 0; s < 3; ++s)
#pragma unroll
          for (int f = 0; f < NX; ++f)
            v = fmaf(sxv[s][f][rowl], sWx[s][f][col], v);
        float hc = tanhf(v);
        size_t idx = (size_t)grow * 64 + col;
        float rr = rbuf[idx];
        float ho = hmat[idx];
        float o = rr * ho + (1.f - rr) * hc;
        hmat[idx] = o;
        transT[col * 136 + rowl] = (ushort)f2bf(o);
        if (PROJ) psv[i][r] += o * pwc;
      }
    }
  }
  if (PROJ) {
#pragma unroll
    for (int i = 0; i < 4; ++i)
#pragma unroll
      for (int r = 0; r < 4; ++r)
#pragma unroll
        for (int off = 8; off; off >>= 1)
          psv[i][r] += __shfl_down(psv[i][r], off, 16);
    if (cc == 0) {
#pragma unroll
      for (int i = 0; i < 4; ++i)
#pragma unroll
        for (int r = 0; r < 4; ++r)
          part[wn >> 5][wm + i * 16 + cr + r] = psv[i][r];
    }
  }
  __syncthreads();
  const int bq = bm >> 10, nb = bm & 1023;
  for (int idx = t; idx < 1024; idx += 256) {
    int j = idx >> 4, ch = idx & 15;
    uint4 v = *(const uint4*)&transT[j * 136 + ch * 8];
    *(uint4*)(Bth + (((size_t)(bq * 64 + j)) << 10) + nb + ch * 8) = v;
  }
  if (PROJ && t < 128) {
    int grow = bm + t;
    int n = grow & 1023, b = grow >> 10;
    float g = part[0][t] + part[1][t] + pb[0];
    gobuf[grow] = g;
    outp[((size_t)b * HOR + tstep) * N + n] = g;
    Bth[((size_t)(4096 + b)) * 1024 + n] = (ushort)f2bf(g);
  }
}

// ---------------------------------------------------------------------------
extern "C" void kernel_launch(void* const* d_in, const int* in_sizes, int n_in,
                              void* d_out, int out_size, void* d_ws, size_t ws_size,
                              hipStream_t stream) {
  const float* x    = (const float*)d_in[0];
  const float* ycov = (const float*)d_in[1];
  const float* emb  = (const float*)d_in[2];
  const float* egW  = (const float*)d_in[3];
  const float* egb  = (const float*)d_in[4];
  const float* euW  = (const float*)d_in[5];
  const float* eub  = (const float*)d_in[6];
  const float* dgW  = (const float*)d_in[7];
  const float* dgb  = (const float*)d_in[8];
  const float* duW  = (const float*)d_in[9];
  const float* dub  = (const float*)d_in[10];
  const float* pW   = (const float*)d_in[11];
  const float* pb   = (const float*)d_in[12];
  float* out = (float*)d_out;
  float* ws  = (float*)d_ws;

  float* Amat = ws + A_off;
  float* Pxy  = ws + Pxy_off;
  float* hmat = ws + h_off;
  float* Ph   = ws + Ph_off;
  float* zh   = ws + zh_off;
  float* rb   = ws + r_off;
  float* gob  = ws + go_off;
  float* Pgo  = ws + Pgo_off;
  ushort* A2   = (ushort*)(ws + A2_off);
  ushort* Bth  = (ushort*)(ws + Bth_off);
  ushort* Btz  = (ushort*)(ws + Btz_off);
  ushort* xyK  = (ushort*)(ws + xyK_off);
  ushort* AspL = (ushort*)(ws + zh_off);   // precompute-only aliases
  ushort* AspR = (ushort*)(ws + r_off);
  float*  Pp   = ws + Ph_off;              // S2 partials alias
  ushort* WPge = (ushort*)(ws + wp_off);
  ushort* WPgd = WPge + 2 * 24576;
  ushort* WPue = WPgd + 2 * 24576;
  ushort* WPud = WPue + 2 * 12288;

  // ---- precompute ----
  build_A<<<N, 256, 0, stream>>>(emb, Amat);
  pack_split_S<<<dim3(32, 32), 256, 0, stream>>>(Amat, AspL, AspR);
  gemm_s2p<<<dim3(8, 8, 4), 256, 0, stream>>>(AspL, AspR, Pp);
  comb_s2<<<1024, 256, 0, stream>>>(Pp, A2);
  conv_bf16<<<1024, 256, 0, stream>>>(Amat, A2);   // rows 0..1023
  conv_xyK<<<3072, 256, 0, stream>>>(x, xyK, 0);
  conv_xyK<<<3072, 256, 0, stream>>>(ycov, xyK, 768);
  pack_W<<<(3 * 2 * 128 * 32 + 255) / 256, 256, 0, stream>>>(egW, WPge, 65, 128, 1);
  pack_W<<<(3 * 2 * 128 * 32 + 255) / 256, 256, 0, stream>>>(dgW, WPgd, 66, 128, 2);
  pack_W<<<(3 * 2 * 64 * 32 + 255) / 256, 256, 0, stream>>>(euW, WPue, 65, 64, 1);
  pack_W<<<(3 * 2 * 64 * 32 + 255) / 256, 256, 0, stream>>>(duW, WPud, 66, 64, 2);
  gemm_bt<0><<<dim3(12, 16), 256, 0, stream>>>(A2, xyK, 1536, Pxy, nullptr);
  (void)hipMemsetAsync(hmat, 0, NBH * sizeof(float), stream);
  (void)hipMemsetAsync(Ph, 0, 2 * NBH * sizeof(float), stream);
  (void)hipMemsetAsync(gob, 0, 65536 * sizeof(float), stream);
  (void)hipMemsetAsync(Bth + (size_t)4096 * 1024, 0, 128 * 1024 * sizeof(ushort), stream);

  // ---- encoder ----
  for (int t = 0; t < T; ++t) {
    if (t > 0)  // t=0: h=0 so Ph=0 (memset)
      gemm_bt<1><<<dim3(32, 16), 256, 0, stream>>>(A2, Bth, 4096, Ph, nullptr);
    gate_mfma<1><<<512, 256, 0, stream>>>(hmat, Ph, WPge, egW, egb,
                                          x + t * 1024, T * 1024, Pxy + t * 64, 1536,
                                          nullptr, 0, nullptr, 0, zh, rb, Btz);
    if (t > 0)  // t=0: zh = z*0 = 0, so P(zh)=0
      gemm_bt<1><<<dim3(32, 16), 256, 0, stream>>>(A2, Btz, 4096, Ph, nullptr);
    upd_mfma<1, 0><<<512, 256, 0, stream>>>(hmat, zh, Ph, WPue, euW, eub,
                                            x + t * 1024, T * 1024, Pxy + t * 64, 1536,
                                            nullptr, 0, nullptr, 0, rb, Bth,
                                            nullptr, nullptr, nullptr, nullptr, 0);
  }

  // ---- decoder ----
  for (int t = 0; t < HOR; ++t) {
    gemm_bt<1><<<dim3(33, 16), 256, 0, stream>>>(A2, Bth, 4096, Ph, Pgo);
    gate_mfma<2><<<512, 256, 0, stream>>>(hmat, Ph, WPgd, dgW, dgb,
                                          gob, 1024, Pgo, 64,
                                          ycov + t * 1024, HOR * 1024,
                                          Pxy + 768 + t * 64, 1536, zh, rb, Btz);
    gemm_bt<1><<<dim3(32, 16), 256, 0, stream>>>(A2, Btz, 4096, Ph, nullptr);
    upd_mfma<2, 1><<<512, 256, 0, stream>>>(hmat, zh, Ph, WPud, duW, dub,
                                            gob, 1024, Pgo, 64,
                                            ycov + t * 1024, HOR * 1024,
                                            Pxy + 768 + t * 64, 1536,
                                            rb, Bth, pW, pb, gob, out, t);
  }
}

// Round 8
// 2701.367 us; speedup vs baseline: 5.0584x; 1.1434x over previous
//
#include <hip/hip_runtime.h>
#include <math.h>

// Problem constants
constexpr int N = 1024, B = 64, T = 12, HOR = 12, H = 64, E = 8;
constexpr size_t NBH = 4194304;  // 65536 * 64

// Row index convention for all state arrays: grow = b*1024 + n  (b = grow>>10)
// Workspace layout (float units)
constexpr size_t A_off   = 0;                      // [1024][1024] fp32 A
constexpr size_t Pxy_off = 1048576;                // [2][1024][1536] fp32 (n-major)
constexpr size_t h_off   = Pxy_off + 3145728;      // [65536][64] fp32
constexpr size_t Ph_off  = h_off + NBH;            // [2][65536][64] fp32 (precompute: S2 partials alias)
constexpr size_t zh_off  = Ph_off + 2 * NBH;       // [65536][64] fp32 (precompute: AspL alias)
constexpr size_t r_off   = zh_off + NBH;           // [65536][64] fp32 (precompute: AspR alias)
constexpr size_t go_off  = r_off + NBH;            // [65536] fp32
constexpr size_t A2_off  = go_off + 65536;         // ushort[2048][1024]
constexpr size_t Bth_off = A2_off + 1048576;       // ushort[4224][1024] (rows 4096..4159 = go)
constexpr size_t Btz_off = Bth_off + 2162688;      // ushort[4096][1024]
constexpr size_t xyK_off = Btz_off + 2097152;      // ushort[1536][1024]
constexpr size_t Pgo_off = xyK_off + 786432;       // [2][1024][64] fp32
constexpr size_t wp_off  = Pgo_off + 131072;       // weight panels

typedef __attribute__((ext_vector_type(8))) short short8;
typedef __attribute__((ext_vector_type(4))) float f32x4;

__device__ __forceinline__ unsigned f2bf(float x) {
  unsigned u = __float_as_uint(x);
  return (u + 0x7fffu + ((u >> 16) & 1u)) >> 16;   // RNE
}
__device__ __forceinline__ float bf2f(unsigned h) {
  return __uint_as_float(h << 16);
}
__device__ __forceinline__ void split4(float4 v, uint2& hi, uint2& lo) {
  unsigned h0 = f2bf(v.x), h1 = f2bf(v.y), h2 = f2bf(v.z), h3 = f2bf(v.w);
  unsigned l0 = f2bf(v.x - bf2f(h0)), l1 = f2bf(v.y - bf2f(h1));
  unsigned l2 = f2bf(v.z - bf2f(h2)), l3 = f2bf(v.w - bf2f(h3));
  hi.x = (h0 & 0xffffu) | (h1 << 16); hi.y = (h2 & 0xffffu) | (h3 << 16);
  lo.x = (l0 & 0xffffu) | (l1 << 16); lo.y = (l2 & 0xffffu) | (l3 << 16);
}

typedef const __attribute__((address_space(1))) void gas_t;
typedef __attribute__((address_space(3))) void las_t;

// ---------------------------------------------------------------------------
// A = softmax(relu(emb @ emb^T)) row-wise. One block per row.
// ---------------------------------------------------------------------------
__global__ __launch_bounds__(256) void build_A(const float* __restrict__ emb,
                                               float* __restrict__ A) {
  __shared__ float sE[N * E];
  __shared__ float sv[N];
  __shared__ float rmax[4], rsum[4];
  const int i = blockIdx.x;
  for (int idx = threadIdx.x; idx < N * E / 4; idx += 256)
    ((float4*)sE)[idx] = ((const float4*)emb)[idx];
  __syncthreads();
  float ei[E];
#pragma unroll
  for (int e = 0; e < E; ++e) ei[e] = sE[i * E + e];
  float mymax = 0.f;
  for (int j = threadIdx.x; j < N; j += 256) {
    float d = 0.f;
#pragma unroll
    for (int e = 0; e < E; ++e) d = fmaf(ei[e], sE[j * E + e], d);
    d = fmaxf(d, 0.f);
    sv[j] = d;
    mymax = fmaxf(mymax, d);
  }
  for (int off = 32; off; off >>= 1) mymax = fmaxf(mymax, __shfl_down(mymax, off));
  const int wid = threadIdx.x >> 6, lid = threadIdx.x & 63;
  if (lid == 0) rmax[wid] = mymax;
  __syncthreads();
  const float m = fmaxf(fmaxf(rmax[0], rmax[1]), fmaxf(rmax[2], rmax[3]));
  float mysum = 0.f;
  for (int j = threadIdx.x; j < N; j += 256) {
    float ev = expf(sv[j] - m);
    sv[j] = ev;
    mysum += ev;
  }
  for (int off = 32; off; off >>= 1) mysum += __shfl_down(mysum, off);
  if (lid == 0) rsum[wid] = mysum;
  __syncthreads();
  const float inv = 1.f / (rsum[0] + rsum[1] + rsum[2] + rsum[3]);
  for (int j = threadIdx.x; j < N; j += 256) A[i * N + j] = sv[j] * inv;
}

// ---------------------------------------------------------------------------
// Split-pack A for the exact S2 gemm: L=(hi,lo,hi), R=(hi,hi,lo) K-triples.
// ---------------------------------------------------------------------------
__global__ __launch_bounds__(256) void pack_split_S(const float* __restrict__ A,
                                                    ushort* __restrict__ L,
                                                    ushort* __restrict__ R) {
  __shared__ float tile[32][33];
  const int bx = blockIdx.x * 32;
  const int by = blockIdx.y * 32;
  const int tx = threadIdx.x & 31;
  const int tg = threadIdx.x >> 5;
#pragma unroll
  for (int p = 0; p < 4; ++p) {
    int ty = tg * 4 + p;
    tile[ty][tx] = A[(size_t)(by + ty) * 1024 + bx + tx];
  }
  __syncthreads();
#pragma unroll
  for (int p = 0; p < 4; ++p) {
    int ty = tg * 4 + p;
    float v = tile[ty][tx];
    unsigned h = f2bf(v);
    unsigned l = f2bf(v - bf2f(h));
    size_t lb = (size_t)(by + ty) * 3072 + 3 * (bx + tx);
    L[lb + 0] = (ushort)h; L[lb + 1] = (ushort)l; L[lb + 2] = (ushort)h;
    float w = tile[tx][ty];
    unsigned hh = f2bf(w);
    unsigned ll = f2bf(w - bf2f(hh));
    size_t rbi = (size_t)(bx + ty) * 3072 + 3 * (by + tx);
    R[rbi + 0] = (ushort)hh; R[rbi + 1] = (ushort)hh; R[rbi + 2] = (ushort)ll;
  }
}

// ---------------------------------------------------------------------------
// fp32 -> bf16 bulk convert (A2 rows 0..1023 = bf16(A))
// ---------------------------------------------------------------------------
__global__ __launch_bounds__(256) void conv_bf16(const float* __restrict__ src,
                                                 ushort* __restrict__ dst) {
  int i = blockIdx.x * 256 + threadIdx.x;   // over float4s
  float4 v = ((const float4*)src)[i];
  ushort4 o;
  o.x = (ushort)f2bf(v.x); o.y = (ushort)f2bf(v.y);
  o.z = (ushort)f2bf(v.z); o.w = (ushort)f2bf(v.w);
  ((ushort4*)dst)[i] = o;
}

// ---------------------------------------------------------------------------
// x/ycov -> bf16 K-major: dst[(off + t*64 + b)][n] = bf16(src[b][t][n])
// ---------------------------------------------------------------------------
__global__ __launch_bounds__(256) void conv_xyK(const float* __restrict__ src,
                                                ushort* __restrict__ dst, int off) {
  int id = blockIdx.x * 256 + threadIdx.x;   // over 768*1024
  int tb = id >> 10, n = id & 1023;
  int tt = tb >> 6, b = tb & 63;
  dst[(size_t)(off + tb) * 1024 + n] = (ushort)f2bf(src[((size_t)b * T + tt) * 1024 + n]);
}

// ---------------------------------------------------------------------------
// Pre-split gate/upd weights (h-rows) into panel-major bf16.
// ---------------------------------------------------------------------------
__global__ __launch_bounds__(256) void pack_W(const float* __restrict__ W,
                                              ushort* __restrict__ out,
                                              int CIN, int NC, int xoff) {
  int idx = blockIdx.x * 256 + threadIdx.x;
  int total = 3 * 2 * NC * 32;
  if (idx >= total) return;
  int kk = idx & 31;
  int colrest = idx >> 5;
  int col = colrest % NC;
  int rest = colrest / NC;
  int half = rest & 1;
  int s = rest >> 1;
  float v = W[(size_t)(s * CIN + xoff + half * 32 + kk) * NC + col];
  unsigned hi = f2bf(v);
  unsigned lo = f2bf(v - bf2f(hi));
  size_t base = (size_t)((s * 2 + half) * 2) * NC * 32;
  out[base + (size_t)col * 32 + kk] = (ushort)hi;
  out[base + (size_t)NC * 32 + (size_t)col * 32 + kk] = (ushort)lo;
}

// ---------------------------------------------------------------------------
// S2 partials: split-K=4 of the split-bf16 A@A gemm (K=3072 interleaved).
// ---------------------------------------------------------------------------
__global__ __launch_bounds__(256) void gemm_s2p(
    const ushort* __restrict__ L, const ushort* __restrict__ R,
    float* __restrict__ P) {
  __shared__ ushort As[128 * 32];
  __shared__ ushort Bs[128 * 32];
  const int t = threadIdx.x;
  const int wave = t >> 6, lane = t & 63;
  const int bm = blockIdx.y * 128, bn = blockIdx.x * 128;
  const int wm = (wave & 1) * 64, wn = (wave >> 1) * 64;
  float* Pz = P + (size_t)blockIdx.z * 1048576;
  const int kbase = blockIdx.z * 768;

  const ushort* aSrc[2]; const ushort* bSrc[2];
  ushort* aDst[2]; ushort* bDst[2];
#pragma unroll
  for (int u = 0; u < 2; ++u) {
    int idx = wave * 128 + u * 64 + lane;
    int row = idx >> 2;
    int kq = (idx & 3) * 8;
    aSrc[u] = L + (size_t)(bm + row) * 3072 + kq;
    bSrc[u] = R + (size_t)(bn + row) * 3072 + kq;
    aDst[u] = &As[(wave * 128 + u * 64) * 8];
    bDst[u] = &Bs[(wave * 128 + u * 64) * 8];
  }
  const int lr = lane & 15;
  const int lk = (lane >> 4) * 8;
  f32x4 acc[4][4];
#pragma unroll
  for (int i = 0; i < 4; ++i)
#pragma unroll
    for (int j = 0; j < 4; ++j) acc[i][j] = {0.f, 0.f, 0.f, 0.f};

  for (int k0 = kbase; k0 < kbase + 768; k0 += 32) {
#pragma unroll
    for (int u = 0; u < 2; ++u) {
      __builtin_amdgcn_global_load_lds((gas_t*)(aSrc[u] + k0), (las_t*)aDst[u], 16, 0, 0);
      __builtin_amdgcn_global_load_lds((gas_t*)(bSrc[u] + k0), (las_t*)bDst[u], 16, 0, 0);
    }
    __syncthreads();
    short8 a[4], b[4];
#pragma unroll
    for (int i = 0; i < 4; ++i) a[i] = *(const short8*)&As[(wm + i * 16 + lr) * 32 + lk];
#pragma unroll
    for (int j = 0; j < 4; ++j) b[j] = *(const short8*)&Bs[(wn + j * 16 + lr) * 32 + lk];
#pragma unroll
    for (int i = 0; i < 4; ++i)
#pragma unroll
      for (int j = 0; j < 4; ++j)
        acc[i][j] = __builtin_amdgcn_mfma_f32_16x16x32_bf16(a[i], b[j], acc[i][j], 0, 0, 0);
    __syncthreads();
  }
  const int cr = (lane >> 4) * 4;
  const int cc = lane & 15;
#pragma unroll
  for (int i = 0; i < 4; ++i)
#pragma unroll
    for (int j = 0; j < 4; ++j) {
      int gm = bm + wm + i * 16 + cr;
      int gn = bn + wn + j * 16 + cc;
#pragma unroll
      for (int r = 0; r < 4; ++r)
        Pz[(size_t)(gm + r) * 1024 + gn] = acc[i][j][r];
    }
}

// ---------------------------------------------------------------------------
// Combine S2 partials: v = 2*sum - I, write bf16 into A2 rows 1024..2047.
// ---------------------------------------------------------------------------
__global__ __launch_bounds__(256) void comb_s2(const float* __restrict__ P,
                                               ushort* __restrict__ A2) {
  int idx = blockIdx.x * 256 + threadIdx.x;    // over 262144 float4s
  float4 a = ((const float4*)P)[idx];
  float4 b = ((const float4*)(P + 1048576))[idx];
  float4 c = ((const float4*)(P + 2097152))[idx];
  float4 d = ((const float4*)(P + 3145728))[idx];
  int base = idx << 2;
  int m = base >> 10, c0 = base & 1023;
  float v0 = 2.f * (a.x + b.x + c.x + d.x) - (m == c0 + 0 ? 1.f : 0.f);
  float v1 = 2.f * (a.y + b.y + c.y + d.y) - (m == c0 + 1 ? 1.f : 0.f);
  float v2 = 2.f * (a.z + b.z + c.z + d.z) - (m == c0 + 2 ? 1.f : 0.f);
  float v3 = 2.f * (a.w + b.w + c.w + d.w) - (m == c0 + 3 ? 1.f : 0.f);
  ushort4 o;
  o.x = (ushort)f2bf(v0); o.y = (ushort)f2bf(v1);
  o.z = (ushort)f2bf(v2); o.w = (ushort)f2bf(v3);
  ((ushort4*)(A2 + 1048576))[idx] = o;
}

// ---------------------------------------------------------------------------
// Propagation GEMM (pure bf16 B^T, m97 form): C[2048][cols] = A2 @ Bt^T.
// CMODE 0: C1 row-major stride n1 (Pxy). CMODE 1: C1 = Ph state layout.
// ---------------------------------------------------------------------------
template <int CMODE>
__global__ __launch_bounds__(256) void gemm_bt(
    const ushort* __restrict__ A2, const ushort* __restrict__ Bt, int n1,
    float* __restrict__ C1, float* __restrict__ C2) {
  __shared__ ushort As[2][128 * 32];
  __shared__ ushort Bs[2][128 * 32];
  const int t = threadIdx.x;
  const int wave = t >> 6, lane = t & 63;
  const int bm = blockIdx.y * 128, bn = blockIdx.x * 128;
  const int wm = (wave & 1) * 64, wn = (wave >> 1) * 64;

  const ushort* aSrc[2]; const ushort* bSrc[2];
  ushort* aDst[2][2]; ushort* bDst[2][2];
#pragma unroll
  for (int u = 0; u < 2; ++u) {
    int idx = wave * 128 + u * 64 + lane;
    int row = idx >> 2;
    int kq = (idx & 3) * 8;
    aSrc[u] = A2 + (size_t)(bm + row) * 1024 + kq;
    bSrc[u] = Bt + (size_t)(bn + row) * 1024 + kq;
#pragma unroll
    for (int p = 0; p < 2; ++p) {
      aDst[p][u] = &As[p][(wave * 128 + u * 64) * 8];
      bDst[p][u] = &Bs[p][(wave * 128 + u * 64) * 8];
    }
  }
  const int lr = lane & 15, lk = (lane >> 4) * 8;
  int aOff[4], bOff[4];
#pragma unroll
  for (int i = 0; i < 4; ++i) {
    aOff[i] = (wm + i * 16 + lr) * 32 + lk;
    bOff[i] = (wn + i * 16 + lr) * 32 + lk;
  }
  f32x4 acc[4][4];
#pragma unroll
  for (int i = 0; i < 4; ++i)
#pragma unroll
    for (int j = 0; j < 4; ++j) acc[i][j] = {0.f, 0.f, 0.f, 0.f};

  for (int k0 = 0; k0 < 1024; k0 += 64) {
#pragma unroll
    for (int p = 0; p < 2; ++p)
#pragma unroll
      for (int u = 0; u < 2; ++u) {
        __builtin_amdgcn_global_load_lds((gas_t*)(aSrc[u] + k0 + p * 32),
                                         (las_t*)aDst[p][u], 16, 0, 0);
        __builtin_amdgcn_global_load_lds((gas_t*)(bSrc[u] + k0 + p * 32),
                                         (las_t*)bDst[p][u], 16, 0, 0);
      }
    __syncthreads();
#pragma unroll
    for (int p = 0; p < 2; ++p) {
      short8 a[4], b[4];
#pragma unroll
      for (int i = 0; i < 4; ++i) a[i] = *(const short8*)&As[p][aOff[i]];
#pragma unroll
      for (int j = 0; j < 4; ++j) b[j] = *(const short8*)&Bs[p][bOff[j]];
#pragma unroll
      for (int i = 0; i < 4; ++i)
#pragma unroll
        for (int j = 0; j < 4; ++j)
          acc[i][j] = __builtin_amdgcn_mfma_f32_16x16x32_bf16(a[i], b[j], acc[i][j], 0, 0, 0);
    }
    __syncthreads();
  }

  const int cr = (lane >> 4) * 4;
  const int cc = lane & 15;
#pragma unroll
  for (int i = 0; i < 4; ++i) {
#pragma unroll
    for (int j = 0; j < 4; ++j) {
      int gm = bm + wm + i * 16 + cr;
      int gn = bn + wn + j * 16 + cc;
      if (gn < n1) {
        if (CMODE == 0) {
          float* p = C1 + (size_t)gm * n1 + gn;
#pragma unroll
          for (int r = 0; r < 4; ++r) p[(size_t)r * n1] = acc[i][j][r];
        } else {
          int half = gm >> 10, nn = gm & 1023;
          float* p = C1 + (size_t)half * NBH +
                     ((size_t)(gn >> 6) * 1024 + nn) * 64 + (gn & 63);
#pragma unroll
          for (int r = 0; r < 4; ++r) p[(size_t)r * 64] = acc[i][j][r];
        }
      } else if (C2 != nullptr && gn < n1 + 64) {
        float* p = C2 + (size_t)gm * 64 + (gn - n1);
#pragma unroll
        for (int r = 0; r < 4; ++r) p[(size_t)r * 64] = acc[i][j][r];
      }
    }
  }
}

// ---------------------------------------------------------------------------
// Gate via MFMA (split-bf16, fp32-quality) + exact fp32 x-terms.
// 64-row tiles (grid 1024 = 4 blocks/CU), register-prefetch pipelined A-pack,
// LDS union (transpose buffer aliases dead staging). Writes zh, r, Btz.
// ---------------------------------------------------------------------------
template <int NX>
__global__ __launch_bounds__(256, 4) void gate_mfma(
    const float* __restrict__ hmat, const float* __restrict__ Ph,
    const ushort* __restrict__ Wp, const float* __restrict__ Wf, const float* __restrict__ bias,
    const float* __restrict__ xb0, int xbs0, const float* __restrict__ xp0, int xs0,
    const float* __restrict__ xb1, int xbs1, const float* __restrict__ xp1, int xs1,
    float* __restrict__ zh, float* __restrict__ rbuf, ushort* __restrict__ Btz) {
  constexpr int CIN = NX + 64;
  __shared__ ushort smem[12288];            // Ah|Al|Bh|Bl ; epilogue: transT alias
  ushort* Ah = smem;                        // 64*32
  ushort* Al = smem + 2048;                 // 64*32
  ushort* Bh = smem + 4096;                 // 128*32
  ushort* Bl = smem + 8192;                 // 128*32
  ushort* transT = smem;                    // 64*72 = 4608 (aliases Ah/Al)
  __shared__ float sxv[3][2][64];
  __shared__ float sWx[3][2][128];
  const int t = threadIdx.x;
  const int wave = t >> 6, lane = t & 63;
  const int bm = blockIdx.x * 64;
  const int wm = (wave & 1) * 32, wn = (wave >> 1) * 64;
  const int lr = lane & 15, lk = (lane >> 4) * 8;
  const float* srcs[3] = {hmat, Ph, Ph + NBH};

  if (t < 64) {
    int grow = bm + t;
    int n = grow & 1023, b = grow >> 10;
    sxv[0][0][t] = xb0[(size_t)b * xbs0 + n];
    sxv[1][0][t] = xp0[(size_t)n * xs0 + b];
    sxv[2][0][t] = xp0[(size_t)1024 * xs0 + (size_t)n * xs0 + b];
    if (NX == 2) {
      sxv[0][1][t] = xb1[(size_t)b * xbs1 + n];
      sxv[1][1][t] = xp1[(size_t)n * xs1 + b];
      sxv[2][1][t] = xp1[(size_t)1024 * xs1 + (size_t)n * xs1 + b];
    }
  } else if (t < 192) {
    int col = t - 64;
#pragma unroll
    for (int s = 0; s < 3; ++s)
#pragma unroll
      for (int f = 0; f < NX; ++f)
        sWx[s][f][col] = Wf[(size_t)(s * CIN + f) * 128 + col];
  }

  // A-pack addresses (2 float4 per thread per iter)
  int arow[2], ajq[2];
#pragma unroll
  for (int p = 0; p < 2; ++p) {
    int f = p * 256 + t;      // 0..511 over 64 rows x 8 float4s
    arow[p] = f >> 3;
    ajq[p] = (f & 7) * 4;
  }
  float4 pf[2];
#pragma unroll
  for (int p = 0; p < 2; ++p)
    pf[p] = *(const float4*)(hmat + (size_t)(bm + arow[p]) * 64 + ajq[p]);

  f32x4 acc[2][4];
#pragma unroll
  for (int i = 0; i < 2; ++i)
#pragma unroll
    for (int j = 0; j < 4; ++j) acc[i][j] = {0.f, 0.f, 0.f, 0.f};

  for (int it = 0; it < 6; ++it) {
    const int s = it >> 1, half = it & 1;
#pragma unroll
    for (int p = 0; p < 2; ++p) {
      uint2 hi, lo;
      split4(pf[p], hi, lo);
      *(uint2*)&Ah[arow[p] * 32 + ajq[p]] = hi;
      *(uint2*)&Al[arow[p] * 32 + ajq[p]] = lo;
    }
    const ushort* wph = Wp + (size_t)((s * 2 + half) * 2) * (128 * 32);
    const ushort* wpl = wph + 128 * 32;
#pragma unroll
    for (int u = 0; u < 2; ++u) {
      int idx = wave * 128 + u * 64 + lane;
      __builtin_amdgcn_global_load_lds((gas_t*)(wph + idx * 8), (las_t*)&Bh[idx * 8], 16, 0, 0);
      __builtin_amdgcn_global_load_lds((gas_t*)(wpl + idx * 8), (las_t*)&Bl[idx * 8], 16, 0, 0);
    }
    __syncthreads();
    if (it < 5) {   // prefetch next iteration's A tile (hides global latency)
      const float* nsrc = srcs[(it + 1) >> 1];
      const int nj0 = ((it + 1) & 1) * 32;
#pragma unroll
      for (int p = 0; p < 2; ++p)
        pf[p] = *(const float4*)(nsrc + (size_t)(bm + arow[p]) * 64 + nj0 + ajq[p]);
    }
    short8 ah[2], al[2], bh[4], bl[4];
#pragma unroll
    for (int i = 0; i < 2; ++i) {
      ah[i] = *(const short8*)&Ah[(wm + i * 16 + lr) * 32 + lk];
      al[i] = *(const short8*)&Al[(wm + i * 16 + lr) * 32 + lk];
    }
#pragma unroll
    for (int j = 0; j < 4; ++j) {
      bh[j] = *(const short8*)&Bh[(wn + j * 16 + lr) * 32 + lk];
      bl[j] = *(const short8*)&Bl[(wn + j * 16 + lr) * 32 + lk];
    }
#pragma unroll
    for (int i = 0; i < 2; ++i)
#pragma unroll
      for (int j = 0; j < 4; ++j) {
        acc[i][j] = __builtin_amdgcn_mfma_f32_16x16x32_bf16(ah[i], bh[j], acc[i][j], 0, 0, 0);
        acc[i][j] = __builtin_amdgcn_mfma_f32_16x16x32_bf16(al[i], bh[j], acc[i][j], 0, 0, 0);
        acc[i][j] = __builtin_amdgcn_mfma_f32_16x16x32_bf16(ah[i], bl[j], acc[i][j], 0, 0, 0);
      }
    __syncthreads();
  }

  const int cr = (lane >> 4) * 4;
  const int cc = lane & 15;
#pragma unroll
  for (int i = 0; i < 2; ++i) {
#pragma unroll
    for (int j = 0; j < 4; ++j) {
      int col = wn + j * 16 + cc;
      float bcol = bias[col];
#pragma unroll
      for (int r = 0; r < 4; ++r) {
        int rowl = wm + i * 16 + cr + r;
        int grow = bm + rowl;
        float v = acc[i][j][r] + bcol;
#pragma unroll
        for (int s = 0; s < 3; ++s)
#pragma unroll
          for (int f = 0; f < NX; ++f)
            v = fmaf(sxv[s][f][rowl], sWx[s][f][col], v);
        float sig = 1.f / (1.f + expf(-v));
        if (col < 64) {
          float zv = sig * hmat[(size_t)grow * 64 + col];
          zh[(size_t)grow * 64 + col] = zv;
          transT[col * 72 + rowl] = (ushort)f2bf(zv);
        } else {
          rbuf[(size_t)grow * 64 + col - 64] = sig;
        }
      }
    }
  }
  __syncthreads();
  const int bq = bm >> 10, nb = bm & 1023;
  for (int idx = t; idx < 512; idx += 256) {
    int j = idx >> 3, ch = idx & 7;
    uint4 v = *(const uint4*)&transT[j * 72 + ch * 8];
    *(uint4*)(Btz + (((size_t)(bq * 64 + j)) << 10) + nb + ch * 8) = v;
  }
}

// ---------------------------------------------------------------------------
// Update via MFMA: hc = tanh(GEMM + x-terms + b); h = r*h + (1-r)*hc.
// 64-row tiles, pipelined A-pack, LDS union. PROJ=1 fuses go-projection.
// ---------------------------------------------------------------------------
template <int NX, int PROJ>
__global__ __launch_bounds__(256, 4) void upd_mfma(
    float* __restrict__ hmat, const float* __restrict__ zhb, const float* __restrict__ Pzh,
    const ushort* __restrict__ Wp, const float* __restrict__ Wf, const float* __restrict__ bias,
    const float* __restrict__ xb0, int xbs0, const float* __restrict__ xp0, int xs0,
    const float* __restrict__ xb1, int xbs1, const float* __restrict__ xp1, int xs1,
    const float* __restrict__ rbuf, ushort* __restrict__ Bth,
    const float* __restrict__ pW, const float* __restrict__ pb,
    float* __restrict__ gobuf, float* __restrict__ outp, int tstep) {
  constexpr int CIN = NX + 64;
  __shared__ ushort smem[8192];             // Ah|Al|Bh|Bl ; epilogue: transT alias
  ushort* Ah = smem;                        // 64*32
  ushort* Al = smem + 2048;
  ushort* Bh = smem + 4096;                 // 64*32
  ushort* Bl = smem + 6144;
  ushort* transT = smem;                    // 64*72 = 4608
  __shared__ float sxv[3][2][64];
  __shared__ float sWx[3][2][64];
  __shared__ float part[2][64];
  const int t = threadIdx.x;
  const int wave = t >> 6, lane = t & 63;
  const int bm = blockIdx.x * 64;
  const int wm = (wave & 1) * 32, wn = (wave >> 1) * 32;
  const int lr = lane & 15, lk = (lane >> 4) * 8;
  const float* srcs[3] = {zhb, Pzh, Pzh + NBH};

  if (t < 64) {
    int grow = bm + t;
    int n = grow & 1023, b = grow >> 10;
    sxv[0][0][t] = xb0[(size_t)b * xbs0 + n];
    sxv[1][0][t] = xp0[(size_t)n * xs0 + b];
    sxv[2][0][t] = xp0[(size_t)1024 * xs0 + (size_t)n * xs0 + b];
    if (NX == 2) {
      sxv[0][1][t] = xb1[(size_t)b * xbs1 + n];
      sxv[1][1][t] = xp1[(size_t)n * xs1 + b];
      sxv[2][1][t] = xp1[(size_t)1024 * xs1 + (size_t)n * xs1 + b];
    }
  } else if (t < 128) {
    int col = t - 64;
#pragma unroll
    for (int s = 0; s < 3; ++s)
#pragma unroll
      for (int f = 0; f < NX; ++f)
        sWx[s][f][col] = Wf[(size_t)(s * CIN + f) * 64 + col];
  }

  int arow[2], ajq[2];
#pragma unroll
  for (int p = 0; p < 2; ++p) {
    int f = p * 256 + t;
    arow[p] = f >> 3;
    ajq[p] = (f & 7) * 4;
  }
  float4 pf[2];
#pragma unroll
  for (int p = 0; p < 2; ++p)
    pf[p] = *(const float4*)(zhb + (size_t)(bm + arow[p]) * 64 + ajq[p]);

  f32x4 acc[2][2];
#pragma unroll
  for (int i = 0; i < 2; ++i)
#pragma unroll
    for (int j = 0; j < 2; ++j) acc[i][j] = {0.f, 0.f, 0.f, 0.f};

  for (int it = 0; it < 6; ++it) {
    const int s = it >> 1, half = it & 1;
#pragma unroll
    for (int p = 0; p < 2; ++p) {
      uint2 hi, lo;
      split4(pf[p], hi, lo);
      *(uint2*)&Ah[arow[p] * 32 + ajq[p]] = hi;
      *(uint2*)&Al[arow[p] * 32 + ajq[p]] = lo;
    }
    const ushort* wph = Wp + (size_t)((s * 2 + half) * 2) * (64 * 32);
    const ushort* wpl = wph + 64 * 32;
    {
      int idx = wave * 64 + lane;
      __builtin_amdgcn_global_load_lds((gas_t*)(wph + idx * 8), (las_t*)&Bh[idx * 8], 16, 0, 0);
      __builtin_amdgcn_global_load_lds((gas_t*)(wpl + idx * 8), (las_t*)&Bl[idx * 8], 16, 0, 0);
    }
    __syncthreads();
    if (it < 5) {
      const float* nsrc = srcs[(it + 1) >> 1];
      const int nj0 = ((it + 1) & 1) * 32;
#pragma unroll
      for (int p = 0; p < 2; ++p)
        pf[p] = *(const float4*)(nsrc + (size_t)(bm + arow[p]) * 64 + nj0 + ajq[p]);
    }
    short8 ah[2], al[2], bh[2], bl[2];
#pragma unroll
    for (int i = 0; i < 2; ++i) {
      ah[i] = *(const short8*)&Ah[(wm + i * 16 + lr) * 32 + lk];
      al[i] = *(const short8*)&Al[(wm + i * 16 + lr) * 32 + lk];
    }
#pragma unroll
    for (int j = 0; j < 2; ++j) {
      bh[j] = *(const short8*)&Bh[(wn + j * 16 + lr) * 32 + lk];
      bl[j] = *(const short8*)&Bl[(wn + j * 16 + lr) * 32 + lk];
    }
#pragma unroll
    for (int i = 0; i < 2; ++i)
#pragma unroll
      for (int j = 0; j < 2; ++j) {
        acc[i][j] = __builtin_amdgcn_mfma_f32_16x16x32_bf16(ah[i], bh[j], acc[i][j], 0, 0, 0);
        acc[i][j] = __builtin_amdgcn_mfma_f32_16x16x32_bf16(al[i], bh[j], acc[i][j], 0, 0, 0);
        acc[i][j] = __builtin_amdgcn_mfma_f32_16x16x32_bf16(ah[i], bl[j], acc[i][j], 0, 0, 0);
      }
    __syncthreads();
  }

  const int cr = (lane >> 4) * 4;
  const int cc = lane & 15;
  float psv[2][4];
#pragma unroll
  for (int i = 0; i < 2; ++i)
#pragma unroll
    for (int r = 0; r < 4; ++r) psv[i][r] = 0.f;

#pragma unroll
  for (int i = 0; i < 2; ++i) {
#pragma unroll
    for (int j = 0; j < 2; ++j) {
      int col = wn + j * 16 + cc;
      float bcol = bias[col];
      float pwc = PROJ ? pW[col] : 0.f;
#pragma unroll
      for (int r = 0; r < 4; ++r) {
        int rowl = wm + i * 16 + cr + r;
        int grow = bm + rowl;
        float v = acc[i][j][r] + bcol;
#pragma unroll
        for (int s = 0; s < 3; ++s)
#pragma unroll
          for (int f = 0; f < NX; ++f)
            v = fmaf(sxv[s][f][rowl], sWx[s][f][col], v);
        float hc = tanhf(v);
        size_t idx = (size_t)grow * 64 + col;
        float rr = rbuf[idx];
        float ho = hmat[idx];
        float o = rr * ho + (1.f - rr) * hc;
        hmat[idx] = o;
        transT[col * 72 + rowl] = (ushort)f2bf(o);
        if (PROJ) psv[i][r] += o * pwc;
      }
    }
  }
  if (PROJ) {
#pragma unroll
    for (int i = 0; i < 2; ++i)
#pragma unroll
      for (int r = 0; r < 4; ++r)
#pragma unroll
        for (int off = 8; off; off >>= 1)
          psv[i][r] += __shfl_down(psv[i][r], off, 16);
    if (cc == 0) {
#pragma unroll
      for (int i = 0; i < 2; ++i)
#pragma unroll
        for (int r = 0; r < 4; ++r)
          part[wn >> 5][wm + i * 16 + cr + r] = psv[i][r];
    }
  }
  __syncthreads();
  const int bq = bm >> 10, nb = bm & 1023;
  for (int idx = t; idx < 512; idx += 256) {
    int j = idx >> 3, ch = idx & 7;
    uint4 v = *(const uint4*)&transT[j * 72 + ch * 8];
    *(uint4*)(Bth + (((size_t)(bq * 64 + j)) << 10) + nb + ch * 8) = v;
  }
  if (PROJ && t < 64) {
    int grow = bm + t;
    int n = grow & 1023, b = grow >> 10;
    float g = part[0][t] + part[1][t] + pb[0];
    gobuf[grow] = g;
    outp[((size_t)b * HOR + tstep) * N + n] = g;
    Bth[((size_t)(4096 + b)) * 1024 + n] = (ushort)f2bf(g);
  }
}

// ---------------------------------------------------------------------------
extern "C" void kernel_launch(void* const* d_in, const int* in_sizes, int n_in,
                              void* d_out, int out_size, void* d_ws, size_t ws_size,
                              hipStream_t stream) {
  const float* x    = (const float*)d_in[0];
  const float* ycov = (const float*)d_in[1];
  const float* emb  = (const float*)d_in[2];
  const float* egW  = (const float*)d_in[3];
  const float* egb  = (const float*)d_in[4];
  const float* euW  = (const float*)d_in[5];
  const float* eub  = (const float*)d_in[6];
  const float* dgW  = (const float*)d_in[7];
  const float* dgb  = (const float*)d_in[8];
  const float* duW  = (const float*)d_in[9];
  const float* dub  = (const float*)d_in[10];
  const float* pW   = (const float*)d_in[11];
  const float* pb   = (const float*)d_in[12];
  float* out = (float*)d_out;
  float* ws  = (float*)d_ws;

  float* Amat = ws + A_off;
  float* Pxy  = ws + Pxy_off;
  float* hmat = ws + h_off;
  float* Ph   = ws + Ph_off;
  float* zh   = ws + zh_off;
  float* rb   = ws + r_off;
  float* gob  = ws + go_off;
  float* Pgo  = ws + Pgo_off;
  ushort* A2   = (ushort*)(ws + A2_off);
  ushort* Bth  = (ushort*)(ws + Bth_off);
  ushort* Btz  = (ushort*)(ws + Btz_off);
  ushort* xyK  = (ushort*)(ws + xyK_off);
  ushort* AspL = (ushort*)(ws + zh_off);   // precompute-only aliases
  ushort* AspR = (ushort*)(ws + r_off);
  float*  Pp   = ws + Ph_off;              // S2 partials alias
  ushort* WPge = (ushort*)(ws + wp_off);
  ushort* WPgd = WPge + 2 * 24576;
  ushort* WPue = WPgd + 2 * 24576;
  ushort* WPud = WPue + 2 * 12288;

  // ---- precompute ----
  build_A<<<N, 256, 0, stream>>>(emb, Amat);
  pack_split_S<<<dim3(32, 32), 256, 0, stream>>>(Amat, AspL, AspR);
  gemm_s2p<<<dim3(8, 8, 4), 256, 0, stream>>>(AspL, AspR, Pp);
  comb_s2<<<1024, 256, 0, stream>>>(Pp, A2);
  conv_bf16<<<1024, 256, 0, stream>>>(Amat, A2);   // rows 0..1023
  conv_xyK<<<3072, 256, 0, stream>>>(x, xyK, 0);
  conv_xyK<<<3072, 256, 0, stream>>>(ycov, xyK, 768);
  pack_W<<<(3 * 2 * 128 * 32 + 255) / 256, 256, 0, stream>>>(egW, WPge, 65, 128, 1);
  pack_W<<<(3 * 2 * 128 * 32 + 255) / 256, 256, 0, stream>>>(dgW, WPgd, 66, 128, 2);
  pack_W<<<(3 * 2 * 64 * 32 + 255) / 256, 256, 0, stream>>>(euW, WPue, 65, 64, 1);
  pack_W<<<(3 * 2 * 64 * 32 + 255) / 256, 256, 0, stream>>>(duW, WPud, 66, 64, 2);
  gemm_bt<0><<<dim3(12, 16), 256, 0, stream>>>(A2, xyK, 1536, Pxy, nullptr);
  (void)hipMemsetAsync(hmat, 0, NBH * sizeof(float), stream);
  (void)hipMemsetAsync(Ph, 0, 2 * NBH * sizeof(float), stream);
  (void)hipMemsetAsync(gob, 0, 65536 * sizeof(float), stream);
  (void)hipMemsetAsync(Bth + (size_t)4096 * 1024, 0, 128 * 1024 * sizeof(ushort), stream);

  // ---- encoder ----
  for (int t = 0; t < T; ++t) {
    if (t > 0)  // t=0: h=0 so Ph=0 (memset)
      gemm_bt<1><<<dim3(32, 16), 256, 0, stream>>>(A2, Bth, 4096, Ph, nullptr);
    gate_mfma<1><<<1024, 256, 0, stream>>>(hmat, Ph, WPge, egW, egb,
                                           x + t * 1024, T * 1024, Pxy + t * 64, 1536,
                                           nullptr, 0, nullptr, 0, zh, rb, Btz);
    if (t > 0)  // t=0: zh = z*0 = 0, so P(zh)=0
      gemm_bt<1><<<dim3(32, 16), 256, 0, stream>>>(A2, Btz, 4096, Ph, nullptr);
    upd_mfma<1, 0><<<1024, 256, 0, stream>>>(hmat, zh, Ph, WPue, euW, eub,
                                             x + t * 1024, T * 1024, Pxy + t * 64, 1536,
                                             nullptr, 0, nullptr, 0, rb, Bth,
                                             nullptr, nullptr, nullptr, nullptr, 0);
  }

  // ---- decoder ----
  for (int t = 0; t < HOR; ++t) {
    gemm_bt<1><<<dim3(33, 16), 256, 0, stream>>>(A2, Bth, 4096, Ph, Pgo);
    gate_mfma<2><<<1024, 256, 0, stream>>>(hmat, Ph, WPgd, dgW, dgb,
                                           gob, 1024, Pgo, 64,
                                           ycov + t * 1024, HOR * 1024,
                                           Pxy + 768 + t * 64, 1536, zh, rb, Btz);
    gemm_bt<1><<<dim3(32, 16), 256, 0, stream>>>(A2, Btz, 4096, Ph, nullptr);
    upd_mfma<2, 1><<<1024, 256, 0, stream>>>(hmat, zh, Ph, WPud, duW, dub,
                                             gob, 1024, Pgo, 64,
                                             ycov + t * 1024, HOR * 1024,
                                             Pxy + 768 + t * 64, 1536,
                                             rb, Bth, pW, pb, gob, out, t);
  }
}

// Round 9
// 2510.880 us; speedup vs baseline: 5.4422x; 1.0759x over previous
//
#include <hip/hip_runtime.h>
#include <math.h>

// Problem constants
constexpr int N = 1024, B = 64, T = 12, HOR = 12, H = 64, E = 8;
constexpr size_t NBH = 4194304;  // 65536 * 64

// Row index convention for all state arrays: grow = b*1024 + n  (b = grow>>10)
// Workspace layout (float units)
constexpr size_t A_off   = 0;                      // [1024][1024] fp32 A
constexpr size_t Pxy_off = 1048576;                // [2][1024][1536] fp32 (n-major)
constexpr size_t h_off   = Pxy_off + 3145728;      // [65536][64] fp32
constexpr size_t Ph_off  = h_off + NBH;            // ushort[2][65536][64] fp16 (precompute: S2 partials alias)
constexpr size_t zh_off  = Ph_off + 2 * NBH;       // [65536][64] fp32 (precompute: AspL alias)
constexpr size_t r_off   = zh_off + NBH;           // [65536][64] fp32 (precompute: AspR alias)
constexpr size_t go_off  = r_off + NBH;            // [65536] fp32
constexpr size_t A2_off  = go_off + 65536;         // ushort[2048][1024]
constexpr size_t Bth_off = A2_off + 1048576;       // ushort[4224][1024] (rows 4096..4159 = go)
constexpr size_t Btz_off = Bth_off + 2162688;      // ushort[4096][1024]
constexpr size_t xyK_off = Btz_off + 2097152;      // ushort[1536][1024]
constexpr size_t Pgo_off = xyK_off + 786432;       // [2][1024][64] fp32
constexpr size_t wp_off  = Pgo_off + 131072;       // weight panels (ushort)

typedef __attribute__((ext_vector_type(8))) short short8;
typedef _Float16 half8 __attribute__((ext_vector_type(8)));
typedef __attribute__((ext_vector_type(4))) float f32x4;

__device__ __forceinline__ unsigned f2bf(float x) {
  unsigned u = __float_as_uint(x);
  return (u + 0x7fffu + ((u >> 16) & 1u)) >> 16;   // RNE
}
__device__ __forceinline__ float bf2f(unsigned h) {
  return __uint_as_float(h << 16);
}
__device__ __forceinline__ ushort f2h(float x) {
  _Float16 h = (_Float16)x;
  ushort u;
  __builtin_memcpy(&u, &h, 2);
  return u;
}
__device__ __forceinline__ void split4(float4 v, uint2& hi, uint2& lo) {
  unsigned h0 = f2bf(v.x), h1 = f2bf(v.y), h2 = f2bf(v.z), h3 = f2bf(v.w);
  unsigned l0 = f2bf(v.x - bf2f(h0)), l1 = f2bf(v.y - bf2f(h1));
  unsigned l2 = f2bf(v.z - bf2f(h2)), l3 = f2bf(v.w - bf2f(h3));
  hi.x = (h0 & 0xffffu) | (h1 << 16); hi.y = (h2 & 0xffffu) | (h3 << 16);
  lo.x = (l0 & 0xffffu) | (l1 << 16); lo.y = (l2 & 0xffffu) | (l3 << 16);
}

typedef const __attribute__((address_space(1))) void gas_t;
typedef __attribute__((address_space(3))) void las_t;

// ---------------------------------------------------------------------------
// A = softmax(relu(emb @ emb^T)) row-wise. One block per row.
// ---------------------------------------------------------------------------
__global__ __launch_bounds__(256) void build_A(const float* __restrict__ emb,
                                               float* __restrict__ A) {
  __shared__ float sE[N * E];
  __shared__ float sv[N];
  __shared__ float rmax[4], rsum[4];
  const int i = blockIdx.x;
  for (int idx = threadIdx.x; idx < N * E / 4; idx += 256)
    ((float4*)sE)[idx] = ((const float4*)emb)[idx];
  __syncthreads();
  float ei[E];
#pragma unroll
  for (int e = 0; e < E; ++e) ei[e] = sE[i * E + e];
  float mymax = 0.f;
  for (int j = threadIdx.x; j < N; j += 256) {
    float d = 0.f;
#pragma unroll
    for (int e = 0; e < E; ++e) d = fmaf(ei[e], sE[j * E + e], d);
    d = fmaxf(d, 0.f);
    sv[j] = d;
    mymax = fmaxf(mymax, d);
  }
  for (int off = 32; off; off >>= 1) mymax = fmaxf(mymax, __shfl_down(mymax, off));
  const int wid = threadIdx.x >> 6, lid = threadIdx.x & 63;
  if (lid == 0) rmax[wid] = mymax;
  __syncthreads();
  const float m = fmaxf(fmaxf(rmax[0], rmax[1]), fmaxf(rmax[2], rmax[3]));
  float mysum = 0.f;
  for (int j = threadIdx.x; j < N; j += 256) {
    float ev = expf(sv[j] - m);
    sv[j] = ev;
    mysum += ev;
  }
  for (int off = 32; off; off >>= 1) mysum += __shfl_down(mysum, off);
  if (lid == 0) rsum[wid] = mysum;
  __syncthreads();
  const float inv = 1.f / (rsum[0] + rsum[1] + rsum[2] + rsum[3]);
  for (int j = threadIdx.x; j < N; j += 256) A[i * N + j] = sv[j] * inv;
}

// ---------------------------------------------------------------------------
// Split-pack A for the exact S2 gemm: L=(hi,lo,hi), R=(hi,hi,lo) K-triples.
// ---------------------------------------------------------------------------
__global__ __launch_bounds__(256) void pack_split_S(const float* __restrict__ A,
                                                    ushort* __restrict__ L,
                                                    ushort* __restrict__ R) {
  __shared__ float tile[32][33];
  const int bx = blockIdx.x * 32;
  const int by = blockIdx.y * 32;
  const int tx = threadIdx.x & 31;
  const int tg = threadIdx.x >> 5;
#pragma unroll
  for (int p = 0; p < 4; ++p) {
    int ty = tg * 4 + p;
    tile[ty][tx] = A[(size_t)(by + ty) * 1024 + bx + tx];
  }
  __syncthreads();
#pragma unroll
  for (int p = 0; p < 4; ++p) {
    int ty = tg * 4 + p;
    float v = tile[ty][tx];
    unsigned h = f2bf(v);
    unsigned l = f2bf(v - bf2f(h));
    size_t lb = (size_t)(by + ty) * 3072 + 3 * (bx + tx);
    L[lb + 0] = (ushort)h; L[lb + 1] = (ushort)l; L[lb + 2] = (ushort)h;
    float w = tile[tx][ty];
    unsigned hh = f2bf(w);
    unsigned ll = f2bf(w - bf2f(hh));
    size_t rbi = (size_t)(bx + ty) * 3072 + 3 * (by + tx);
    R[rbi + 0] = (ushort)hh; R[rbi + 1] = (ushort)hh; R[rbi + 2] = (ushort)ll;
  }
}

// ---------------------------------------------------------------------------
// fp32 -> bf16 bulk convert (A2 rows 0..1023 = bf16(A))
// ---------------------------------------------------------------------------
__global__ __launch_bounds__(256) void conv_bf16(const float* __restrict__ src,
                                                 ushort* __restrict__ dst) {
  int i = blockIdx.x * 256 + threadIdx.x;
  float4 v = ((const float4*)src)[i];
  ushort4 o;
  o.x = (ushort)f2bf(v.x); o.y = (ushort)f2bf(v.y);
  o.z = (ushort)f2bf(v.z); o.w = (ushort)f2bf(v.w);
  ((ushort4*)dst)[i] = o;
}

// ---------------------------------------------------------------------------
// x/ycov -> bf16 K-major: dst[(off + t*64 + b)][n] = bf16(src[b][t][n])
// ---------------------------------------------------------------------------
__global__ __launch_bounds__(256) void conv_xyK(const float* __restrict__ src,
                                                ushort* __restrict__ dst, int off) {
  int id = blockIdx.x * 256 + threadIdx.x;
  int tb = id >> 10, n = id & 1023;
  int tt = tb >> 6, b = tb & 63;
  dst[(size_t)(off + tb) * 1024 + n] = (ushort)f2bf(src[((size_t)b * T + tt) * 1024 + n]);
}

// ---------------------------------------------------------------------------
// Pre-split s=0 (h-part) weights into panel-major bf16 hi/lo.
// layout out[half][hi|lo][col][32]
// ---------------------------------------------------------------------------
__global__ __launch_bounds__(256) void pack_Wbf(const float* __restrict__ W,
                                                ushort* __restrict__ out,
                                                int CIN, int NC, int xoff) {
  int idx = blockIdx.x * 256 + threadIdx.x;
  int total = 2 * NC * 32;
  if (idx >= total) return;
  int kk = idx & 31;
  int rest = idx >> 5;
  int col = rest % NC;
  int half = rest / NC;
  float v = W[(size_t)(xoff + half * 32 + kk) * NC + col];
  unsigned hi = f2bf(v);
  unsigned lo = f2bf(v - bf2f(hi));
  size_t base = (size_t)(half * 2) * NC * 32;
  out[base + (size_t)col * 32 + kk] = (ushort)hi;
  out[base + (size_t)NC * 32 + (size_t)col * 32 + kk] = (ushort)lo;
}

// ---------------------------------------------------------------------------
// Pack s=1,2 (Ph-part) weights into panel-major fp16: out[(s-1)*2+half][col][32]
// ---------------------------------------------------------------------------
__global__ __launch_bounds__(256) void pack_W16(const float* __restrict__ W,
                                                ushort* __restrict__ out,
                                                int CIN, int NC, int xoff) {
  int idx = blockIdx.x * 256 + threadIdx.x;
  int total = 2 * 2 * NC * 32;
  if (idx >= total) return;
  int kk = idx & 31;
  int rest = idx >> 5;
  int col = rest % NC;
  rest /= NC;
  int half = rest & 1;
  int s1 = rest >> 1;
  int s = s1 + 1;
  float v = W[(size_t)(s * CIN + xoff + half * 32 + kk) * NC + col];
  out[(size_t)(s1 * 2 + half) * NC * 32 + (size_t)col * 32 + kk] = f2h(v);
}

// ---------------------------------------------------------------------------
// S2 partials: split-K=4 of the split-bf16 A@A gemm (K=3072 interleaved).
// ---------------------------------------------------------------------------
__global__ __launch_bounds__(256) void gemm_s2p(
    const ushort* __restrict__ L, const ushort* __restrict__ R,
    float* __restrict__ P) {
  __shared__ ushort As[128 * 32];
  __shared__ ushort Bs[128 * 32];
  const int t = threadIdx.x;
  const int wave = t >> 6, lane = t & 63;
  const int bm = blockIdx.y * 128, bn = blockIdx.x * 128;
  const int wm = (wave & 1) * 64, wn = (wave >> 1) * 64;
  float* Pz = P + (size_t)blockIdx.z * 1048576;
  const int kbase = blockIdx.z * 768;

  const ushort* aSrc[2]; const ushort* bSrc[2];
  ushort* aDst[2]; ushort* bDst[2];
#pragma unroll
  for (int u = 0; u < 2; ++u) {
    int idx = wave * 128 + u * 64 + lane;
    int row = idx >> 2;
    int kq = (idx & 3) * 8;
    aSrc[u] = L + (size_t)(bm + row) * 3072 + kq;
    bSrc[u] = R + (size_t)(bn + row) * 3072 + kq;
    aDst[u] = &As[(wave * 128 + u * 64) * 8];
    bDst[u] = &Bs[(wave * 128 + u * 64) * 8];
  }
  const int lr = lane & 15;
  const int lk = (lane >> 4) * 8;
  f32x4 acc[4][4];
#pragma unroll
  for (int i = 0; i < 4; ++i)
#pragma unroll
    for (int j = 0; j < 4; ++j) acc[i][j] = {0.f, 0.f, 0.f, 0.f};

  for (int k0 = kbase; k0 < kbase + 768; k0 += 32) {
#pragma unroll
    for (int u = 0; u < 2; ++u) {
      __builtin_amdgcn_global_load_lds((gas_t*)(aSrc[u] + k0), (las_t*)aDst[u], 16, 0, 0);
      __builtin_amdgcn_global_load_lds((gas_t*)(bSrc[u] + k0), (las_t*)bDst[u], 16, 0, 0);
    }
    __syncthreads();
    short8 a[4], b[4];
#pragma unroll
    for (int i = 0; i < 4; ++i) a[i] = *(const short8*)&As[(wm + i * 16 + lr) * 32 + lk];
#pragma unroll
    for (int j = 0; j < 4; ++j) b[j] = *(const short8*)&Bs[(wn + j * 16 + lr) * 32 + lk];
#pragma unroll
    for (int i = 0; i < 4; ++i)
#pragma unroll
      for (int j = 0; j < 4; ++j)
        acc[i][j] = __builtin_amdgcn_mfma_f32_16x16x32_bf16(a[i], b[j], acc[i][j], 0, 0, 0);
    __syncthreads();
  }
  const int cr = (lane >> 4) * 4;
  const int cc = lane & 15;
#pragma unroll
  for (int i = 0; i < 4; ++i)
#pragma unroll
    for (int j = 0; j < 4; ++j) {
      int gm = bm + wm + i * 16 + cr;
      int gn = bn + wn + j * 16 + cc;
#pragma unroll
      for (int r = 0; r < 4; ++r)
        Pz[(size_t)(gm + r) * 1024 + gn] = acc[i][j][r];
    }
}

// ---------------------------------------------------------------------------
// Combine S2 partials: v = 2*sum - I, write bf16 into A2 rows 1024..2047.
// ---------------------------------------------------------------------------
__global__ __launch_bounds__(256) void comb_s2(const float* __restrict__ P,
                                               ushort* __restrict__ A2) {
  int idx = blockIdx.x * 256 + threadIdx.x;
  float4 a = ((const float4*)P)[idx];
  float4 b = ((const float4*)(P + 1048576))[idx];
  float4 c = ((const float4*)(P + 2097152))[idx];
  float4 d = ((const float4*)(P + 3145728))[idx];
  int base = idx << 2;
  int m = base >> 10, c0 = base & 1023;
  float v0 = 2.f * (a.x + b.x + c.x + d.x) - (m == c0 + 0 ? 1.f : 0.f);
  float v1 = 2.f * (a.y + b.y + c.y + d.y) - (m == c0 + 1 ? 1.f : 0.f);
  float v2 = 2.f * (a.z + b.z + c.z + d.z) - (m == c0 + 2 ? 1.f : 0.f);
  float v3 = 2.f * (a.w + b.w + c.w + d.w) - (m == c0 + 3 ? 1.f : 0.f);
  ushort4 o;
  o.x = (ushort)f2bf(v0); o.y = (ushort)f2bf(v1);
  o.z = (ushort)f2bf(v2); o.w = (ushort)f2bf(v3);
  ((ushort4*)(A2 + 1048576))[idx] = o;
}

// ---------------------------------------------------------------------------
// Propagation GEMM (pure bf16 B^T, m97 form): C[2048][cols] = A2 @ Bt^T.
// CMODE 0: C1f row-major stride n1 (fp32, 2-D grid).
// CMODE 1: C1h fp16 state layout [half][(b,n)][j]; 1-D grid with XCD swizzle
//          (each XCD owns 4 bn-tiles -> B working set ~1 MB, L2-resident).
// Fold cols >= n1 -> C2 (fp32).
// ---------------------------------------------------------------------------
template <int CMODE>
__global__ __launch_bounds__(256) void gemm_bt(
    const ushort* __restrict__ A2, const ushort* __restrict__ Bt, int n1,
    ushort* __restrict__ C1h, float* __restrict__ C1f, float* __restrict__ C2) {
  __shared__ ushort As[2][128 * 32];
  __shared__ ushort Bs[2][128 * 32];
  const int t = threadIdx.x;
  const int wave = t >> 6, lane = t & 63;
  int bxi, byi;
  if (CMODE == 0) {
    bxi = blockIdx.x; byi = blockIdx.y;
  } else {
    int lin = blockIdx.x;
    if (lin < 512) {
      bxi = (lin & 7) * 4 + ((lin >> 3) & 3);
      byi = lin >> 5;
    } else {
      bxi = 32; byi = lin - 512;
    }
  }
  const int bm = byi * 128, bn = bxi * 128;
  const int wm = (wave & 1) * 64, wn = (wave >> 1) * 64;

  const ushort* aSrc[2]; const ushort* bSrc[2];
  ushort* aDst[2][2]; ushort* bDst[2][2];
#pragma unroll
  for (int u = 0; u < 2; ++u) {
    int idx = wave * 128 + u * 64 + lane;
    int row = idx >> 2;
    int kq = (idx & 3) * 8;
    aSrc[u] = A2 + (size_t)(bm + row) * 1024 + kq;
    bSrc[u] = Bt + (size_t)(bn + row) * 1024 + kq;
#pragma unroll
    for (int p = 0; p < 2; ++p) {
      aDst[p][u] = &As[p][(wave * 128 + u * 64) * 8];
      bDst[p][u] = &Bs[p][(wave * 128 + u * 64) * 8];
    }
  }
  const int lr = lane & 15, lk = (lane >> 4) * 8;
  int aOff[4], bOff[4];
#pragma unroll
  for (int i = 0; i < 4; ++i) {
    aOff[i] = (wm + i * 16 + lr) * 32 + lk;
    bOff[i] = (wn + i * 16 + lr) * 32 + lk;
  }
  f32x4 acc[4][4];
#pragma unroll
  for (int i = 0; i < 4; ++i)
#pragma unroll
    for (int j = 0; j < 4; ++j) acc[i][j] = {0.f, 0.f, 0.f, 0.f};

  for (int k0 = 0; k0 < 1024; k0 += 64) {
#pragma unroll
    for (int p = 0; p < 2; ++p)
#pragma unroll
      for (int u = 0; u < 2; ++u) {
        __builtin_amdgcn_global_load_lds((gas_t*)(aSrc[u] + k0 + p * 32),
                                         (las_t*)aDst[p][u], 16, 0, 0);
        __builtin_amdgcn_global_load_lds((gas_t*)(bSrc[u] + k0 + p * 32),
                                         (las_t*)bDst[p][u], 16, 0, 0);
      }
    __syncthreads();
#pragma unroll
    for (int p = 0; p < 2; ++p) {
      short8 a[4], b[4];
#pragma unroll
      for (int i = 0; i < 4; ++i) a[i] = *(const short8*)&As[p][aOff[i]];
#pragma unroll
      for (int j = 0; j < 4; ++j) b[j] = *(const short8*)&Bs[p][bOff[j]];
#pragma unroll
      for (int i = 0; i < 4; ++i)
#pragma unroll
        for (int j = 0; j < 4; ++j)
          acc[i][j] = __builtin_amdgcn_mfma_f32_16x16x32_bf16(a[i], b[j], acc[i][j], 0, 0, 0);
    }
    __syncthreads();
  }

  const int cr = (lane >> 4) * 4;
  const int cc = lane & 15;
#pragma unroll
  for (int i = 0; i < 4; ++i) {
#pragma unroll
    for (int j = 0; j < 4; ++j) {
      int gm = bm + wm + i * 16 + cr;
      int gn = bn + wn + j * 16 + cc;
      if (gn < n1) {
        if (CMODE == 0) {
          float* p = C1f + (size_t)gm * n1 + gn;
#pragma unroll
          for (int r = 0; r < 4; ++r) p[(size_t)r * n1] = acc[i][j][r];
        } else {
          int half = gm >> 10, nn = gm & 1023;
          ushort* p = C1h + (size_t)half * NBH +
                      ((size_t)(gn >> 6) * 1024 + nn) * 64 + (gn & 63);
#pragma unroll
          for (int r = 0; r < 4; ++r) p[(size_t)r * 64] = f2h(acc[i][j][r]);
        }
      } else if (C2 != nullptr && gn < n1 + 64) {
        float* p = C2 + (size_t)gm * 64 + (gn - n1);
#pragma unroll
        for (int r = 0; r < 4; ++r) p[(size_t)r * 64] = acc[i][j][r];
      }
    }
  }
}

// ---------------------------------------------------------------------------
// Gate: zr = sigmoid( s0-GEMM(split-bf16 exact h) + s1,2-GEMM(fp16 Ph, f16 MFMA)
//                     + exact fp32 x-terms + bias ). Writes zh, r, Btz.
// ---------------------------------------------------------------------------
template <int NX>
__global__ __launch_bounds__(256, 4) void gate_mfma(
    const float* __restrict__ hmat, const ushort* __restrict__ Ph16,
    const ushort* __restrict__ Wbf, const ushort* __restrict__ W16,
    const float* __restrict__ Wf, const float* __restrict__ bias,
    const float* __restrict__ xb0, int xbs0, const float* __restrict__ xp0, int xs0,
    const float* __restrict__ xb1, int xbs1, const float* __restrict__ xp1, int xs1,
    float* __restrict__ zh, float* __restrict__ rbuf, ushort* __restrict__ Btz) {
  constexpr int CIN = NX + 64;
  __shared__ ushort smem[12288];            // Ah|Al|Bh|Bl ; fp16: A16@0, B16@4096 ; epi: transT
  ushort* Ah = smem;                        // 64*32
  ushort* Al = smem + 2048;
  ushort* Bh = smem + 4096;                 // 128*32
  ushort* Bl = smem + 8192;
  ushort* A16 = smem;                       // 64*32 fp16
  ushort* B16 = smem + 4096;                // 128*32 fp16
  ushort* transT = smem;                    // 64*72
  __shared__ float sxv[3][2][64];
  __shared__ float sWx[3][2][128];
  const int t = threadIdx.x;
  const int wave = t >> 6, lane = t & 63;
  const int bm = blockIdx.x * 64;
  const int wm = (wave & 1) * 32, wn = (wave >> 1) * 64;
  const int lr = lane & 15, lk = (lane >> 4) * 8;

  if (t < 64) {
    int grow = bm + t;
    int n = grow & 1023, b = grow >> 10;
    sxv[0][0][t] = xb0[(size_t)b * xbs0 + n];
    sxv[1][0][t] = xp0[(size_t)n * xs0 + b];
    sxv[2][0][t] = xp0[(size_t)1024 * xs0 + (size_t)n * xs0 + b];
    if (NX == 2) {
      sxv[0][1][t] = xb1[(size_t)b * xbs1 + n];
      sxv[1][1][t] = xp1[(size_t)n * xs1 + b];
      sxv[2][1][t] = xp1[(size_t)1024 * xs1 + (size_t)n * xs1 + b];
    }
  } else if (t < 192) {
    int col = t - 64;
#pragma unroll
    for (int s = 0; s < 3; ++s)
#pragma unroll
      for (int f = 0; f < NX; ++f)
        sWx[s][f][col] = Wf[(size_t)(s * CIN + f) * 128 + col];
  }

  // s=0 A-pack addressing (2 float4 per thread)
  int arow[2], ajq[2];
#pragma unroll
  for (int p = 0; p < 2; ++p) {
    int f = p * 256 + t;
    arow[p] = f >> 3;
    ajq[p] = (f & 7) * 4;
  }
  // fp16 A-pack addressing (1 uint4 = 8 halves per thread)
  const int hrow = t >> 2, hjq = (t & 3) * 8;

  float4 pf[2];
#pragma unroll
  for (int p = 0; p < 2; ++p)
    pf[p] = *(const float4*)(hmat + (size_t)(bm + arow[p]) * 64 + ajq[p]);
  uint4 px;

  f32x4 acc[2][4];
#pragma unroll
  for (int i = 0; i < 2; ++i)
#pragma unroll
    for (int j = 0; j < 4; ++j) acc[i][j] = {0.f, 0.f, 0.f, 0.f};

  // ---- phase 1: s=0, exact split-bf16, 2 halves ----
#pragma unroll
  for (int half = 0; half < 2; ++half) {
#pragma unroll
    for (int p = 0; p < 2; ++p) {
      uint2 hi, lo;
      split4(pf[p], hi, lo);
      *(uint2*)&Ah[arow[p] * 32 + ajq[p]] = hi;
      *(uint2*)&Al[arow[p] * 32 + ajq[p]] = lo;
    }
    const ushort* wph = Wbf + (size_t)(half * 2) * (128 * 32);
    const ushort* wpl = wph + 128 * 32;
#pragma unroll
    for (int u = 0; u < 2; ++u) {
      int idx = wave * 128 + u * 64 + lane;
      __builtin_amdgcn_global_load_lds((gas_t*)(wph + idx * 8), (las_t*)&Bh[idx * 8], 16, 0, 0);
      __builtin_amdgcn_global_load_lds((gas_t*)(wpl + idx * 8), (las_t*)&Bl[idx * 8], 16, 0, 0);
    }
    __syncthreads();
    if (half == 0) {
#pragma unroll
      for (int p = 0; p < 2; ++p)
        pf[p] = *(const float4*)(hmat + (size_t)(bm + arow[p]) * 64 + 32 + ajq[p]);
    } else {
      px = *(const uint4*)(Ph16 + (size_t)(bm + hrow) * 64 + hjq);
    }
    short8 ah[2], al[2], bh[4], bl[4];
#pragma unroll
    for (int i = 0; i < 2; ++i) {
      ah[i] = *(const short8*)&Ah[(wm + i * 16 + lr) * 32 + lk];
      al[i] = *(const short8*)&Al[(wm + i * 16 + lr) * 32 + lk];
    }
#pragma unroll
    for (int j = 0; j < 4; ++j) {
      bh[j] = *(const short8*)&Bh[(wn + j * 16 + lr) * 32 + lk];
      bl[j] = *(const short8*)&Bl[(wn + j * 16 + lr) * 32 + lk];
    }
#pragma unroll
    for (int i = 0; i < 2; ++i)
#pragma unroll
      for (int j = 0; j < 4; ++j) {
        acc[i][j] = __builtin_amdgcn_mfma_f32_16x16x32_bf16(ah[i], bh[j], acc[i][j], 0, 0, 0);
        acc[i][j] = __builtin_amdgcn_mfma_f32_16x16x32_bf16(al[i], bh[j], acc[i][j], 0, 0, 0);
        acc[i][j] = __builtin_amdgcn_mfma_f32_16x16x32_bf16(ah[i], bl[j], acc[i][j], 0, 0, 0);
      }
    __syncthreads();
  }

  // ---- phase 2: s=1,2 fp16 Ph, single f16 MFMA ----
  for (int it = 0; it < 4; ++it) {
    const int s1 = it >> 1, half = it & 1;
    *(uint4*)&A16[hrow * 32 + hjq] = px;
    const ushort* w16 = W16 + (size_t)(s1 * 2 + half) * (128 * 32);
#pragma unroll
    for (int u = 0; u < 2; ++u) {
      int idx = wave * 128 + u * 64 + lane;
      __builtin_amdgcn_global_load_lds((gas_t*)(w16 + idx * 8), (las_t*)&B16[idx * 8], 16, 0, 0);
    }
    __syncthreads();
    if (it < 3) {
      const int nit = it + 1;
      const ushort* src = Ph16 + (size_t)(nit >> 1) * NBH;
      px = *(const uint4*)(src + (size_t)(bm + hrow) * 64 + (nit & 1) * 32 + hjq);
    }
    half8 a16[2], b16[4];
#pragma unroll
    for (int i = 0; i < 2; ++i)
      a16[i] = *(const half8*)&A16[(wm + i * 16 + lr) * 32 + lk];
#pragma unroll
    for (int j = 0; j < 4; ++j)
      b16[j] = *(const half8*)&B16[(wn + j * 16 + lr) * 32 + lk];
#pragma unroll
    for (int i = 0; i < 2; ++i)
#pragma unroll
      for (int j = 0; j < 4; ++j)
        acc[i][j] = __builtin_amdgcn_mfma_f32_16x16x32_f16(a16[i], b16[j], acc[i][j], 0, 0, 0);
    __syncthreads();
  }

  const int cr = (lane >> 4) * 4;
  const int cc = lane & 15;
#pragma unroll
  for (int i = 0; i < 2; ++i) {
#pragma unroll
    for (int j = 0; j < 4; ++j) {
      int col = wn + j * 16 + cc;
      float bcol = bias[col];
#pragma unroll
      for (int r = 0; r < 4; ++r) {
        int rowl = wm + i * 16 + cr + r;
        int grow = bm + rowl;
        float v = acc[i][j][r] + bcol;
#pragma unroll
        for (int s = 0; s < 3; ++s)
#pragma unroll
          for (int f = 0; f < NX; ++f)
            v = fmaf(sxv[s][f][rowl], sWx[s][f][col], v);
        float sig = 1.f / (1.f + expf(-v));
        if (col < 64) {
          float zv = sig * hmat[(size_t)grow * 64 + col];
          zh[(size_t)grow * 64 + col] = zv;
          transT[col * 72 + rowl] = (ushort)f2bf(zv);
        } else {
          rbuf[(size_t)grow * 64 + col - 64] = sig;
        }
      }
    }
  }
  __syncthreads();
  const int bq = bm >> 10, nb = bm & 1023;
  for (int idx = t; idx < 512; idx += 256) {
    int j = idx >> 3, ch = idx & 7;
    uint4 v = *(const uint4*)&transT[j * 72 + ch * 8];
    *(uint4*)(Btz + (((size_t)(bq * 64 + j)) << 10) + nb + ch * 8) = v;
  }
}

// ---------------------------------------------------------------------------
// Update: hc = tanh(s0-GEMM(split zh) + s1,2-GEMM(fp16 Pzh) + x-terms + b);
// h = r*h + (1-r)*hc. PROJ=1 fuses go-projection.
// ---------------------------------------------------------------------------
template <int NX, int PROJ>
__global__ __launch_bounds__(256, 4) void upd_mfma(
    float* __restrict__ hmat, const float* __restrict__ zhb, const ushort* __restrict__ Pzh16,
    const ushort* __restrict__ Wbf, const ushort* __restrict__ W16,
    const float* __restrict__ Wf, const float* __restrict__ bias,
    const float* __restrict__ xb0, int xbs0, const float* __restrict__ xp0, int xs0,
    const float* __restrict__ xb1, int xbs1, const float* __restrict__ xp1, int xs1,
    const float* __restrict__ rbuf, ushort* __restrict__ Bth,
    const float* __restrict__ pW, const float* __restrict__ pb,
    float* __restrict__ gobuf, float* __restrict__ outp, int tstep) {
  constexpr int CIN = NX + 64;
  __shared__ ushort smem[8192];             // Ah|Al|Bh|Bl ; fp16: A16@0, B16@4096 ; epi: transT
  ushort* Ah = smem;
  ushort* Al = smem + 2048;
  ushort* Bh = smem + 4096;                 // 64*32
  ushort* Bl = smem + 6144;
  ushort* A16 = smem;
  ushort* B16 = smem + 4096;                // 64*32 fp16
  ushort* transT = smem;                    // 64*72
  __shared__ float sxv[3][2][64];
  __shared__ float sWx[3][2][64];
  __shared__ float part[2][64];
  const int t = threadIdx.x;
  const int wave = t >> 6, lane = t & 63;
  const int bm = blockIdx.x * 64;
  const int wm = (wave & 1) * 32, wn = (wave >> 1) * 32;
  const int lr = lane & 15, lk = (lane >> 4) * 8;

  if (t < 64) {
    int grow = bm + t;
    int n = grow & 1023, b = grow >> 10;
    sxv[0][0][t] = xb0[(size_t)b * xbs0 + n];
    sxv[1][0][t] = xp0[(size_t)n * xs0 + b];
    sxv[2][0][t] = xp0[(size_t)1024 * xs0 + (size_t)n * xs0 + b];
    if (NX == 2) {
      sxv[0][1][t] = xb1[(size_t)b * xbs1 + n];
      sxv[1][1][t] = xp1[(size_t)n * xs1 + b];
      sxv[2][1][t] = xp1[(size_t)1024 * xs1 + (size_t)n * xs1 + b];
    }
  } else if (t < 128) {
    int col = t - 64;
#pragma unroll
    for (int s = 0; s < 3; ++s)
#pragma unroll
      for (int f = 0; f < NX; ++f)
        sWx[s][f][col] = Wf[(size_t)(s * CIN + f) * 64 + col];
  }

  int arow[2], ajq[2];
#pragma unroll
  for (int p = 0; p < 2; ++p) {
    int f = p * 256 + t;
    arow[p] = f >> 3;
    ajq[p] = (f & 7) * 4;
  }
  const int hrow = t >> 2, hjq = (t & 3) * 8;

  float4 pf[2];
#pragma unroll
  for (int p = 0; p < 2; ++p)
    pf[p] = *(const float4*)(zhb + (size_t)(bm + arow[p]) * 64 + ajq[p]);
  uint4 px;

  f32x4 acc[2][2];
#pragma unroll
  for (int i = 0; i < 2; ++i)
#pragma unroll
    for (int j = 0; j < 2; ++j) acc[i][j] = {0.f, 0.f, 0.f, 0.f};

  // ---- phase 1: s=0 exact split ----
#pragma unroll
  for (int half = 0; half < 2; ++half) {
#pragma unroll
    for (int p = 0; p < 2; ++p) {
      uint2 hi, lo;
      split4(pf[p], hi, lo);
      *(uint2*)&Ah[arow[p] * 32 + ajq[p]] = hi;
      *(uint2*)&Al[arow[p] * 32 + ajq[p]] = lo;
    }
    const ushort* wph = Wbf + (size_t)(half * 2) * (64 * 32);
    const ushort* wpl = wph + 64 * 32;
    {
      int idx = wave * 64 + lane;
      __builtin_amdgcn_global_load_lds((gas_t*)(wph + idx * 8), (las_t*)&Bh[idx * 8], 16, 0, 0);
      __builtin_amdgcn_global_load_lds((gas_t*)(wpl + idx * 8), (las_t*)&Bl[idx * 8], 16, 0, 0);
    }
    __syncthreads();
    if (half == 0) {
#pragma unroll
      for (int p = 0; p < 2; ++p)
        pf[p] = *(const float4*)(zhb + (size_t)(bm + arow[p]) * 64 + 32 + ajq[p]);
    } else {
      px = *(const uint4*)(Pzh16 + (size_t)(bm + hrow) * 64 + hjq);
    }
    short8 ah[2], al[2], bh[2], bl[2];
#pragma unroll
    for (int i = 0; i < 2; ++i) {
      ah[i] = *(const short8*)&Ah[(wm + i * 16 + lr) * 32 + lk];
      al[i] = *(const short8*)&Al[(wm + i * 16 + lr) * 32 + lk];
    }
#pragma unroll
    for (int j = 0; j < 2; ++j) {
      bh[j] = *(const short8*)&Bh[(wn + j * 16 + lr) * 32 + lk];
      bl[j] = *(const short8*)&Bl[(wn + j * 16 + lr) * 32 + lk];
    }
#pragma unroll
    for (int i = 0; i < 2; ++i)
#pragma unroll
      for (int j = 0; j < 2; ++j) {
        acc[i][j] = __builtin_amdgcn_mfma_f32_16x16x32_bf16(ah[i], bh[j], acc[i][j], 0, 0, 0);
        acc[i][j] = __builtin_amdgcn_mfma_f32_16x16x32_bf16(al[i], bh[j], acc[i][j], 0, 0, 0);
        acc[i][j] = __builtin_amdgcn_mfma_f32_16x16x32_bf16(ah[i], bl[j], acc[i][j], 0, 0, 0);
      }
    __syncthreads();
  }

  // ---- phase 2: s=1,2 fp16 ----
  for (int it = 0; it < 4; ++it) {
    const int s1 = it >> 1, half = it & 1;
    *(uint4*)&A16[hrow * 32 + hjq] = px;
    const ushort* w16 = W16 + (size_t)(s1 * 2 + half) * (64 * 32);
    {
      int idx = wave * 64 + lane;
      __builtin_amdgcn_global_load_lds((gas_t*)(w16 + idx * 8), (las_t*)&B16[idx * 8], 16, 0, 0);
    }
    __syncthreads();
    if (it < 3) {
      const int nit = it + 1;
      const ushort* src = Pzh16 + (size_t)(nit >> 1) * NBH;
      px = *(const uint4*)(src + (size_t)(bm + hrow) * 64 + (nit & 1) * 32 + hjq);
    }
    half8 a16[2], b16[2];
#pragma unroll
    for (int i = 0; i < 2; ++i)
      a16[i] = *(const half8*)&A16[(wm + i * 16 + lr) * 32 + lk];
#pragma unroll
    for (int j = 0; j < 2; ++j)
      b16[j] = *(const half8*)&B16[(wn + j * 16 + lr) * 32 + lk];
#pragma unroll
    for (int i = 0; i < 2; ++i)
#pragma unroll
      for (int j = 0; j < 2; ++j)
        acc[i][j] = __builtin_amdgcn_mfma_f32_16x16x32_f16(a16[i], b16[j], acc[i][j], 0, 0, 0);
    __syncthreads();
  }

  const int cr = (lane >> 4) * 4;
  const int cc = lane & 15;
  float psv[2][4];
#pragma unroll
  for (int i = 0; i < 2; ++i)
#pragma unroll
    for (int r = 0; r < 4; ++r) psv[i][r] = 0.f;

#pragma unroll
  for (int i = 0; i < 2; ++i) {
#pragma unroll
    for (int j = 0; j < 2; ++j) {
      int col = wn + j * 16 + cc;
      float bcol = bias[col];
      float pwc = PROJ ? pW[col] : 0.f;
#pragma unroll
      for (int r = 0; r < 4; ++r) {
        int rowl = wm + i * 16 + cr + r;
        int grow = bm + rowl;
        float v = acc[i][j][r] + bcol;
#pragma unroll
        for (int s = 0; s < 3; ++s)
#pragma unroll
          for (int f = 0; f < NX; ++f)
            v = fmaf(sxv[s][f][rowl], sWx[s][f][col], v);
        float hc = tanhf(v);
        size_t idx = (size_t)grow * 64 + col;
        float rr = rbuf[idx];
        float ho = hmat[idx];
        float o = rr * ho + (1.f - rr) * hc;
        hmat[idx] = o;
        transT[col * 72 + rowl] = (ushort)f2bf(o);
        if (PROJ) psv[i][r] += o * pwc;
      }
    }
  }
  if (PROJ) {
#pragma unroll
    for (int i = 0; i < 2; ++i)
#pragma unroll
      for (int r = 0; r < 4; ++r)
#pragma unroll
        for (int off = 8; off; off >>= 1)
          psv[i][r] += __shfl_down(psv[i][r], off, 16);
    if (cc == 0) {
#pragma unroll
      for (int i = 0; i < 2; ++i)
#pragma unroll
        for (int r = 0; r < 4; ++r)
          part[wn >> 5][wm + i * 16 + cr + r] = psv[i][r];
    }
  }
  __syncthreads();
  const int bq = bm >> 10, nb = bm & 1023;
  for (int idx = t; idx < 512; idx += 256) {
    int j = idx >> 3, ch = idx & 7;
    uint4 v = *(const uint4*)&transT[j * 72 + ch * 8];
    *(uint4*)(Bth + (((size_t)(bq * 64 + j)) << 10) + nb + ch * 8) = v;
  }
  if (PROJ && t < 64) {
    int grow = bm + t;
    int n = grow & 1023, b = grow >> 10;
    float g = part[0][t] + part[1][t] + pb[0];
    gobuf[grow] = g;
    outp[((size_t)b * HOR + tstep) * N + n] = g;
    Bth[((size_t)(4096 + b)) * 1024 + n] = (ushort)f2bf(g);
  }
}

// ---------------------------------------------------------------------------
extern "C" void kernel_launch(void* const* d_in, const int* in_sizes, int n_in,
                              void* d_out, int out_size, void* d_ws, size_t ws_size,
                              hipStream_t stream) {
  const float* x    = (const float*)d_in[0];
  const float* ycov = (const float*)d_in[1];
  const float* emb  = (const float*)d_in[2];
  const float* egW  = (const float*)d_in[3];
  const float* egb  = (const float*)d_in[4];
  const float* euW  = (const float*)d_in[5];
  const float* eub  = (const float*)d_in[6];
  const float* dgW  = (const float*)d_in[7];
  const float* dgb  = (const float*)d_in[8];
  const float* duW  = (const float*)d_in[9];
  const float* dub  = (const float*)d_in[10];
  const float* pW   = (const float*)d_in[11];
  const float* pb   = (const float*)d_in[12];
  float* out = (float*)d_out;
  float* ws  = (float*)d_ws;

  float* Amat = ws + A_off;
  float* Pxy  = ws + Pxy_off;
  float* hmat = ws + h_off;
  ushort* Ph16 = (ushort*)(ws + Ph_off);
  float* zh   = ws + zh_off;
  float* rb   = ws + r_off;
  float* gob  = ws + go_off;
  float* Pgo  = ws + Pgo_off;
  ushort* A2   = (ushort*)(ws + A2_off);
  ushort* Bth  = (ushort*)(ws + Bth_off);
  ushort* Btz  = (ushort*)(ws + Btz_off);
  ushort* xyK  = (ushort*)(ws + xyK_off);
  ushort* AspL = (ushort*)(ws + zh_off);   // precompute-only aliases
  ushort* AspR = (ushort*)(ws + r_off);
  float*  Pp   = ws + Ph_off;              // S2 partials alias (precompute only)
  ushort* WB   = (ushort*)(ws + wp_off);
  ushort* WbfGE = WB;                      // 2*2*128*32 = 16384
  ushort* WbfGD = WB + 16384;
  ushort* WbfUE = WB + 32768;              // 2*2*64*32 = 8192
  ushort* WbfUD = WB + 40960;
  ushort* W16GE = WB + 49152;              // 2*2*128*32 = 16384
  ushort* W16GD = WB + 65536;
  ushort* W16UE = WB + 81920;              // 2*2*64*32 = 8192
  ushort* W16UD = WB + 90112;

  // ---- precompute ----
  build_A<<<N, 256, 0, stream>>>(emb, Amat);
  pack_split_S<<<dim3(32, 32), 256, 0, stream>>>(Amat, AspL, AspR);
  gemm_s2p<<<dim3(8, 8, 4), 256, 0, stream>>>(AspL, AspR, Pp);
  comb_s2<<<1024, 256, 0, stream>>>(Pp, A2);
  conv_bf16<<<1024, 256, 0, stream>>>(Amat, A2);   // rows 0..1023
  conv_xyK<<<3072, 256, 0, stream>>>(x, xyK, 0);
  conv_xyK<<<3072, 256, 0, stream>>>(ycov, xyK, 768);
  pack_Wbf<<<32, 256, 0, stream>>>(egW, WbfGE, 65, 128, 1);
  pack_Wbf<<<32, 256, 0, stream>>>(dgW, WbfGD, 66, 128, 2);
  pack_Wbf<<<16, 256, 0, stream>>>(euW, WbfUE, 65, 64, 1);
  pack_Wbf<<<16, 256, 0, stream>>>(duW, WbfUD, 66, 64, 2);
  pack_W16<<<64, 256, 0, stream>>>(egW, W16GE, 65, 128, 1);
  pack_W16<<<64, 256, 0, stream>>>(dgW, W16GD, 66, 128, 2);
  pack_W16<<<32, 256, 0, stream>>>(euW, W16UE, 65, 64, 1);
  pack_W16<<<32, 256, 0, stream>>>(duW, W16UD, 66, 64, 2);
  gemm_bt<0><<<dim3(12, 16), 256, 0, stream>>>(A2, xyK, 1536, nullptr, Pxy, nullptr);
  (void)hipMemsetAsync(hmat, 0, NBH * sizeof(float), stream);
  (void)hipMemsetAsync(Ph16, 0, 2 * NBH * sizeof(ushort), stream);
  (void)hipMemsetAsync(gob, 0, 65536 * sizeof(float), stream);
  (void)hipMemsetAsync(Bth + (size_t)4096 * 1024, 0, 128 * 1024 * sizeof(ushort), stream);

  // ---- encoder ----
  for (int t = 0; t < T; ++t) {
    if (t > 0)  // t=0: h=0 so Ph=0 (memset)
      gemm_bt<1><<<512, 256, 0, stream>>>(A2, Bth, 4096, Ph16, nullptr, nullptr);
    gate_mfma<1><<<1024, 256, 0, stream>>>(hmat, Ph16, WbfGE, W16GE, egW, egb,
                                           x + t * 1024, T * 1024, Pxy + t * 64, 1536,
                                           nullptr, 0, nullptr, 0, zh, rb, Btz);
    if (t > 0)  // t=0: zh = z*0 = 0, so P(zh)=0
      gemm_bt<1><<<512, 256, 0, stream>>>(A2, Btz, 4096, Ph16, nullptr, nullptr);
    upd_mfma<1, 0><<<1024, 256, 0, stream>>>(hmat, zh, Ph16, WbfUE, W16UE, euW, eub,
                                             x + t * 1024, T * 1024, Pxy + t * 64, 1536,
                                             nullptr, 0, nullptr, 0, rb, Bth,
                                             nullptr, nullptr, nullptr, nullptr, 0);
  }

  // ---- decoder ----
  for (int t = 0; t < HOR; ++t) {
    gemm_bt<1><<<528, 256, 0, stream>>>(A2, Bth, 4096, Ph16, nullptr, Pgo);
    gate_mfma<2><<<1024, 256, 0, stream>>>(hmat, Ph16, WbfGD, W16GD, dgW, dgb,
                                           gob, 1024, Pgo, 64,
                                           ycov + t * 1024, HOR * 1024,
                                           Pxy + 768 + t * 64, 1536, zh, rb, Btz);
    gemm_bt<1><<<512, 256, 0, stream>>>(A2, Btz, 4096, Ph16, nullptr, nullptr);
    upd_mfma<2, 1><<<1024, 256, 0, stream>>>(hmat, zh, Ph16, WbfUD, W16UD, duW, dub,
                                             gob, 1024, Pgo, 64,
                                             ycov + t * 1024, HOR * 1024,
                                             Pxy + 768 + t * 64, 1536,
                                             rb, Bth, pW, pb, gob, out, t);
  }
}